// Round 3
// baseline (24205.196 us; speedup 1.0000x reference)
//
#include <hip/hip_runtime.h>
#include <hip/hip_bf16.h>

#define TID threadIdx.x

typedef __hip_bfloat16 bf16;
__device__ __forceinline__ float b2f(bf16 x) { return __bfloat162float(x); }
__device__ __forceinline__ bf16  f2b(float x) { return __float2bfloat16(x); }

// ---- problem constants ----
#define B_   256
#define T_   7
#define NI_  12
#define TN_  84          // T_*NI_
#define J_   17
#define D_   128
#define H_   4
#define DH_  32
#define C_   8
#define G1_  21504       // B_*TN_  (joint-stage graphs)
#define R1_  365568      // G1_*J_  (joint-stage rows)
#define G2_  1792        // B_*T_   (ind-stage graphs)
#define R2_  21504       // G2_*NI_ (ind-stage rows)
#define EPS_ 1e-5f

// =====================================================================
__global__ __launch_bounds__(256)
void zero_kernel(float* __restrict__ p, int n)
{
    for (int i = TID; i < n; i += 256) p[i] = 0.f;
}

// =====================================================================
// Embedding: h = leaky_relu(poses @ emb_w.T + emb_b)  -> bf16 [R1,128]
// =====================================================================
__global__ __launch_bounds__(256)
void embed_kernel(const float* __restrict__ poses, const float* __restrict__ ew,
                  const float* __restrict__ eb, bf16* __restrict__ h, int total)
{
    int stride = gridDim.x * 256;
    for (int idx = blockIdx.x * 256 + TID; idx < total; idx += stride) {
        int r = idx >> 7, d = idx & 127;
        float p0 = poses[2 * r], p1 = poses[2 * r + 1];
        float v = p0 * ew[2 * d] + p1 * ew[2 * d + 1] + eb[d];
        h[idx] = f2b(v > 0.f ? v : 0.01f * v);
    }
}

// =====================================================================
// Per-graph mean over nodes: hbar[g,d] = mean_i h[g,i,d]
// =====================================================================
__global__ __launch_bounds__(256)
void gmean_kernel(const bf16* __restrict__ h, bf16* __restrict__ hbar, int G, int n)
{
    int idx = blockIdx.x * 256 + TID;
    if (idx >= G * D_) return;
    int g = idx >> 7, d = idx & 127;
    const bf16* p = h + (size_t)g * n * D_ + d;
    float s = 0.f;
    for (int i = 0; i < n; ++i) s += b2f(p[i * D_]);
    hbar[idx] = f2b(s * (1.f / n));
}

// =====================================================================
// gcn[g,:] = hbar[g,:] @ gw.T + gb   (16 graphs / block)
// =====================================================================
__global__ __launch_bounds__(256)
void gcnmv_kernel(const bf16* __restrict__ hbar, const float* __restrict__ gw,
                  const float* __restrict__ gb, bf16* __restrict__ gcn, int G)
{
    __shared__ float sA[16][129];
    __shared__ float sW[32][129];
    int gbase = blockIdx.x * 16;
    for (int t = TID; t < 16 * D_; t += 256) sA[t >> 7][t & 127] = b2f(hbar[gbase * D_ + t]);
    for (int c0 = 0; c0 < D_; c0 += 32) {
        for (int t = TID; t < 32 * D_; t += 256)
            sW[t >> 7][t & 127] = gw[(c0 + (t >> 7)) * D_ + (t & 127)];
        __syncthreads();
        for (int t = TID; t < 16 * 32; t += 256) {
            int r = t >> 5, c = t & 31;
            float acc = gb[c0 + c];
            #pragma unroll 8
            for (int k = 0; k < D_; ++k) acc += sA[r][k] * sW[c][k];
            gcn[(gbase + r) * D_ + c0 + c] = f2b(acc);
        }
        __syncthreads();
    }
}

// =====================================================================
// BN statistics: per-channel sum & sumsq of X (+ optional broadcast gcn row)
// writes into stats[0..127] / stats[128..255]; caller pre-zeroes.
// =====================================================================
__global__ __launch_bounds__(256)
void bnstats_kernel(const bf16* __restrict__ X, const bf16* __restrict__ gcn,
                    int n, int R, float* __restrict__ stats)
{
    int c = TID & 127, half = TID >> 7;
    float s = 0.f, q = 0.f;
    for (int r = blockIdx.x * 2 + half; r < R; r += gridDim.x * 2) {
        float x = b2f(X[(size_t)r * D_ + c]);
        if (gcn) x += b2f(gcn[(r / n) * D_ + c]);
        s += x; q += x * x;
    }
    __shared__ float sS[256], sQ[256];
    sS[TID] = s; sQ[TID] = q;
    __syncthreads();
    if (TID < 128) {
        atomicAdd(&stats[c], sS[TID] + sS[TID + 128]);
        atomicAdd(&stats[D_ + c], sQ[TID] + sQ[TID + 128]);
    }
}

// =====================================================================
// Fused double-BN apply, in place over X:
//   X = BN1(X + gcn_bcast)*g1+b1 + BN2(t2)*g2+b2
// stats layout: [0:128] sum1, [128:256] sq1, [256:384] sum2, [384:512] sq2
// =====================================================================
__global__ __launch_bounds__(256)
void apply12_kernel(bf16* __restrict__ X, const bf16* __restrict__ gcn,
                    const bf16* __restrict__ t2, const float* __restrict__ stats,
                    const float* __restrict__ bng, const float* __restrict__ bnb,
                    float rcount, int n, int total)
{
    int stride = gridDim.x * 256;
    for (int idx = blockIdx.x * 256 + TID; idx < total; idx += stride) {
        int c = idx & 127, r = idx >> 7;
        float m1 = stats[c] * rcount;
        float v1 = stats[128 + c] * rcount - m1 * m1;
        float m2 = stats[256 + c] * rcount;
        float v2 = stats[384 + c] * rcount - m2 * m2;
        float x1 = b2f(X[idx]) + b2f(gcn[(r / n) * D_ + c]);
        float x2 = b2f(t2[idx]);
        float y = (x1 - m1) * rsqrtf(v1 + EPS_) * bng[c] + bnb[c]
                + (x2 - m2) * rsqrtf(v2 + EPS_) * bng[128 + c] + bnb[128 + c];
        X[idx] = f2b(y);
    }
}

// =====================================================================
// Single-BN apply, in place:  X = BN(X)*g+b
// =====================================================================
__global__ __launch_bounds__(256)
void apply3_kernel(bf16* __restrict__ X, const float* __restrict__ stats,
                   const float* __restrict__ gamma, const float* __restrict__ beta,
                   float rcount, int total)
{
    int stride = gridDim.x * 256;
    for (int idx = blockIdx.x * 256 + TID; idx < total; idx += stride) {
        int c = idx & 127;
        float m = stats[c] * rcount;
        float v = stats[128 + c] * rcount - m * m;
        float y = (b2f(X[idx]) - m) * rsqrtf(v + EPS_) * gamma[c] + beta[c];
        X[idx] = f2b(y);
    }
}

// =====================================================================
// Fused attention per graph (one block per graph, fp32 in LDS):
//   t2 = attn(h) + h  (includes output proj + ob + residual)
// =====================================================================
template<int NN>
__global__ __launch_bounds__(256)
void attn_kernel(const bf16* __restrict__ h,
                 const float* __restrict__ qw, const float* __restrict__ qb,
                 const float* __restrict__ ow, const float* __restrict__ ob,
                 bf16* __restrict__ out)
{
    __shared__ float sH[NN][129];
    __shared__ float sQKV[NN][385];
    __shared__ float sS[H_][NN][NN + 1];
    __shared__ float sO[NN][129];
    __shared__ float sW[32][129];

    const int g = blockIdx.x;
    const bf16* hg = h + (size_t)g * NN * D_;

    for (int t = TID; t < NN * D_; t += 256) sH[t >> 7][t & 127] = b2f(hg[t]);

    // qkv = h @ qw.T + qb, streamed in 32-column chunks of qw
    for (int c0 = 0; c0 < 3 * D_; c0 += 32) {
        for (int t = TID; t < 32 * D_; t += 256)
            sW[t >> 7][t & 127] = qw[(c0 + (t >> 7)) * D_ + (t & 127)];
        __syncthreads();
        for (int t = TID; t < NN * 32; t += 256) {
            int i = t >> 5, c = t & 31;
            float acc = qb[c0 + c];
            const float* a = sH[i]; const float* w = sW[c];
            #pragma unroll 8
            for (int k = 0; k < D_; ++k) acc += a[k] * w[k];
            sQKV[i][c0 + c] = acc;
        }
        __syncthreads();
    }

    // scores
    const float inv = 0.17677669529663687f; // 1/sqrt(32)
    for (int t = TID; t < H_ * NN * NN; t += 256) {
        int hd = t / (NN * NN); int rem = t - hd * NN * NN;
        int i = rem / NN, j = rem - i * NN;
        const float* q = &sQKV[i][hd * DH_];
        const float* k = &sQKV[j][D_ + hd * DH_];
        float acc = 0.f;
        #pragma unroll
        for (int d = 0; d < DH_; ++d) acc += q[d] * k[d];
        sS[hd][i][j] = acc * inv;
    }
    __syncthreads();

    // row softmax
    for (int t = TID; t < H_ * NN; t += 256) {
        int hd = t / NN, i = t - hd * NN;
        float* row = sS[hd][i];
        float m = row[0];
        for (int j = 1; j < NN; ++j) m = fmaxf(m, row[j]);
        float s = 0.f;
        for (int j = 0; j < NN; ++j) { float e = expf(row[j] - m); row[j] = e; s += e; }
        float rs = 1.f / s;
        for (int j = 0; j < NN; ++j) row[j] *= rs;
    }
    __syncthreads();

    // attn @ v
    for (int t = TID; t < NN * D_; t += 256) {
        int i = t >> 7, c = t & 127, hd = c >> 5;
        float acc = 0.f;
        #pragma unroll
        for (int j = 0; j < NN; ++j) acc += sS[hd][i][j] * sQKV[j][2 * D_ + c];
        sO[i][c] = acc;
    }
    __syncthreads();

    // proj + ob + residual h
    bf16* og = out + (size_t)g * NN * D_;
    for (int c0 = 0; c0 < D_; c0 += 32) {
        for (int t = TID; t < 32 * D_; t += 256)
            sW[t >> 7][t & 127] = ow[(c0 + (t >> 7)) * D_ + (t & 127)];
        __syncthreads();
        for (int t = TID; t < NN * 32; t += 256) {
            int i = t >> 5, c = t & 31;
            float acc = ob[c0 + c] + sH[i][c0 + c];
            const float* a = sO[i]; const float* w = sW[c];
            #pragma unroll 8
            for (int k = 0; k < D_; ++k) acc += a[k] * w[k];
            og[i * D_ + c0 + c] = f2b(acc);
        }
        __syncthreads();
    }
}

// =====================================================================
// Fused MLP, in place (16 rows / block): X = X + relu(X@w1.T+b1)@w2.T + b2
// Safe in-place: block stages its own 16 rows in LDS before writing them.
// =====================================================================
__global__ __launch_bounds__(256)
void mlp_kernel(bf16* __restrict__ X, const float* __restrict__ w1,
                const float* __restrict__ b1, const float* __restrict__ w2,
                const float* __restrict__ b2)
{
    __shared__ float sX[16][129];
    __shared__ float sM[16][257];
    __shared__ float sW[32][257];
    int rbase = blockIdx.x * 16;
    for (int t = TID; t < 16 * D_; t += 256) sX[t >> 7][t & 127] = b2f(X[(size_t)rbase * D_ + t]);

    for (int c0 = 0; c0 < 2 * D_; c0 += 32) {
        for (int t = TID; t < 32 * D_; t += 256)
            sW[t >> 7][t & 127] = w1[(c0 + (t >> 7)) * D_ + (t & 127)];
        __syncthreads();
        for (int t = TID; t < 16 * 32; t += 256) {
            int r = t >> 5, c = t & 31;
            float acc = b1[c0 + c];
            #pragma unroll 8
            for (int k = 0; k < D_; ++k) acc += sX[r][k] * sW[c][k];
            sM[r][c0 + c] = fmaxf(acc, 0.f);
        }
        __syncthreads();
    }
    for (int c0 = 0; c0 < D_; c0 += 32) {
        for (int t = TID; t < 32 * 256; t += 256)
            sW[t >> 8][t & 255] = w2[(c0 + (t >> 8)) * 256 + (t & 255)];
        __syncthreads();
        for (int t = TID; t < 16 * 32; t += 256) {
            int r = t >> 5, c = t & 31;
            float acc = b2[c0 + c] + sX[r][c0 + c];
            #pragma unroll 8
            for (int k = 0; k < 2 * D_; ++k) acc += sM[r][k] * sW[c][k];
            X[((size_t)rbase + r) * D_ + c0 + c] = f2b(acc);
        }
        __syncthreads();
    }
}

// =====================================================================
// Final pooling over (T,N) + classifier. One block per batch element.
// =====================================================================
__global__ __launch_bounds__(128)
void poolcls_kernel(const bf16* __restrict__ gi, const float* __restrict__ cw,
                    const float* __restrict__ cb, float* __restrict__ out)
{
    __shared__ float sP[128];
    int b = blockIdx.x, d = TID;
    const bf16* p = gi + (size_t)b * TN_ * D_ + d;
    float s = 0.f;
    for (int i = 0; i < TN_; ++i) s += b2f(p[i * D_]);
    sP[d] = s * (1.f / TN_);
    __syncthreads();
    if (d < C_) {
        float acc = cb[d];
        for (int k = 0; k < D_; ++k) acc += sP[k] * cw[d * D_ + k];
        out[b * C_ + d] = acc;
    }
}

// =====================================================================
extern "C" void kernel_launch(void* const* d_in, const int* in_sizes, int n_in,
                              void* d_out, int out_size, void* d_ws, size_t ws_size,
                              hipStream_t stream)
{
    (void)in_sizes; (void)n_in; (void)out_size; (void)ws_size;

    const float* poses = (const float*)d_in[0];
    const float* emb_w = (const float*)d_in[1];
    const float* emb_b = (const float*)d_in[2];
    const float* cls_w = (const float*)d_in[3];
    const float* cls_b = (const float*)d_in[4];
    const float* jp[12]; const float* ip[12];
    for (int k = 0; k < 12; ++k) { jp[k] = (const float*)d_in[5 + k]; ip[k] = (const float*)d_in[17 + k]; }

    // ---- workspace layout (~199 MB total) ----
    char* base = (char*)d_ws;
    size_t off = 0;
    auto alloc_b = [&](size_t elems) -> bf16* {
        bf16* p = (bf16*)(base + off);
        off = (off + elems * sizeof(bf16) + 255) & ~(size_t)255;
        return p;
    };
    bf16* bufA  = alloc_b((size_t)R1_ * D_);   // joint h (in-place through layers)
    bf16* bufB  = alloc_b((size_t)R1_ * D_);   // t2 scratch (joint & ind stages)
    bf16* hbarJ = alloc_b((size_t)G1_ * D_);   // joint graph means; later ind-stage h
    bf16* gcn1  = alloc_b((size_t)G1_ * D_);
    bf16* hbar2 = alloc_b((size_t)G2_ * D_);
    bf16* gcn2  = alloc_b((size_t)G2_ * D_);
    float* stats = (float*)(base + off);       // 768 floats

    embed_kernel<<<4096, 256, 0, stream>>>(poses, emb_w, emb_b, bufA, R1_ * D_);

    auto run_stage = [&](const float** P, bf16* h, bf16* t2, bf16* hbar, bf16* gcn,
                         int G, int n, int R) {
        for (int L = 0; L < 3; ++L) {
            const float* gw  = P[0] + (size_t)L * D_ * D_;
            const float* gb  = P[1] + (size_t)L * D_;
            const float* qw  = P[2] + (size_t)L * 3 * D_ * D_;
            const float* qb  = P[3] + (size_t)L * 3 * D_;
            const float* ow  = P[4] + (size_t)L * D_ * D_;
            const float* ob  = P[5] + (size_t)L * D_;
            const float* bng = P[6] + (size_t)L * 3 * D_;
            const float* bnb = P[7] + (size_t)L * 3 * D_;
            const float* w1  = P[8] + (size_t)L * 2 * D_ * D_;
            const float* b1  = P[9] + (size_t)L * 2 * D_;
            const float* w2  = P[10] + (size_t)L * D_ * 2 * D_;
            const float* b2  = P[11] + (size_t)L * D_;
            int total = R * D_;
            int egrid = (total + 255) / 256; if (egrid > 8192) egrid = 8192;
            float rcount = 1.f / (float)R;

            zero_kernel<<<1, 256, 0, stream>>>(stats, 768);
            gmean_kernel<<<(G * D_ + 255) / 256, 256, 0, stream>>>(h, hbar, G, n);
            gcnmv_kernel<<<G / 16, 256, 0, stream>>>(hbar, gw, gb, gcn, G);
            if (n == J_) attn_kernel<J_><<<G, 256, 0, stream>>>(h, qw, qb, ow, ob, t2);
            else         attn_kernel<NI_><<<G, 256, 0, stream>>>(h, qw, qb, ow, ob, t2);
            bnstats_kernel<<<512, 256, 0, stream>>>(h, gcn, n, R, stats);        // stats1
            bnstats_kernel<<<512, 256, 0, stream>>>(t2, nullptr, 1, R, stats + 256); // stats2
            apply12_kernel<<<egrid, 256, 0, stream>>>(h, gcn, t2, stats, bng, bnb,
                                                      rcount, n, total);
            mlp_kernel<<<R / 16, 256, 0, stream>>>(h, w1, b1, w2, b2);
            bnstats_kernel<<<512, 256, 0, stream>>>(h, nullptr, 1, R, stats + 512);  // stats3
            apply3_kernel<<<egrid, 256, 0, stream>>>(h, stats + 512, bng + 2 * D_,
                                                     bnb + 2 * D_, rcount, total);
        }
    };

    // joint stage (h in bufA, in place)
    run_stage(jp, bufA, bufB, hbarJ, gcn1, G1_, J_, R1_);
    // joint->individual pooling == graph-mean of final joint h (row orders coincide)
    gmean_kernel<<<(G1_ * D_ + 255) / 256, 256, 0, stream>>>(bufA, hbarJ, G1_, J_);
    // individual stage (h lives in hbarJ; reuse bufB as t2 scratch)
    run_stage(ip, hbarJ, bufB, hbar2, gcn2, G2_, NI_, R2_);
    // final pooling + classifier
    poolcls_kernel<<<B_, 128, 0, stream>>>(hbarJ, cls_w, cls_b, (float*)d_out);
}

// Round 4
// 2607.273 us; speedup vs baseline: 9.2837x; 9.2837x over previous
//
#include <hip/hip_runtime.h>
#include <hip/hip_bf16.h>

#define TID threadIdx.x

typedef __hip_bfloat16 bf16;
typedef short s8v __attribute__((ext_vector_type(8)));
typedef float f4v __attribute__((ext_vector_type(4)));

__device__ __forceinline__ float b2f(bf16 x) { return __bfloat162float(x); }
__device__ __forceinline__ bf16  f2b(float x) { return __float2bfloat16(x); }
__device__ __forceinline__ short f2s(float x) {
    __hip_bfloat16 b = __float2bfloat16(x); short s; __builtin_memcpy(&s, &b, 2); return s;
}
__device__ __forceinline__ float bfu(short s) {
    unsigned u = ((unsigned)(unsigned short)s) << 16; float f; __builtin_memcpy(&f, &u, 4); return f;
}

// ---- problem constants ----
#define B_   256
#define T_   7
#define NI_  12
#define TN_  84
#define J_   17
#define D_   128
#define H_   4
#define DH_  32
#define C_   8
#define G1_  21504       // B_*TN_
#define R1_  365568      // G1_*J_
#define G2_  1792        // B_*T_
#define R2_  21504       // G2_*NI_
#define EPS_ 1e-5f

// =====================================================================
__global__ __launch_bounds__(256)
void zero_kernel(float* __restrict__ p, int n)
{
    for (int i = TID; i < n; i += 256) p[i] = 0.f;
}

// fp32 -> bf16 weight conversion
__global__ __launch_bounds__(256)
void wconv_kernel(const float* __restrict__ src, bf16* __restrict__ dst, int n)
{
    int stride = gridDim.x * 256;
    for (int i = blockIdx.x * 256 + TID; i < n; i += stride) dst[i] = f2b(src[i]);
}

// =====================================================================
// Embedding (vectorized 8 cols/thread): h = leaky_relu(poses @ ew.T + eb)
// =====================================================================
__global__ __launch_bounds__(256)
void embedv_kernel(const float* __restrict__ poses, const float* __restrict__ ew,
                   const float* __restrict__ eb, bf16* __restrict__ h, int R)
{
    __shared__ float sE0[128], sE1[128], sEb[128];
    if (TID < 128) { sE0[TID] = ew[2 * TID]; sE1[TID] = ew[2 * TID + 1]; sEb[TID] = eb[TID]; }
    __syncthreads();
    int stride = gridDim.x * 256;
    for (int i8 = blockIdx.x * 256 + TID; i8 < R * 16; i8 += stride) {
        int r = i8 >> 4, c8 = (i8 & 15) * 8;
        float p0 = poses[2 * r], p1 = poses[2 * r + 1];
        s8v o;
        #pragma unroll
        for (int e = 0; e < 8; ++e) {
            int c = c8 + e;
            float v = p0 * sE0[c] + p1 * sE1[c] + sEb[c];
            o[e] = f2s(v > 0.f ? v : 0.01f * v);
        }
        *(s8v*)(h + (size_t)r * D_ + c8) = o;
    }
}

// =====================================================================
// Per-graph mean over nodes (vectorized)
// =====================================================================
__global__ __launch_bounds__(256)
void gmeanv_kernel(const bf16* __restrict__ h, bf16* __restrict__ hbar, int G, int n)
{
    int i8 = blockIdx.x * 256 + TID;
    if (i8 >= G * 16) return;
    int g = i8 >> 4, c8 = (i8 & 15) * 8;
    const bf16* p = h + (size_t)g * n * D_ + c8;
    float acc[8] = {0,0,0,0,0,0,0,0};
    for (int j = 0; j < n; ++j) {
        s8v v = *(const s8v*)(p + j * D_);
        #pragma unroll
        for (int e = 0; e < 8; ++e) acc[e] += bfu(v[e]);
    }
    float rn = 1.f / n;
    s8v o;
    #pragma unroll
    for (int e = 0; e < 8; ++e) o[e] = f2s(acc[e] * rn);
    *(s8v*)(hbar + (size_t)g * D_ + c8) = o;
}

// =====================================================================
// linear64: out[r,:] = X[r,:] @ W.T + bias   (64 rows/block, MFMA)
// X bf16 [R,128], W bf16 [128,128] row-major, out bf16
// =====================================================================
__global__ __launch_bounds__(256)
void linear64_kernel(const bf16* __restrict__ X, const bf16* __restrict__ Wb,
                     const float* __restrict__ bias, bf16* __restrict__ out)
{
    const int l = TID & 63, wid = TID >> 6;
    const size_t rbase = (size_t)blockIdx.x * 64;
    const int t = wid;
    const int arow = t * 16 + (l & 15);
    s8v a[4];
    #pragma unroll
    for (int ks = 0; ks < 4; ++ks)
        a[ks] = *(const s8v*)(X + (rbase + arow) * D_ + ks * 32 + ((l >> 4) * 8));
    for (int nt = 0; nt < 8; ++nt) {
        int col = nt * 16 + (l & 15);
        float bs = bias[col];
        f4v acc = {bs, bs, bs, bs};
        #pragma unroll
        for (int ks = 0; ks < 4; ++ks) {
            s8v b = *(const s8v*)(Wb + (size_t)col * D_ + ks * 32 + ((l >> 4) * 8));
            acc = __builtin_amdgcn_mfma_f32_16x16x32_bf16(a[ks], b, acc, 0, 0, 0);
        }
        #pragma unroll
        for (int r = 0; r < 4; ++r) {
            int row = t * 16 + (l >> 4) * 4 + r;
            out[(rbase + row) * D_ + col] = f2b(acc[r]);
        }
    }
}

// =====================================================================
// Fused attention, MFMA projections. NG graphs/block.
//  t2 = attn(h) + h
// =====================================================================
template<int NN, int NG>
__global__ __launch_bounds__(256)
void attn_mfma_kernel(const bf16* __restrict__ h,
                      const bf16* __restrict__ qwb, const float* __restrict__ qb,
                      const bf16* __restrict__ owb, const float* __restrict__ ob,
                      bf16* __restrict__ out)
{
    constexpr int ROWS = NG * NN;
    constexpr int MT = (ROWS + 15) / 16;
    constexpr int QP = 3 * D_ + 8;            // 392 shorts: 784B rows, 16B-aligned, banks+4
    __shared__ short sQKV[MT * 16][QP];
    __shared__ short sP[NG][H_][NN][NN + 1];

    const int l = TID & 63, wid = TID >> 6;
    const size_t gbase = (size_t)blockIdx.x * ROWS * D_;
    const bf16* hb = h + gbase;

    // ---------- phase 1: QKV = h @ qw.T + qb  (nt split across waves) ----------
    s8v a[MT][4];
    #pragma unroll
    for (int t = 0; t < MT; ++t) {
        int row = t * 16 + (l & 15);
        if (row >= ROWS) row = ROWS - 1;      // padded rows duplicate last row (masked later)
        const bf16* rp = hb + (size_t)row * D_ + ((l >> 4) * 8);
        #pragma unroll
        for (int ks = 0; ks < 4; ++ks) a[t][ks] = *(const s8v*)(rp + ks * 32);
    }
    for (int nt = wid; nt < 24; nt += 4) {
        int col = nt * 16 + (l & 15);
        const bf16* wp = qwb + (size_t)col * D_ + ((l >> 4) * 8);
        s8v b[4];
        #pragma unroll
        for (int ks = 0; ks < 4; ++ks) b[ks] = *(const s8v*)(wp + ks * 32);
        float bs = qb[col];
        #pragma unroll
        for (int t = 0; t < MT; ++t) {
            f4v acc = {bs, bs, bs, bs};
            #pragma unroll
            for (int ks = 0; ks < 4; ++ks)
                acc = __builtin_amdgcn_mfma_f32_16x16x32_bf16(a[t][ks], b[ks], acc, 0, 0, 0);
            #pragma unroll
            for (int r = 0; r < 4; ++r)
                sQKV[t * 16 + (l >> 4) * 4 + r][col] = f2s(acc[r]);
        }
    }
    __syncthreads();

    // ---------- phase 2: scores + softmax -> sP (bf16) ----------
    const float inv = 0.17677669529663687f;   // 1/sqrt(32)
    for (int task = TID; task < NG * H_ * NN; task += 256) {
        int g = task / (H_ * NN), rem = task % (H_ * NN);
        int hd = rem / NN, i = rem % NN;
        float qv[DH_];
        const short* qp = &sQKV[g * NN + i][hd * DH_];
        #pragma unroll
        for (int v8 = 0; v8 < 4; ++v8) {
            s8v q8 = *(const s8v*)(qp + v8 * 8);
            #pragma unroll
            for (int e = 0; e < 8; ++e) qv[v8 * 8 + e] = bfu(q8[e]);
        }
        float s[NN]; float m = -1e30f;
        #pragma unroll
        for (int j = 0; j < NN; ++j) {
            const short* kp = &sQKV[g * NN + j][D_ + hd * DH_];
            float acc = 0.f;
            #pragma unroll
            for (int v8 = 0; v8 < 4; ++v8) {
                s8v k8 = *(const s8v*)(kp + v8 * 8);
                #pragma unroll
                for (int e = 0; e < 8; ++e) acc += qv[v8 * 8 + e] * bfu(k8[e]);
            }
            s[j] = acc * inv;
            m = fmaxf(m, s[j]);
        }
        float sum = 0.f;
        #pragma unroll
        for (int j = 0; j < NN; ++j) { s[j] = __expf(s[j] - m); sum += s[j]; }
        float rs = 1.f / sum;
        #pragma unroll
        for (int j = 0; j < NN; ++j) sP[g][hd][i][j] = f2s(s[j] * rs);
    }
    __syncthreads();

    // ---------- phase 3: O = P @ V  -> overwrite Q slot (cols 0..127) ----------
    for (int task = TID; task < ROWS * 16; task += 256) {
        int r = task >> 4, c8 = task & 15;
        int g = r / NN, i = r % NN, hd = c8 >> 2;
        float acc[8] = {0,0,0,0,0,0,0,0};
        #pragma unroll
        for (int j = 0; j < NN; ++j) {
            float p = bfu(sP[g][hd][i][j]);
            s8v vv = *(const s8v*)(&sQKV[g * NN + j][2 * D_ + c8 * 8]);
            #pragma unroll
            for (int e = 0; e < 8; ++e) acc[e] += p * bfu(vv[e]);
        }
        s8v ov;
        #pragma unroll
        for (int e = 0; e < 8; ++e) ov[e] = f2s(acc[e]);
        *(s8v*)(&sQKV[r][c8 * 8]) = ov;
    }
    __syncthreads();

    // ---------- phase 4: out = O @ ow.T + ob + h ----------
    bf16* og = out + gbase;
    #pragma unroll
    for (int t = 0; t < MT; ++t) {
        int row = t * 16 + (l & 15);
        const short* rp = &sQKV[row][(l >> 4) * 8];
        #pragma unroll
        for (int ks = 0; ks < 4; ++ks) a[t][ks] = *(const s8v*)(rp + ks * 32);
    }
    for (int nt = wid; nt < 8; nt += 4) {
        int col = nt * 16 + (l & 15);
        const bf16* wp = owb + (size_t)col * D_ + ((l >> 4) * 8);
        s8v b[4];
        #pragma unroll
        for (int ks = 0; ks < 4; ++ks) b[ks] = *(const s8v*)(wp + ks * 32);
        float bs = ob[col];
        #pragma unroll
        for (int t = 0; t < MT; ++t) {
            f4v acc = {bs, bs, bs, bs};
            #pragma unroll
            for (int ks = 0; ks < 4; ++ks)
                acc = __builtin_amdgcn_mfma_f32_16x16x32_bf16(a[t][ks], b[ks], acc, 0, 0, 0);
            #pragma unroll
            for (int r = 0; r < 4; ++r) {
                int row = t * 16 + (l >> 4) * 4 + r;
                if (row < ROWS) {
                    float res = b2f(hb[(size_t)row * D_ + col]);
                    og[(size_t)row * D_ + col] = f2b(acc[r] + res);
                }
            }
        }
    }
}

// =====================================================================
// Fused MLP (MFMA, 64 rows/block, in place):
//   X = X + relu(X@w1.T + b1) @ w2.T + b2
// =====================================================================
__global__ __launch_bounds__(256)
void mlp_mfma_kernel(bf16* __restrict__ X, const bf16* __restrict__ w1b,
                     const float* __restrict__ b1, const bf16* __restrict__ w2b,
                     const float* __restrict__ b2)
{
    constexpr int MP = 264;                   // 256+8 shorts: 528B rows, banks+4
    __shared__ short sM[64][MP];
    const int l = TID & 63, wid = TID >> 6;
    bf16* Xb = X + (size_t)blockIdx.x * 64 * D_;

    // phase 1: M = relu(X @ w1.T + b1)  (nt split)
    s8v a[4][4];
    #pragma unroll
    for (int t = 0; t < 4; ++t) {
        const bf16* rp = Xb + (size_t)(t * 16 + (l & 15)) * D_ + ((l >> 4) * 8);
        #pragma unroll
        for (int ks = 0; ks < 4; ++ks) a[t][ks] = *(const s8v*)(rp + ks * 32);
    }
    for (int nt = wid; nt < 16; nt += 4) {
        int col = nt * 16 + (l & 15);
        const bf16* wp = w1b + (size_t)col * D_ + ((l >> 4) * 8);
        s8v b[4];
        #pragma unroll
        for (int ks = 0; ks < 4; ++ks) b[ks] = *(const s8v*)(wp + ks * 32);
        float bs = b1[col];
        #pragma unroll
        for (int t = 0; t < 4; ++t) {
            f4v acc = {bs, bs, bs, bs};
            #pragma unroll
            for (int ks = 0; ks < 4; ++ks)
                acc = __builtin_amdgcn_mfma_f32_16x16x32_bf16(a[t][ks], b[ks], acc, 0, 0, 0);
            #pragma unroll
            for (int r = 0; r < 4; ++r)
                sM[t * 16 + (l >> 4) * 4 + r][col] = f2s(fmaxf(acc[r], 0.f));
        }
    }
    __syncthreads();

    // phase 2: X += M @ w2.T + b2   (tile split: wave w -> rows 16w..16w+15)
    {
        const int t = wid;
        s8v am[8];
        const short* rp = &sM[t * 16 + (l & 15)][(l >> 4) * 8];
        #pragma unroll
        for (int ks = 0; ks < 8; ++ks) am[ks] = *(const s8v*)(rp + ks * 32);
        for (int nt = 0; nt < 8; ++nt) {
            int col = nt * 16 + (l & 15);
            float bs = b2[col];
            f4v acc = {bs, bs, bs, bs};
            #pragma unroll
            for (int ks = 0; ks < 8; ++ks) {
                s8v b = *(const s8v*)(w2b + (size_t)col * 256 + ks * 32 + ((l >> 4) * 8));
                acc = __builtin_amdgcn_mfma_f32_16x16x32_bf16(am[ks], b, acc, 0, 0, 0);
            }
            #pragma unroll
            for (int r = 0; r < 4; ++r) {
                size_t idx = (size_t)(t * 16 + (l >> 4) * 4 + r) * D_ + col;
                Xb[idx] = f2b(acc[r] + b2f(Xb[idx]));
            }
        }
    }
}

// =====================================================================
// Fused BN stats for branches 1&2: sum/sumsq of (h+gcn) and t2
// stats[0:128]=s1 [128:256]=q1 [256:384]=s2 [384:512]=q2 (pre-zeroed)
// =====================================================================
__global__ __launch_bounds__(256)
void bnstats12_kernel(const bf16* __restrict__ h, const bf16* __restrict__ gcn,
                      const bf16* __restrict__ t2, int n, int R, float* __restrict__ stats)
{
    __shared__ float red[4][256][8];
    int c8 = TID & 15, rg = TID >> 4;
    float s1[8] = {0}, q1[8] = {0}, s2[8] = {0}, q2[8] = {0};
    for (int r = blockIdx.x * 16 + rg; r < R; r += gridDim.x * 16) {
        s8v xv = *(const s8v*)(h + (size_t)r * D_ + c8 * 8);
        s8v gv = *(const s8v*)(gcn + (size_t)(r / n) * D_ + c8 * 8);
        s8v tv = *(const s8v*)(t2 + (size_t)r * D_ + c8 * 8);
        #pragma unroll
        for (int e = 0; e < 8; ++e) {
            float x = bfu(xv[e]) + bfu(gv[e]);
            s1[e] += x; q1[e] += x * x;
            float y = bfu(tv[e]);
            s2[e] += y; q2[e] += y * y;
        }
    }
    #pragma unroll
    for (int e = 0; e < 8; ++e) {
        red[0][TID][e] = s1[e]; red[1][TID][e] = q1[e];
        red[2][TID][e] = s2[e]; red[3][TID][e] = q2[e];
    }
    __syncthreads();
    if (TID < 128) {
        int chunk = TID >> 3, e = TID & 7;
        #pragma unroll
        for (int a = 0; a < 4; ++a) {
            float s = 0.f;
            #pragma unroll
            for (int rg2 = 0; rg2 < 16; ++rg2) s += red[a][rg2 * 16 + chunk][e];
            atomicAdd(&stats[a * 128 + TID], s);
        }
    }
}

// single-tensor BN stats -> stats[0:128], [128:256]
__global__ __launch_bounds__(256)
void bnstats1_kernel(const bf16* __restrict__ X, int R, float* __restrict__ stats)
{
    __shared__ float red[2][256][8];
    int c8 = TID & 15, rg = TID >> 4;
    float s1[8] = {0}, q1[8] = {0};
    for (int r = blockIdx.x * 16 + rg; r < R; r += gridDim.x * 16) {
        s8v xv = *(const s8v*)(X + (size_t)r * D_ + c8 * 8);
        #pragma unroll
        for (int e = 0; e < 8; ++e) { float x = bfu(xv[e]); s1[e] += x; q1[e] += x * x; }
    }
    #pragma unroll
    for (int e = 0; e < 8; ++e) { red[0][TID][e] = s1[e]; red[1][TID][e] = q1[e]; }
    __syncthreads();
    if (TID < 128) {
        int chunk = TID >> 3, e = TID & 7;
        #pragma unroll
        for (int a = 0; a < 2; ++a) {
            float s = 0.f;
            #pragma unroll
            for (int rg2 = 0; rg2 < 16; ++rg2) s += red[a][rg2 * 16 + chunk][e];
            atomicAdd(&stats[a * 128 + TID], s);
        }
    }
}

// =====================================================================
// apply12 (vectorized, in place): X = BN1(X+gcn) + BN2(t2)
// =====================================================================
__global__ __launch_bounds__(256)
void apply12v_kernel(bf16* __restrict__ X, const bf16* __restrict__ gcn,
                     const bf16* __restrict__ t2, const float* __restrict__ stats,
                     const float* __restrict__ bng, const float* __restrict__ bnb,
                     float rcount, int n, int total8)
{
    __shared__ float sA1[128], sB1[128], sA2[128], sB2[128];
    if (TID < 128) {
        int c = TID;
        float m1 = stats[c] * rcount, v1 = stats[128 + c] * rcount - m1 * m1;
        float a1 = rsqrtf(v1 + EPS_) * bng[c];
        sA1[c] = a1; sB1[c] = bnb[c] - m1 * a1;
        float m2 = stats[256 + c] * rcount, v2 = stats[384 + c] * rcount - m2 * m2;
        float a2 = rsqrtf(v2 + EPS_) * bng[128 + c];
        sA2[c] = a2; sB2[c] = bnb[128 + c] - m2 * a2;
    }
    __syncthreads();
    int stride = gridDim.x * 256;
    for (int i8 = blockIdx.x * 256 + TID; i8 < total8; i8 += stride) {
        int r = i8 >> 4, c8 = (i8 & 15) * 8;
        s8v xv = *(const s8v*)(X + (size_t)r * D_ + c8);
        s8v gv = *(const s8v*)(gcn + (size_t)(r / n) * D_ + c8);
        s8v tv = *(const s8v*)(t2 + (size_t)r * D_ + c8);
        s8v o;
        #pragma unroll
        for (int e = 0; e < 8; ++e) {
            int c = c8 + e;
            float y = (bfu(xv[e]) + bfu(gv[e])) * sA1[c] + sB1[c]
                    + bfu(tv[e]) * sA2[c] + sB2[c];
            o[e] = f2s(y);
        }
        *(s8v*)(X + (size_t)r * D_ + c8) = o;
    }
}

// apply3 (vectorized, in place): X = BN(X)
__global__ __launch_bounds__(256)
void apply3v_kernel(bf16* __restrict__ X, const float* __restrict__ stats,
                    const float* __restrict__ gamma, const float* __restrict__ beta,
                    float rcount, int total8)
{
    __shared__ float sA[128], sB[128];
    if (TID < 128) {
        int c = TID;
        float m = stats[c] * rcount, v = stats[128 + c] * rcount - m * m;
        float a = rsqrtf(v + EPS_) * gamma[c];
        sA[c] = a; sB[c] = beta[c] - m * a;
    }
    __syncthreads();
    int stride = gridDim.x * 256;
    for (int i8 = blockIdx.x * 256 + TID; i8 < total8; i8 += stride) {
        int r = i8 >> 4, c8 = (i8 & 15) * 8;
        s8v xv = *(const s8v*)(X + (size_t)r * D_ + c8);
        s8v o;
        #pragma unroll
        for (int e = 0; e < 8; ++e) {
            int c = c8 + e;
            o[e] = f2s(bfu(xv[e]) * sA[c] + sB[c]);
        }
        *(s8v*)(X + (size_t)r * D_ + c8) = o;
    }
}

// =====================================================================
// Final pooling over 84 rows + classifier
// =====================================================================
__global__ __launch_bounds__(128)
void poolcls_kernel(const bf16* __restrict__ gi, const float* __restrict__ cw,
                    const float* __restrict__ cb, float* __restrict__ out)
{
    __shared__ float sP[128];
    int b = blockIdx.x, d = TID;
    const bf16* p = gi + (size_t)b * TN_ * D_ + d;
    float s = 0.f;
    for (int i = 0; i < TN_; ++i) s += b2f(p[i * D_]);
    sP[d] = s * (1.f / TN_);
    __syncthreads();
    if (d < C_) {
        float acc = cb[d];
        for (int k = 0; k < D_; ++k) acc += sP[k] * cw[d * D_ + k];
        out[b * C_ + d] = acc;
    }
}

// =====================================================================
extern "C" void kernel_launch(void* const* d_in, const int* in_sizes, int n_in,
                              void* d_out, int out_size, void* d_ws, size_t ws_size,
                              hipStream_t stream)
{
    (void)in_sizes; (void)n_in; (void)out_size; (void)ws_size;

    const float* poses = (const float*)d_in[0];
    const float* emb_w = (const float*)d_in[1];
    const float* emb_b = (const float*)d_in[2];
    const float* cls_w = (const float*)d_in[3];
    const float* cls_b = (const float*)d_in[4];
    const float* jp[12]; const float* ip[12];
    for (int k = 0; k < 12; ++k) { jp[k] = (const float*)d_in[5 + k]; ip[k] = (const float*)d_in[17 + k]; }

    // ---- workspace layout (~201 MB) ----
    char* base = (char*)d_ws;
    size_t off = 0;
    auto alloc_b = [&](size_t elems) -> bf16* {
        bf16* p = (bf16*)(base + off);
        off = (off + elems * sizeof(bf16) + 255) & ~(size_t)255;
        return p;
    };
    bf16* bufA  = alloc_b((size_t)R1_ * D_);
    bf16* bufB  = alloc_b((size_t)R1_ * D_);
    bf16* hbarJ = alloc_b((size_t)G1_ * D_);
    bf16* gcn1  = alloc_b((size_t)G1_ * D_);
    bf16* hbar2 = alloc_b((size_t)G2_ * D_);
    bf16* gcn2  = alloc_b((size_t)G2_ * D_);
    float* stats = (float*)(base + off); off = (off + 768 * 4 + 255) & ~(size_t)255;
    // bf16 weights: per stage {gw, qw, ow, w1, w2} for all 3 layers
    bf16* wb[2][5];
    const int wsz[5] = {3 * D_ * D_, 3 * 3 * D_ * D_, 3 * D_ * D_, 3 * 2 * D_ * D_, 3 * 2 * D_ * D_};
    for (int s = 0; s < 2; ++s)
        for (int k = 0; k < 5; ++k) wb[s][k] = alloc_b((size_t)wsz[k]);

    // convert weights (every launch; graph-safe)
    const int widx[5] = {0, 2, 4, 8, 10};   // gw, qw, ow, w1, w2 within param list
    for (int s = 0; s < 2; ++s) {
        const float** P = s ? ip : jp;
        for (int k = 0; k < 5; ++k)
            wconv_kernel<<<(wsz[k] + 4095) / 4096, 256, 0, stream>>>(P[widx[k]], wb[s][k], wsz[k]);
    }

    embedv_kernel<<<4096, 256, 0, stream>>>(poses, emb_w, emb_b, bufA, R1_);

    auto run_stage = [&](const float** P, const bf16* const* W, bf16* h, bf16* t2,
                         bf16* hbar, bf16* gcn, int G, int n, int R) {
        for (int L = 0; L < 3; ++L) {
            const bf16* gwb = W[0] + (size_t)L * D_ * D_;
            const bf16* qwb = W[1] + (size_t)L * 3 * D_ * D_;
            const bf16* owb = W[2] + (size_t)L * D_ * D_;
            const bf16* w1b = W[3] + (size_t)L * 2 * D_ * D_;
            const bf16* w2b = W[4] + (size_t)L * 2 * D_ * D_;
            const float* gb  = P[1] + (size_t)L * D_;
            const float* qb  = P[3] + (size_t)L * 3 * D_;
            const float* ob  = P[5] + (size_t)L * D_;
            const float* bng = P[6] + (size_t)L * 3 * D_;
            const float* bnb = P[7] + (size_t)L * 3 * D_;
            const float* b1  = P[9] + (size_t)L * 2 * D_;
            const float* b2  = P[11] + (size_t)L * D_;
            int total8 = R * 16;
            float rcount = 1.f / (float)R;

            zero_kernel<<<1, 256, 0, stream>>>(stats, 768);
            gmeanv_kernel<<<G * 16 / 256, 256, 0, stream>>>(h, hbar, G, n);
            linear64_kernel<<<G / 64, 256, 0, stream>>>(hbar, gwb, gb, gcn);
            if (n == J_) attn_mfma_kernel<J_, 3><<<G / 3, 256, 0, stream>>>(h, qwb, qb, owb, ob, t2);
            else         attn_mfma_kernel<NI_, 4><<<G / 4, 256, 0, stream>>>(h, qwb, qb, owb, ob, t2);
            bnstats12_kernel<<<1024, 256, 0, stream>>>(h, gcn, t2, n, R, stats);
            apply12v_kernel<<<2048, 256, 0, stream>>>(h, gcn, t2, stats, bng, bnb,
                                                      rcount, n, total8);
            mlp_mfma_kernel<<<R / 64, 256, 0, stream>>>(h, w1b, b1, w2b, b2);
            bnstats1_kernel<<<1024, 256, 0, stream>>>(h, R, stats + 512);
            apply3v_kernel<<<2048, 256, 0, stream>>>(h, stats + 512, bng + 2 * D_,
                                                     bnb + 2 * D_, rcount, total8);
        }
    };

    // joint stage
    run_stage(jp, wb[0], bufA, bufB, hbarJ, gcn1, G1_, J_, R1_);
    // joint -> individual pooling (graph-mean over joints; row orders coincide)
    gmeanv_kernel<<<G1_ * 16 / 256, 256, 0, stream>>>(bufA, hbarJ, G1_, J_);
    // individual stage
    run_stage(ip, wb[1], hbarJ, bufB, hbar2, gcn2, G2_, NI_, R2_);
    // final pooling + classifier
    poolcls_kernel<<<B_, 128, 0, stream>>>(hbarJ, cls_w, cls_b, (float*)d_out);
}

// Round 7
// 2450.744 us; speedup vs baseline: 9.8767x; 1.0639x over previous
//
#include <hip/hip_runtime.h>
#include <hip/hip_bf16.h>

#define TID threadIdx.x

typedef __hip_bfloat16 bf16;
typedef short s8v __attribute__((ext_vector_type(8)));
typedef float f4v __attribute__((ext_vector_type(4)));

__device__ __forceinline__ float b2f(bf16 x) { return __bfloat162float(x); }
__device__ __forceinline__ bf16  f2b(float x) { return __float2bfloat16(x); }
__device__ __forceinline__ short f2s(float x) {
    __hip_bfloat16 b = __float2bfloat16(x); short s; __builtin_memcpy(&s, &b, 2); return s;
}
__device__ __forceinline__ float bfu(short s) {
    unsigned u = ((unsigned)(unsigned short)s) << 16; float f; __builtin_memcpy(&f, &u, 4); return f;
}

// ---- problem constants ----
#define B_   256
#define T_   7
#define NI_  12
#define TN_  84
#define J_   17
#define D_   128
#define H_   4
#define DH_  32
#define C_   8
#define G1_  21504       // B_*TN_
#define R1_  365568      // G1_*J_
#define G2_  1792        // B_*T_
#define R2_  21504       // G2_*NI_
#define EPS_ 1e-5f
#define NSLOT 32

// =====================================================================
__global__ __launch_bounds__(256)
void zero_kernel(float* __restrict__ p, int n)
{
    int stride = gridDim.x * 256;
    for (int i = blockIdx.x * 256 + TID; i < n; i += stride) p[i] = 0.f;
}

__global__ __launch_bounds__(128)
void setid_kernel(float* __restrict__ ab)
{
    ab[TID] = 1.f; ab[128 + TID] = 0.f;
}

// fp32 -> bf16 weight conversion
__global__ __launch_bounds__(256)
void wconv_kernel(const float* __restrict__ src, bf16* __restrict__ dst, int n)
{
    int stride = gridDim.x * 256;
    for (int i = blockIdx.x * 256 + TID; i < n; i += stride) dst[i] = f2b(src[i]);
}

// =====================================================================
// Embedding: h = leaky_relu(poses @ ew.T + eb)  (raw, no pending BN)
// =====================================================================
__global__ __launch_bounds__(256)
void embedv_kernel(const float* __restrict__ poses, const float* __restrict__ ew,
                   const float* __restrict__ eb, bf16* __restrict__ h, int R)
{
    __shared__ float sE0[128], sE1[128], sEb[128];
    if (TID < 128) { sE0[TID] = ew[2 * TID]; sE1[TID] = ew[2 * TID + 1]; sEb[TID] = eb[TID]; }
    __syncthreads();
    int stride = gridDim.x * 256;
    for (int i8 = blockIdx.x * 256 + TID; i8 < R * 16; i8 += stride) {
        int r = i8 >> 4, c8 = (i8 & 15) * 8;
        float p0 = poses[2 * r], p1 = poses[2 * r + 1];
        s8v o;
        #pragma unroll
        for (int e = 0; e < 8; ++e) {
            int c = c8 + e;
            float v = p0 * sE0[c] + p1 * sE1[c] + sEb[c];
            o[e] = f2s(v > 0.f ? v : 0.01f * v);
        }
        *(s8v*)(h + (size_t)r * D_ + c8) = o;
    }
}

// =====================================================================
// Per-graph mean with pending-BN affine applied after the (linear) mean:
//   hbar[g,c] = A3[c]*mean_i raw[g,i,c] + B3[c]
// =====================================================================
__global__ __launch_bounds__(256)
void gmeanv_kernel(const bf16* __restrict__ h, const float* __restrict__ ab,
                   bf16* __restrict__ hbar, int G, int n)
{
    int i8 = blockIdx.x * 256 + TID;
    if (i8 >= G * 16) return;
    int g = i8 >> 4, c8 = (i8 & 15) * 8;
    const bf16* p = h + (size_t)g * n * D_ + c8;
    float acc[8] = {0,0,0,0,0,0,0,0};
    for (int j = 0; j < n; ++j) {
        s8v v = *(const s8v*)(p + j * D_);
        #pragma unroll
        for (int e = 0; e < 8; ++e) acc[e] += bfu(v[e]);
    }
    float rn = 1.f / n;
    s8v o;
    #pragma unroll
    for (int e = 0; e < 8; ++e) {
        int c = c8 + e;
        o[e] = f2s(acc[e] * rn * ab[c] + ab[128 + c]);
    }
    *(s8v*)(hbar + (size_t)g * D_ + c8) = o;
}

// =====================================================================
// linear64: out[r,:] = X[r,:] @ W.T + bias   (64 rows/block, MFMA)
// =====================================================================
__global__ __launch_bounds__(256)
void linear64_kernel(const bf16* __restrict__ X, const bf16* __restrict__ Wb,
                     const float* __restrict__ bias, bf16* __restrict__ out)
{
    const int l = TID & 63, wid = TID >> 6;
    const size_t rbase = (size_t)blockIdx.x * 64;
    const int t = wid;
    const int arow = t * 16 + (l & 15);
    s8v a[4];
    #pragma unroll
    for (int ks = 0; ks < 4; ++ks)
        a[ks] = *(const s8v*)(X + (rbase + arow) * D_ + ks * 32 + ((l >> 4) * 8));
    for (int nt = 0; nt < 8; ++nt) {
        int col = nt * 16 + (l & 15);
        float bs = bias[col];
        f4v acc = {bs, bs, bs, bs};
        #pragma unroll
        for (int ks = 0; ks < 4; ++ks) {
            s8v b = *(const s8v*)(Wb + (size_t)col * D_ + ks * 32 + ((l >> 4) * 8));
            acc = __builtin_amdgcn_mfma_f32_16x16x32_bf16(a[ks], b, acc, 0, 0, 0);
        }
        #pragma unroll
        for (int r = 0; r < 4; ++r) {
            int row = t * 16 + (l >> 4) * 4 + r;
            out[(rbase + row) * D_ + col] = f2b(acc[r]);
        }
    }
}

// =====================================================================
// Fused attention + BN1/BN2 stats accumulation.
//  input h is RAW (pending affine ab3 applied on load).
//  t2 = attn(hn) + hn; accumulates sum/sq of (hn+gcn) and t2 into spart.
// =====================================================================
template<int NN, int NG>
__global__ __launch_bounds__(256)
void attn_mfma_kernel(const bf16* __restrict__ h, const float* __restrict__ ab3,
                      const bf16* __restrict__ gcn,
                      const bf16* __restrict__ qwb, const float* __restrict__ qb,
                      const bf16* __restrict__ owb, const float* __restrict__ ob,
                      bf16* __restrict__ out, float* __restrict__ spart)
{
    constexpr int ROWS = NG * NN;
    constexpr int MT = (ROWS + 15) / 16;
    constexpr int QP = 3 * D_ + 8;
    __shared__ short sQKV[MT * 16][QP];
    __shared__ short sP[NG][H_][NN][NN + 1];
    __shared__ short sGCN[NG][128];
    __shared__ float sAB[256];
    __shared__ float sRED[512];

    const int l = TID & 63, wid = TID >> 6;
    const size_t gbase = (size_t)blockIdx.x * ROWS * D_;
    const bf16* hb = h + gbase;

    sAB[TID] = ab3[TID];
    for (int i = TID; i < NG * 128; i += 256)
        sGCN[i >> 7][i & 127] = ((const short*)gcn)[(size_t)blockIdx.x * NG * 128 + i];
    for (int i = TID; i < 512; i += 256) sRED[i] = 0.f;
    __syncthreads();

    // ---------- phase 1: QKV = hn @ qw.T + qb ----------
    s8v a[MT][4];
    #pragma unroll
    for (int t = 0; t < MT; ++t) {
        int row = t * 16 + (l & 15);
        if (row >= ROWS) row = ROWS - 1;
        const bf16* rp = hb + (size_t)row * D_ + ((l >> 4) * 8);
        #pragma unroll
        for (int ks = 0; ks < 4; ++ks) {
            s8v raw = *(const s8v*)(rp + ks * 32);
            s8v af;
            #pragma unroll
            for (int e = 0; e < 8; ++e) {
                int c = ks * 32 + (l >> 4) * 8 + e;
                af[e] = f2s(bfu(raw[e]) * sAB[c] + sAB[128 + c]);
            }
            a[t][ks] = af;
        }
    }
    for (int nt = wid; nt < 24; nt += 4) {
        int col = nt * 16 + (l & 15);
        const bf16* wp = qwb + (size_t)col * D_ + ((l >> 4) * 8);
        s8v b[4];
        #pragma unroll
        for (int ks = 0; ks < 4; ++ks) b[ks] = *(const s8v*)(wp + ks * 32);
        float bs = qb[col];
        #pragma unroll
        for (int t = 0; t < MT; ++t) {
            f4v acc = {bs, bs, bs, bs};
            #pragma unroll
            for (int ks = 0; ks < 4; ++ks)
                acc = __builtin_amdgcn_mfma_f32_16x16x32_bf16(a[t][ks], b[ks], acc, 0, 0, 0);
            #pragma unroll
            for (int r = 0; r < 4; ++r)
                sQKV[t * 16 + (l >> 4) * 4 + r][col] = f2s(acc[r]);
        }
    }
    __syncthreads();

    // ---------- phase 2: scores + softmax -> sP ----------
    const float inv = 0.17677669529663687f;
    for (int task = TID; task < NG * H_ * NN; task += 256) {
        int g = task / (H_ * NN), rem = task % (H_ * NN);
        int hd = rem / NN, i = rem % NN;
        float qv[DH_];
        const short* qp = &sQKV[g * NN + i][hd * DH_];
        #pragma unroll
        for (int v8 = 0; v8 < 4; ++v8) {
            s8v q8 = *(const s8v*)(qp + v8 * 8);
            #pragma unroll
            for (int e = 0; e < 8; ++e) qv[v8 * 8 + e] = bfu(q8[e]);
        }
        float s[NN]; float m = -1e30f;
        #pragma unroll
        for (int j = 0; j < NN; ++j) {
            const short* kp = &sQKV[g * NN + j][D_ + hd * DH_];
            float acc = 0.f;
            #pragma unroll
            for (int v8 = 0; v8 < 4; ++v8) {
                s8v k8 = *(const s8v*)(kp + v8 * 8);
                #pragma unroll
                for (int e = 0; e < 8; ++e) acc += qv[v8 * 8 + e] * bfu(k8[e]);
            }
            s[j] = acc * inv;
            m = fmaxf(m, s[j]);
        }
        float sum = 0.f;
        #pragma unroll
        for (int j = 0; j < NN; ++j) { s[j] = __expf(s[j] - m); sum += s[j]; }
        float rs = 1.f / sum;
        #pragma unroll
        for (int j = 0; j < NN; ++j) sP[g][hd][i][j] = f2s(s[j] * rs);
    }
    __syncthreads();

    // ---------- phase 3: O = P @ V -> overwrite Q slot ----------
    for (int task = TID; task < ROWS * 16; task += 256) {
        int r = task >> 4, c8 = task & 15;
        int g = r / NN, i = r % NN, hd = c8 >> 2;
        float acc[8] = {0,0,0,0,0,0,0,0};
        #pragma unroll
        for (int j = 0; j < NN; ++j) {
            float p = bfu(sP[g][hd][i][j]);
            s8v vv = *(const s8v*)(&sQKV[g * NN + j][2 * D_ + c8 * 8]);
            #pragma unroll
            for (int e = 0; e < 8; ++e) acc[e] += p * bfu(vv[e]);
        }
        s8v ov;
        #pragma unroll
        for (int e = 0; e < 8; ++e) ov[e] = f2s(acc[e]);
        *(s8v*)(&sQKV[r][c8 * 8]) = ov;
    }
    __syncthreads();

    // ---------- phase 4: t2 = O @ ow.T + ob + hn ; stats ----------
    bf16* og = out + gbase;
    #pragma unroll
    for (int t = 0; t < MT; ++t) {
        int row = t * 16 + (l & 15);
        const short* rp = &sQKV[row][(l >> 4) * 8];
        #pragma unroll
        for (int ks = 0; ks < 4; ++ks) a[t][ks] = *(const s8v*)(rp + ks * 32);
    }
    #pragma unroll
    for (int ni = 0; ni < 2; ++ni) {
        int nt = wid + 4 * ni;
        int col = nt * 16 + (l & 15);
        const bf16* wp = owb + (size_t)col * D_ + ((l >> 4) * 8);
        s8v b[4];
        #pragma unroll
        for (int ks = 0; ks < 4; ++ks) b[ks] = *(const s8v*)(wp + ks * 32);
        float bs = ob[col];
        float aa = sAB[col], bb = sAB[128 + col];
        float s1 = 0.f, q1 = 0.f, s2 = 0.f, q2 = 0.f;
        #pragma unroll
        for (int t = 0; t < MT; ++t) {
            f4v acc = {bs, bs, bs, bs};
            #pragma unroll
            for (int ks = 0; ks < 4; ++ks)
                acc = __builtin_amdgcn_mfma_f32_16x16x32_bf16(a[t][ks], b[ks], acc, 0, 0, 0);
            #pragma unroll
            for (int r = 0; r < 4; ++r) {
                int row = t * 16 + (l >> 4) * 4 + r;
                if (row < ROWS) {
                    float res = b2f(hb[(size_t)row * D_ + col]) * aa + bb;
                    float t2v = acc[r] + res;
                    og[(size_t)row * D_ + col] = f2b(t2v);
                    s2 += t2v; q2 += t2v * t2v;
                    int g = row / NN;
                    float x1 = res + bfu(sGCN[g][col]);
                    s1 += x1; q1 += x1 * x1;
                }
            }
        }
        atomicAdd(&sRED[col], s1);
        atomicAdd(&sRED[128 + col], q1);
        atomicAdd(&sRED[256 + col], s2);
        atomicAdd(&sRED[384 + col], q2);
    }
    __syncthreads();
    {
        int slot = blockIdx.x & (NSLOT - 1);
        for (int i = TID; i < 512; i += 256) atomicAdd(&spart[slot * 512 + i], sRED[i]);
    }
}

// =====================================================================
// finalize BN1+BN2: reduce 32 partial slots -> affine (A1,B1,A2,B2); re-zero
// =====================================================================
__global__ __launch_bounds__(128)
void finalize12_kernel(float* __restrict__ spart, const float* __restrict__ bng,
                       const float* __restrict__ bnb, float rcount,
                       float* __restrict__ ab12)
{
    int c = TID;
    float s1 = 0, q1 = 0, s2 = 0, q2 = 0;
    for (int s = 0; s < NSLOT; ++s) {
        float* p = spart + s * 512;
        s1 += p[c]; q1 += p[128 + c]; s2 += p[256 + c]; q2 += p[384 + c];
        p[c] = 0.f; p[128 + c] = 0.f; p[256 + c] = 0.f; p[384 + c] = 0.f;
    }
    float m1 = s1 * rcount, v1 = q1 * rcount - m1 * m1;
    float a1 = rsqrtf(v1 + EPS_) * bng[c];
    ab12[c] = a1; ab12[128 + c] = bnb[c] - m1 * a1;
    float m2 = s2 * rcount, v2 = q2 * rcount - m2 * m2;
    float a2 = rsqrtf(v2 + EPS_) * bng[128 + c];
    ab12[256 + c] = a2; ab12[384 + c] = bnb[128 + c] - m2 * a2;
}

// finalize BN3 -> ab3 (consumed lazily next layer); re-zero partials
__global__ __launch_bounds__(128)
void finalize3_kernel(float* __restrict__ spart, const float* __restrict__ gamma,
                      const float* __restrict__ beta, float rcount,
                      float* __restrict__ ab3)
{
    int c = TID;
    float s1 = 0, q1 = 0;
    for (int s = 0; s < NSLOT; ++s) {
        float* p = spart + s * 256;
        s1 += p[c]; q1 += p[128 + c];
        p[c] = 0.f; p[128 + c] = 0.f;
    }
    float m = s1 * rcount, v = q1 * rcount - m * m;
    float a = rsqrtf(v + EPS_) * gamma[c];
    ab3[c] = a; ab3[128 + c] = beta[c] - m * a;
}

// =====================================================================
// Fused MLP with BN1/BN2 apply on load + BN3 stats:
//   out = A1*(hn+gcn)+B1 + A2*t2+B2   (hn = A3*X+B3)
//   X   = out + relu(out@w1.T+b1)@w2.T + b2   (raw; BN3 deferred via ab3)
// =====================================================================
__global__ __launch_bounds__(256)
void mlp_mfma_kernel(bf16* __restrict__ X, const float* __restrict__ ab3,
                     const bf16* __restrict__ gcn, const bf16* __restrict__ t2,
                     const float* __restrict__ ab12,
                     const bf16* __restrict__ w1b, const float* __restrict__ b1,
                     const bf16* __restrict__ w2b, const float* __restrict__ b2,
                     int n, float* __restrict__ spart3)
{
    constexpr int MP = 264;
    __shared__ short sM[64][MP];
    __shared__ short sOUT[64][136];
    __shared__ float sAB[768];       // [0:256]=ab3, [256:768]=ab12
    __shared__ float sRED[256];
    const int l = TID & 63, wid = TID >> 6;
    const size_t rbase = (size_t)blockIdx.x * 64;
    bf16* Xb = X + rbase * D_;
    const bf16* Tb = t2 + rbase * D_;

    sAB[TID] = ab3[TID];
    for (int i = TID; i < 512; i += 256) sAB[256 + i] = ab12[i];
    sRED[TID] = 0.f;
    __syncthreads();

    // phase 0: build out-frags (+ stage out in LDS)
    s8v a[4][4];
    #pragma unroll
    for (int t = 0; t < 4; ++t) {
        int row = t * 16 + (l & 15);
        int g = (int)((rbase + row) / n);
        #pragma unroll
        for (int ks = 0; ks < 4; ++ks) {
            int cb = ks * 32 + (l >> 4) * 8;
            s8v xv = *(const s8v*)(Xb + (size_t)row * D_ + cb);
            s8v gv = *(const s8v*)(gcn + (size_t)g * D_ + cb);
            s8v tv = *(const s8v*)(Tb + (size_t)row * D_ + cb);
            s8v af;
            #pragma unroll
            for (int e = 0; e < 8; ++e) {
                int c = cb + e;
                float hn = bfu(xv[e]) * sAB[c] + sAB[128 + c];
                float outv = (hn + bfu(gv[e])) * sAB[256 + c] + sAB[384 + c]
                           + bfu(tv[e]) * sAB[512 + c] + sAB[640 + c];
                af[e] = f2s(outv);
            }
            a[t][ks] = af;
            *(s8v*)(&sOUT[row][cb]) = af;   // all waves write same value (benign)
        }
    }

    // phase 1: M = relu(out @ w1.T + b1)
    for (int nt = wid; nt < 16; nt += 4) {
        int col = nt * 16 + (l & 15);
        const bf16* wp = w1b + (size_t)col * D_ + ((l >> 4) * 8);
        s8v b[4];
        #pragma unroll
        for (int ks = 0; ks < 4; ++ks) b[ks] = *(const s8v*)(wp + ks * 32);
        float bs = b1[col];
        #pragma unroll
        for (int t = 0; t < 4; ++t) {
            f4v acc = {bs, bs, bs, bs};
            #pragma unroll
            for (int ks = 0; ks < 4; ++ks)
                acc = __builtin_amdgcn_mfma_f32_16x16x32_bf16(a[t][ks], b[ks], acc, 0, 0, 0);
            #pragma unroll
            for (int r = 0; r < 4; ++r)
                sM[t * 16 + (l >> 4) * 4 + r][col] = f2s(fmaxf(acc[r], 0.f));
        }
    }
    __syncthreads();

    // phase 2: X = out + M @ w2.T + b2 ; stats3
    {
        const int t = wid;
        s8v am[8];
        const short* rp = &sM[t * 16 + (l & 15)][(l >> 4) * 8];
        #pragma unroll
        for (int ks = 0; ks < 8; ++ks) am[ks] = *(const s8v*)(rp + ks * 32);
        for (int nt = 0; nt < 8; ++nt) {
            int col = nt * 16 + (l & 15);
            float bs = b2[col];
            f4v acc = {bs, bs, bs, bs};
            #pragma unroll
            for (int ks = 0; ks < 8; ++ks) {
                s8v b = *(const s8v*)(w2b + (size_t)col * 256 + ks * 32 + ((l >> 4) * 8));
                acc = __builtin_amdgcn_mfma_f32_16x16x32_bf16(am[ks], b, acc, 0, 0, 0);
            }
            float ss = 0.f, qq = 0.f;
            #pragma unroll
            for (int r = 0; r < 4; ++r) {
                int row = t * 16 + (l >> 4) * 4 + r;
                float xn = acc[r] + bfu(sOUT[row][col]);
                Xb[(size_t)row * D_ + col] = f2b(xn);
                ss += xn; qq += xn * xn;
            }
            atomicAdd(&sRED[col], ss);
            atomicAdd(&sRED[128 + col], qq);
        }
    }
    __syncthreads();
    {
        int slot = blockIdx.x & (NSLOT - 1);
        atomicAdd(&spart3[slot * 256 + TID], sRED[TID]);
    }
}

// =====================================================================
// Final pooling (with pending ab3 affine) + classifier
// =====================================================================
__global__ __launch_bounds__(128)
void poolcls_kernel(const bf16* __restrict__ gi, const float* __restrict__ ab,
                    const float* __restrict__ cw, const float* __restrict__ cb,
                    float* __restrict__ out)
{
    __shared__ float sP[128];
    int b = blockIdx.x, d = TID;
    const bf16* p = gi + (size_t)b * TN_ * D_ + d;
    float s = 0.f;
    for (int i = 0; i < TN_; ++i) s += b2f(p[i * D_]);
    sP[d] = (s * (1.f / TN_)) * ab[d] + ab[128 + d];
    __syncthreads();
    if (d < C_) {
        float acc = cb[d];
        for (int k = 0; k < D_; ++k) acc += sP[k] * cw[d * D_ + k];
        out[b * C_ + d] = acc;
    }
}

// =====================================================================
extern "C" void kernel_launch(void* const* d_in, const int* in_sizes, int n_in,
                              void* d_out, int out_size, void* d_ws, size_t ws_size,
                              hipStream_t stream)
{
    (void)in_sizes; (void)n_in; (void)out_size; (void)ws_size;

    const float* poses = (const float*)d_in[0];
    const float* emb_w = (const float*)d_in[1];
    const float* emb_b = (const float*)d_in[2];
    const float* cls_w = (const float*)d_in[3];
    const float* cls_b = (const float*)d_in[4];
    const float* jp[12]; const float* ip[12];
    for (int k = 0; k < 12; ++k) { jp[k] = (const float*)d_in[5 + k]; ip[k] = (const float*)d_in[17 + k]; }

    // ---- workspace layout ----
    char* base = (char*)d_ws;
    size_t off = 0;
    auto alloc_b = [&](size_t elems) -> bf16* {
        bf16* p = (bf16*)(base + off);
        off = (off + elems * sizeof(bf16) + 255) & ~(size_t)255;
        return p;
    };
    bf16* bufA  = alloc_b((size_t)R1_ * D_);
    bf16* bufB  = alloc_b((size_t)R1_ * D_);
    bf16* hbarJ = alloc_b((size_t)G1_ * D_);
    bf16* gcn1  = alloc_b((size_t)G1_ * D_);
    bf16* hbar2 = alloc_b((size_t)G2_ * D_);
    bf16* gcn2  = alloc_b((size_t)G2_ * D_);
    float* spart12 = (float*)(base + off); off += NSLOT * 512 * 4;
    float* spart3  = (float*)(base + off); off += NSLOT * 256 * 4;
    float* ab3     = (float*)(base + off); off += 256 * 4;
    float* ab12    = (float*)(base + off); off = (off + 512 * 4 + 255) & ~(size_t)255;
    bf16* wb[2][5];
    const int wsz[5] = {3 * D_ * D_, 3 * 3 * D_ * D_, 3 * D_ * D_, 3 * 2 * D_ * D_, 3 * 2 * D_ * D_};
    for (int s = 0; s < 2; ++s)
        for (int k = 0; k < 5; ++k) wb[s][k] = alloc_b((size_t)wsz[k]);

    const int widx[5] = {0, 2, 4, 8, 10};
    for (int s = 0; s < 2; ++s) {
        const float** P = s ? ip : jp;
        for (int k = 0; k < 5; ++k)
            wconv_kernel<<<(wsz[k] + 4095) / 4096, 256, 0, stream>>>(P[widx[k]], wb[s][k], wsz[k]);
    }
    zero_kernel<<<24, 256, 0, stream>>>(spart12, NSLOT * 512 + NSLOT * 256);

    embedv_kernel<<<4096, 256, 0, stream>>>(poses, emb_w, emb_b, bufA, R1_);

    auto run_stage = [&](const float** P, const bf16* const* W, bf16* h, bf16* t2,
                         bf16* hbar, bf16* gcn, int G, int n, int R) {
        setid_kernel<<<1, 128, 0, stream>>>(ab3);
        for (int L = 0; L < 3; ++L) {
            const bf16* gwb = W[0] + (size_t)L * D_ * D_;
            const bf16* qwb = W[1] + (size_t)L * 3 * D_ * D_;
            const bf16* owb = W[2] + (size_t)L * D_ * D_;
            const bf16* w1b = W[3] + (size_t)L * 2 * D_ * D_;
            const bf16* w2b = W[4] + (size_t)L * 2 * D_ * D_;
            const float* gb  = P[1] + (size_t)L * D_;
            const float* qb  = P[3] + (size_t)L * 3 * D_;
            const float* ob  = P[5] + (size_t)L * D_;
            const float* bng = P[6] + (size_t)L * 3 * D_;
            const float* bnb = P[7] + (size_t)L * 3 * D_;
            const float* b1  = P[9] + (size_t)L * 2 * D_;
            const float* b2  = P[11] + (size_t)L * D_;
            float rcount = 1.f / (float)R;

            gmeanv_kernel<<<G * 16 / 256, 256, 0, stream>>>(h, ab3, hbar, G, n);
            linear64_kernel<<<G / 64, 256, 0, stream>>>(hbar, gwb, gb, gcn);
            if (n == J_)
                attn_mfma_kernel<J_, 3><<<G / 3, 256, 0, stream>>>(h, ab3, gcn, qwb, qb, owb, ob, t2, spart12);
            else
                attn_mfma_kernel<NI_, 4><<<G / 4, 256, 0, stream>>>(h, ab3, gcn, qwb, qb, owb, ob, t2, spart12);
            finalize12_kernel<<<1, 128, 0, stream>>>(spart12, bng, bnb, rcount, ab12);
            mlp_mfma_kernel<<<R / 64, 256, 0, stream>>>(h, ab3, gcn, t2, ab12,
                                                        w1b, b1, w2b, b2, n, spart3);
            finalize3_kernel<<<1, 128, 0, stream>>>(spart3, bng + 2 * D_, bnb + 2 * D_,
                                                    rcount, ab3);
        }
    };

    // joint stage (h raw in bufA; ab3 carries pending BN3 between layers)
    run_stage(jp, wb[0], bufA, bufB, hbarJ, gcn1, G1_, J_, R1_);
    // joint -> individual pooling (applies joint-final ab3 after the mean)
    gmeanv_kernel<<<G1_ * 16 / 256, 256, 0, stream>>>(bufA, ab3, hbarJ, G1_, J_);
    // individual stage
    run_stage(ip, wb[1], hbarJ, bufB, hbar2, gcn2, G2_, NI_, R2_);
    // final pooling (pending ind-final ab3) + classifier
    poolcls_kernel<<<B_, 128, 0, stream>>>(hbarJ, ab3, cls_w, cls_b, (float*)d_out);
}

// Round 8
// 1828.516 us; speedup vs baseline: 13.2376x; 1.3403x over previous
//
#include <hip/hip_runtime.h>
#include <hip/hip_bf16.h>

#define TID threadIdx.x

typedef __hip_bfloat16 bf16;
typedef short s8v __attribute__((ext_vector_type(8)));
typedef float f4v __attribute__((ext_vector_type(4)));

__device__ __forceinline__ float b2f(bf16 x) { return __bfloat162float(x); }
__device__ __forceinline__ bf16  f2b(float x) { return __float2bfloat16(x); }
__device__ __forceinline__ short f2s(float x) {
    __hip_bfloat16 b = __float2bfloat16(x); short s; __builtin_memcpy(&s, &b, 2); return s;
}
__device__ __forceinline__ float bfu(short s) {
    unsigned u = ((unsigned)(unsigned short)s) << 16; float f; __builtin_memcpy(&f, &u, 4); return f;
}

// ---- problem constants ----
#define B_   256
#define T_   7
#define NI_  12
#define TN_  84
#define J_   17
#define D_   128
#define H_   4
#define DH_  32
#define C_   8
#define G1_  21504       // B_*TN_
#define R1_  365568      // G1_*J_
#define G2_  1792        // B_*T_
#define R2_  21504       // G2_*NI_
#define EPS_ 1e-5f
#define NSLOT 32

// =====================================================================
__global__ __launch_bounds__(256)
void zero_kernel(float* __restrict__ p, int n)
{
    int stride = gridDim.x * 256;
    for (int i = blockIdx.x * 256 + TID; i < n; i += stride) p[i] = 0.f;
}

__global__ __launch_bounds__(128)
void setid_kernel(float* __restrict__ ab)
{
    ab[TID] = 1.f; ab[128 + TID] = 0.f;
}

// fp32 -> bf16 weight conversion
__global__ __launch_bounds__(256)
void wconv_kernel(const float* __restrict__ src, bf16* __restrict__ dst, int n)
{
    int stride = gridDim.x * 256;
    for (int i = blockIdx.x * 256 + TID; i < n; i += stride) dst[i] = f2b(src[i]);
}

// =====================================================================
// Embedding: h = leaky_relu(poses @ ew.T + eb)  (raw, no pending BN)
// =====================================================================
__global__ __launch_bounds__(256)
void embedv_kernel(const float* __restrict__ poses, const float* __restrict__ ew,
                   const float* __restrict__ eb, bf16* __restrict__ h, int R)
{
    __shared__ float sE0[128], sE1[128], sEb[128];
    if (TID < 128) { sE0[TID] = ew[2 * TID]; sE1[TID] = ew[2 * TID + 1]; sEb[TID] = eb[TID]; }
    __syncthreads();
    int stride = gridDim.x * 256;
    for (int i8 = blockIdx.x * 256 + TID; i8 < R * 16; i8 += stride) {
        int r = i8 >> 4, c8 = (i8 & 15) * 8;
        float p0 = poses[2 * r], p1 = poses[2 * r + 1];
        s8v o;
        #pragma unroll
        for (int e = 0; e < 8; ++e) {
            int c = c8 + e;
            float v = p0 * sE0[c] + p1 * sE1[c] + sEb[c];
            o[e] = f2s(v > 0.f ? v : 0.01f * v);
        }
        *(s8v*)(h + (size_t)r * D_ + c8) = o;
    }
}

// =====================================================================
// Per-graph mean with pending-BN affine applied after the (linear) mean
// =====================================================================
__global__ __launch_bounds__(256)
void gmeanv_kernel(const bf16* __restrict__ h, const float* __restrict__ ab,
                   bf16* __restrict__ hbar, int G, int n)
{
    int i8 = blockIdx.x * 256 + TID;
    if (i8 >= G * 16) return;
    int g = i8 >> 4, c8 = (i8 & 15) * 8;
    const bf16* p = h + (size_t)g * n * D_ + c8;
    float acc[8] = {0,0,0,0,0,0,0,0};
    for (int j = 0; j < n; ++j) {
        s8v v = *(const s8v*)(p + j * D_);
        #pragma unroll
        for (int e = 0; e < 8; ++e) acc[e] += bfu(v[e]);
    }
    float rn = 1.f / n;
    s8v o;
    #pragma unroll
    for (int e = 0; e < 8; ++e) {
        int c = c8 + e;
        o[e] = f2s(acc[e] * rn * ab[c] + ab[128 + c]);
    }
    *(s8v*)(hbar + (size_t)g * D_ + c8) = o;
}

// =====================================================================
// linear64: out[r,:] = X[r,:] @ W.T + bias   (64 rows/block, MFMA)
// =====================================================================
__global__ __launch_bounds__(256)
void linear64_kernel(const bf16* __restrict__ X, const bf16* __restrict__ Wb,
                     const float* __restrict__ bias, bf16* __restrict__ out)
{
    const int l = TID & 63, wid = TID >> 6;
    const size_t rbase = (size_t)blockIdx.x * 64;
    const int t = wid;
    const int arow = t * 16 + (l & 15);
    s8v a[4];
    #pragma unroll
    for (int ks = 0; ks < 4; ++ks)
        a[ks] = *(const s8v*)(X + (rbase + arow) * D_ + ks * 32 + ((l >> 4) * 8));
    for (int nt = 0; nt < 8; ++nt) {
        int col = nt * 16 + (l & 15);
        float bs = bias[col];
        f4v acc = {bs, bs, bs, bs};
        #pragma unroll
        for (int ks = 0; ks < 4; ++ks) {
            s8v b = *(const s8v*)(Wb + (size_t)col * D_ + ks * 32 + ((l >> 4) * 8));
            acc = __builtin_amdgcn_mfma_f32_16x16x32_bf16(a[ks], b, acc, 0, 0, 0);
        }
        #pragma unroll
        for (int r = 0; r < 4; ++r) {
            int row = t * 16 + (l >> 4) * 4 + r;
            out[(rbase + row) * D_ + col] = f2b(acc[r]);
        }
    }
}

// =====================================================================
// Fused attention + BN1/BN2 stats. hn staged ONCE in LDS (de-dup).
// =====================================================================
template<int NN, int NG>
__global__ __launch_bounds__(256)
void attn_mfma_kernel(const bf16* __restrict__ h, const float* __restrict__ ab3,
                      const bf16* __restrict__ gcn,
                      const bf16* __restrict__ qwb, const float* __restrict__ qb,
                      const bf16* __restrict__ owb, const float* __restrict__ ob,
                      bf16* __restrict__ out, float* __restrict__ spart)
{
    constexpr int ROWS = NG * NN;
    constexpr int MT = (ROWS + 15) / 16;
    constexpr int QP = 3 * D_ + 8;
    __shared__ short sQKV[MT * 16][QP];
    __shared__ short sHN[ROWS][136];
    __shared__ short sP[NG][H_][NN][NN + 1];
    __shared__ short sGCN[NG][128];
    __shared__ float sAB[256];
    __shared__ float sRED[512];

    const int l = TID & 63, wid = TID >> 6;
    const size_t gbase = (size_t)blockIdx.x * ROWS * D_;
    const bf16* hb = h + gbase;

    sAB[TID] = ab3[TID];
    for (int i = TID; i < NG * 128; i += 256)
        sGCN[i >> 7][i & 127] = ((const short*)gcn)[(size_t)blockIdx.x * NG * 128 + i];
    for (int i = TID; i < 512; i += 256) sRED[i] = 0.f;
    __syncthreads();

    // ---------- phase 0: hn = affine(h) -> sHN (cooperative, no dup) ----------
    for (int task = TID; task < ROWS * 16; task += 256) {
        int row = task >> 4, c8 = (task & 15) * 8;
        s8v raw = *(const s8v*)(hb + (size_t)row * D_ + c8);
        s8v af;
        #pragma unroll
        for (int e = 0; e < 8; ++e) {
            int c = c8 + e;
            af[e] = f2s(bfu(raw[e]) * sAB[c] + sAB[128 + c]);
        }
        *(s8v*)(&sHN[row][c8]) = af;
    }
    __syncthreads();

    // ---------- phase 1: QKV = hn @ qw.T + qb (A-frags from LDS) ----------
    s8v a[MT][4];
    #pragma unroll
    for (int t = 0; t < MT; ++t) {
        int row = t * 16 + (l & 15);
        if (row >= ROWS) row = ROWS - 1;
        const short* rp = &sHN[row][(l >> 4) * 8];
        #pragma unroll
        for (int ks = 0; ks < 4; ++ks) a[t][ks] = *(const s8v*)(rp + ks * 32);
    }
    for (int nt = wid; nt < 24; nt += 4) {
        int col = nt * 16 + (l & 15);
        const bf16* wp = qwb + (size_t)col * D_ + ((l >> 4) * 8);
        s8v b[4];
        #pragma unroll
        for (int ks = 0; ks < 4; ++ks) b[ks] = *(const s8v*)(wp + ks * 32);
        float bs = qb[col];
        #pragma unroll
        for (int t = 0; t < MT; ++t) {
            f4v acc = {bs, bs, bs, bs};
            #pragma unroll
            for (int ks = 0; ks < 4; ++ks)
                acc = __builtin_amdgcn_mfma_f32_16x16x32_bf16(a[t][ks], b[ks], acc, 0, 0, 0);
            #pragma unroll
            for (int r = 0; r < 4; ++r)
                sQKV[t * 16 + (l >> 4) * 4 + r][col] = f2s(acc[r]);
        }
    }
    __syncthreads();

    // ---------- phase 2: scores + softmax -> sP ----------
    const float inv = 0.17677669529663687f;
    for (int task = TID; task < NG * H_ * NN; task += 256) {
        int g = task / (H_ * NN), rem = task % (H_ * NN);
        int hd = rem / NN, i = rem % NN;
        float qv[DH_];
        const short* qp = &sQKV[g * NN + i][hd * DH_];
        #pragma unroll
        for (int v8 = 0; v8 < 4; ++v8) {
            s8v q8 = *(const s8v*)(qp + v8 * 8);
            #pragma unroll
            for (int e = 0; e < 8; ++e) qv[v8 * 8 + e] = bfu(q8[e]);
        }
        float s[NN]; float m = -1e30f;
        #pragma unroll
        for (int j = 0; j < NN; ++j) {
            const short* kp = &sQKV[g * NN + j][D_ + hd * DH_];
            float acc = 0.f;
            #pragma unroll
            for (int v8 = 0; v8 < 4; ++v8) {
                s8v k8 = *(const s8v*)(kp + v8 * 8);
                #pragma unroll
                for (int e = 0; e < 8; ++e) acc += qv[v8 * 8 + e] * bfu(k8[e]);
            }
            s[j] = acc * inv;
            m = fmaxf(m, s[j]);
        }
        float sum = 0.f;
        #pragma unroll
        for (int j = 0; j < NN; ++j) { s[j] = __expf(s[j] - m); sum += s[j]; }
        float rs = 1.f / sum;
        #pragma unroll
        for (int j = 0; j < NN; ++j) sP[g][hd][i][j] = f2s(s[j] * rs);
    }
    __syncthreads();

    // ---------- phase 3: O = P @ V -> overwrite Q slot ----------
    for (int task = TID; task < ROWS * 16; task += 256) {
        int r = task >> 4, c8 = task & 15;
        int g = r / NN, i = r % NN, hd = c8 >> 2;
        float acc[8] = {0,0,0,0,0,0,0,0};
        #pragma unroll
        for (int j = 0; j < NN; ++j) {
            float p = bfu(sP[g][hd][i][j]);
            s8v vv = *(const s8v*)(&sQKV[g * NN + j][2 * D_ + c8 * 8]);
            #pragma unroll
            for (int e = 0; e < 8; ++e) acc[e] += p * bfu(vv[e]);
        }
        s8v ov;
        #pragma unroll
        for (int e = 0; e < 8; ++e) ov[e] = f2s(acc[e]);
        *(s8v*)(&sQKV[r][c8 * 8]) = ov;
    }
    __syncthreads();

    // ---------- phase 4: t2 = O @ ow.T + ob + hn ; stats (res from LDS) ----------
    bf16* og = out + gbase;
    #pragma unroll
    for (int t = 0; t < MT; ++t) {
        int row = t * 16 + (l & 15);
        const short* rp = &sQKV[row][(l >> 4) * 8];
        #pragma unroll
        for (int ks = 0; ks < 4; ++ks) a[t][ks] = *(const s8v*)(rp + ks * 32);
    }
    #pragma unroll
    for (int ni = 0; ni < 2; ++ni) {
        int nt = wid + 4 * ni;
        int col = nt * 16 + (l & 15);
        const bf16* wp = owb + (size_t)col * D_ + ((l >> 4) * 8);
        s8v b[4];
        #pragma unroll
        for (int ks = 0; ks < 4; ++ks) b[ks] = *(const s8v*)(wp + ks * 32);
        float bs = ob[col];
        float s1 = 0.f, q1 = 0.f, s2 = 0.f, q2 = 0.f;
        #pragma unroll
        for (int t = 0; t < MT; ++t) {
            f4v acc = {bs, bs, bs, bs};
            #pragma unroll
            for (int ks = 0; ks < 4; ++ks)
                acc = __builtin_amdgcn_mfma_f32_16x16x32_bf16(a[t][ks], b[ks], acc, 0, 0, 0);
            #pragma unroll
            for (int r = 0; r < 4; ++r) {
                int row = t * 16 + (l >> 4) * 4 + r;
                if (row < ROWS) {
                    float res = bfu(sHN[row][col]);
                    float t2v = acc[r] + res;
                    og[(size_t)row * D_ + col] = f2b(t2v);
                    s2 += t2v; q2 += t2v * t2v;
                    int g = row / NN;
                    float x1 = res + bfu(sGCN[g][col]);
                    s1 += x1; q1 += x1 * x1;
                }
            }
        }
        atomicAdd(&sRED[col], s1);
        atomicAdd(&sRED[128 + col], q1);
        atomicAdd(&sRED[256 + col], s2);
        atomicAdd(&sRED[384 + col], q2);
    }
    __syncthreads();
    {
        int slot = blockIdx.x & (NSLOT - 1);
        for (int i = TID; i < 512; i += 256) atomicAdd(&spart[slot * 512 + i], sRED[i]);
    }
}

// =====================================================================
// finalize BN1+BN2: reduce partial slots -> affine; re-zero
// =====================================================================
__global__ __launch_bounds__(128)
void finalize12_kernel(float* __restrict__ spart, const float* __restrict__ bng,
                       const float* __restrict__ bnb, float rcount,
                       float* __restrict__ ab12)
{
    int c = TID;
    float s1 = 0, q1 = 0, s2 = 0, q2 = 0;
    for (int s = 0; s < NSLOT; ++s) {
        float* p = spart + s * 512;
        s1 += p[c]; q1 += p[128 + c]; s2 += p[256 + c]; q2 += p[384 + c];
        p[c] = 0.f; p[128 + c] = 0.f; p[256 + c] = 0.f; p[384 + c] = 0.f;
    }
    float m1 = s1 * rcount, v1 = q1 * rcount - m1 * m1;
    float a1 = rsqrtf(v1 + EPS_) * bng[c];
    ab12[c] = a1; ab12[128 + c] = bnb[c] - m1 * a1;
    float m2 = s2 * rcount, v2 = q2 * rcount - m2 * m2;
    float a2 = rsqrtf(v2 + EPS_) * bng[128 + c];
    ab12[256 + c] = a2; ab12[384 + c] = bnb[128 + c] - m2 * a2;
}

// finalize BN3 -> ab3; re-zero partials
__global__ __launch_bounds__(128)
void finalize3_kernel(float* __restrict__ spart, const float* __restrict__ gamma,
                      const float* __restrict__ beta, float rcount,
                      float* __restrict__ ab3)
{
    int c = TID;
    float s1 = 0, q1 = 0;
    for (int s = 0; s < NSLOT; ++s) {
        float* p = spart + s * 256;
        s1 += p[c]; q1 += p[128 + c];
        p[c] = 0.f; p[128 + c] = 0.f;
    }
    float m = s1 * rcount, v = q1 * rcount - m * m;
    float a = rsqrtf(v + EPS_) * gamma[c];
    ab3[c] = a; ab3[128 + c] = beta[c] - m * a;
}

// =====================================================================
// Fused MLP v2 — de-duplicated loads:
//  phase 0: 256 threads cooperatively build out = BN1(hn+gcn)+BN2(t2) -> sOUT
//  phase 1: A-frags from LDS; wave owns 4 of 16 hidden col-tiles (w1 1x/block)
//  phase 2: wave owns 2 of 8 output col-tiles (w2 1x/block), M-frags from sM
// =====================================================================
__global__ __launch_bounds__(256)
void mlp_mfma_kernel(bf16* __restrict__ X, const float* __restrict__ ab3,
                     const bf16* __restrict__ gcn, const bf16* __restrict__ t2,
                     const float* __restrict__ ab12,
                     const bf16* __restrict__ w1b, const float* __restrict__ b1,
                     const bf16* __restrict__ w2b, const float* __restrict__ b2,
                     int n, float* __restrict__ spart3)
{
    constexpr int MP = 264;
    __shared__ short sM[64][MP];
    __shared__ short sOUT[64][136];
    __shared__ float sAB[768];       // [0:256]=ab3, [256:768]=ab12
    __shared__ float sRED[256];
    const int l = TID & 63, wid = TID >> 6;
    const size_t rbase = (size_t)blockIdx.x * 64;
    bf16* Xb = X + rbase * D_;
    const bf16* Tb = t2 + rbase * D_;

    sAB[TID] = ab3[TID];
    for (int i = TID; i < 512; i += 256) sAB[256 + i] = ab12[i];
    sRED[TID] = 0.f;
    __syncthreads();

    // phase 0: cooperative build of out -> sOUT (each thread: 1 row, 32 cols)
    {
        int row = TID >> 2;
        int cb0 = (TID & 3) * 32;
        int g = (int)((rbase + row) / n);
        #pragma unroll
        for (int k2 = 0; k2 < 4; ++k2) {
            int cb = cb0 + k2 * 8;
            s8v xv = *(const s8v*)(Xb + (size_t)row * D_ + cb);
            s8v gv = *(const s8v*)(gcn + (size_t)g * D_ + cb);
            s8v tv = *(const s8v*)(Tb + (size_t)row * D_ + cb);
            s8v af;
            #pragma unroll
            for (int e = 0; e < 8; ++e) {
                int c = cb + e;
                float hn = bfu(xv[e]) * sAB[c] + sAB[128 + c];
                float outv = (hn + bfu(gv[e])) * sAB[256 + c] + sAB[384 + c]
                           + bfu(tv[e]) * sAB[512 + c] + sAB[640 + c];
                af[e] = f2s(outv);
            }
            *(s8v*)(&sOUT[row][cb]) = af;
        }
    }
    __syncthreads();

    // phase 1: M = relu(out @ w1.T + b1); A-frags from sOUT
    s8v a[4][4];
    #pragma unroll
    for (int t = 0; t < 4; ++t) {
        const short* rp = &sOUT[t * 16 + (l & 15)][(l >> 4) * 8];
        #pragma unroll
        for (int ks = 0; ks < 4; ++ks) a[t][ks] = *(const s8v*)(rp + ks * 32);
    }
    for (int nt = wid; nt < 16; nt += 4) {
        int col = nt * 16 + (l & 15);
        const bf16* wp = w1b + (size_t)col * D_ + ((l >> 4) * 8);
        s8v b[4];
        #pragma unroll
        for (int ks = 0; ks < 4; ++ks) b[ks] = *(const s8v*)(wp + ks * 32);
        float bs = b1[col];
        #pragma unroll
        for (int t = 0; t < 4; ++t) {
            f4v acc = {bs, bs, bs, bs};
            #pragma unroll
            for (int ks = 0; ks < 4; ++ks)
                acc = __builtin_amdgcn_mfma_f32_16x16x32_bf16(a[t][ks], b[ks], acc, 0, 0, 0);
            #pragma unroll
            for (int r = 0; r < 4; ++r)
                sM[t * 16 + (l >> 4) * 4 + r][col] = f2s(fmaxf(acc[r], 0.f));
        }
    }
    __syncthreads();

    // phase 2: X = out + M @ w2.T + b2 ; stats3. Wave owns 2 col-tiles.
    {
        const int nt0 = wid * 2;
        const int col0 = nt0 * 16 + (l & 15), col1 = col0 + 16;
        s8v b0[8], b1v[8];
        #pragma unroll
        for (int ks = 0; ks < 8; ++ks) {
            b0[ks]  = *(const s8v*)(w2b + (size_t)col0 * 256 + ks * 32 + ((l >> 4) * 8));
            b1v[ks] = *(const s8v*)(w2b + (size_t)col1 * 256 + ks * 32 + ((l >> 4) * 8));
        }
        float bs0 = b2[col0], bs1 = b2[col1];
        float ss0 = 0.f, qq0 = 0.f, ss1 = 0.f, qq1 = 0.f;
        #pragma unroll
        for (int t = 0; t < 4; ++t) {
            s8v am[8];
            const short* rp = &sM[t * 16 + (l & 15)][(l >> 4) * 8];
            #pragma unroll
            for (int ks = 0; ks < 8; ++ks) am[ks] = *(const s8v*)(rp + ks * 32);
            f4v acc0 = {bs0, bs0, bs0, bs0};
            f4v acc1 = {bs1, bs1, bs1, bs1};
            #pragma unroll
            for (int ks = 0; ks < 8; ++ks) {
                acc0 = __builtin_amdgcn_mfma_f32_16x16x32_bf16(am[ks], b0[ks], acc0, 0, 0, 0);
                acc1 = __builtin_amdgcn_mfma_f32_16x16x32_bf16(am[ks], b1v[ks], acc1, 0, 0, 0);
            }
            #pragma unroll
            for (int r = 0; r < 4; ++r) {
                int row = t * 16 + (l >> 4) * 4 + r;
                float xn0 = acc0[r] + bfu(sOUT[row][col0]);
                float xn1 = acc1[r] + bfu(sOUT[row][col1]);
                Xb[(size_t)row * D_ + col0] = f2b(xn0);
                Xb[(size_t)row * D_ + col1] = f2b(xn1);
                ss0 += xn0; qq0 += xn0 * xn0;
                ss1 += xn1; qq1 += xn1 * xn1;
            }
        }
        atomicAdd(&sRED[col0], ss0); atomicAdd(&sRED[128 + col0], qq0);
        atomicAdd(&sRED[col1], ss1); atomicAdd(&sRED[128 + col1], qq1);
    }
    __syncthreads();
    {
        int slot = blockIdx.x & (NSLOT - 1);
        atomicAdd(&spart3[slot * 256 + TID], sRED[TID]);
    }
}

// =====================================================================
// Final pooling (with pending ab3 affine) + classifier
// =====================================================================
__global__ __launch_bounds__(128)
void poolcls_kernel(const bf16* __restrict__ gi, const float* __restrict__ ab,
                    const float* __restrict__ cw, const float* __restrict__ cb,
                    float* __restrict__ out)
{
    __shared__ float sP[128];
    int b = blockIdx.x, d = TID;
    const bf16* p = gi + (size_t)b * TN_ * D_ + d;
    float s = 0.f;
    for (int i = 0; i < TN_; ++i) s += b2f(p[i * D_]);
    sP[d] = (s * (1.f / TN_)) * ab[d] + ab[128 + d];
    __syncthreads();
    if (d < C_) {
        float acc = cb[d];
        for (int k = 0; k < D_; ++k) acc += sP[k] * cw[d * D_ + k];
        out[b * C_ + d] = acc;
    }
}

// =====================================================================
extern "C" void kernel_launch(void* const* d_in, const int* in_sizes, int n_in,
                              void* d_out, int out_size, void* d_ws, size_t ws_size,
                              hipStream_t stream)
{
    (void)in_sizes; (void)n_in; (void)out_size; (void)ws_size;

    const float* poses = (const float*)d_in[0];
    const float* emb_w = (const float*)d_in[1];
    const float* emb_b = (const float*)d_in[2];
    const float* cls_w = (const float*)d_in[3];
    const float* cls_b = (const float*)d_in[4];
    const float* jp[12]; const float* ip[12];
    for (int k = 0; k < 12; ++k) { jp[k] = (const float*)d_in[5 + k]; ip[k] = (const float*)d_in[17 + k]; }

    // ---- workspace layout ----
    char* base = (char*)d_ws;
    size_t off = 0;
    auto alloc_b = [&](size_t elems) -> bf16* {
        bf16* p = (bf16*)(base + off);
        off = (off + elems * sizeof(bf16) + 255) & ~(size_t)255;
        return p;
    };
    bf16* bufA  = alloc_b((size_t)R1_ * D_);
    bf16* bufB  = alloc_b((size_t)R1_ * D_);
    bf16* hbarJ = alloc_b((size_t)G1_ * D_);
    bf16* gcn1  = alloc_b((size_t)G1_ * D_);
    bf16* hbar2 = alloc_b((size_t)G2_ * D_);
    bf16* gcn2  = alloc_b((size_t)G2_ * D_);
    float* spart12 = (float*)(base + off); off += NSLOT * 512 * 4;
    float* spart3  = (float*)(base + off); off += NSLOT * 256 * 4;
    float* ab3     = (float*)(base + off); off += 256 * 4;
    float* ab12    = (float*)(base + off); off = (off + 512 * 4 + 255) & ~(size_t)255;
    bf16* wb[2][5];
    const int wsz[5] = {3 * D_ * D_, 3 * 3 * D_ * D_, 3 * D_ * D_, 3 * 2 * D_ * D_, 3 * 2 * D_ * D_};
    for (int s = 0; s < 2; ++s)
        for (int k = 0; k < 5; ++k) wb[s][k] = alloc_b((size_t)wsz[k]);

    const int widx[5] = {0, 2, 4, 8, 10};
    for (int s = 0; s < 2; ++s) {
        const float** P = s ? ip : jp;
        for (int k = 0; k < 5; ++k)
            wconv_kernel<<<(wsz[k] + 4095) / 4096, 256, 0, stream>>>(P[widx[k]], wb[s][k], wsz[k]);
    }
    zero_kernel<<<24, 256, 0, stream>>>(spart12, NSLOT * 512 + NSLOT * 256);

    embedv_kernel<<<4096, 256, 0, stream>>>(poses, emb_w, emb_b, bufA, R1_);

    auto run_stage = [&](const float** P, const bf16* const* W, bf16* h, bf16* t2,
                         bf16* hbar, bf16* gcn, int G, int n, int R) {
        setid_kernel<<<1, 128, 0, stream>>>(ab3);
        for (int L = 0; L < 3; ++L) {
            const bf16* gwb = W[0] + (size_t)L * D_ * D_;
            const bf16* qwb = W[1] + (size_t)L * 3 * D_ * D_;
            const bf16* owb = W[2] + (size_t)L * D_ * D_;
            const bf16* w1b = W[3] + (size_t)L * 2 * D_ * D_;
            const bf16* w2b = W[4] + (size_t)L * 2 * D_ * D_;
            const float* gb  = P[1] + (size_t)L * D_;
            const float* qb  = P[3] + (size_t)L * 3 * D_;
            const float* ob  = P[5] + (size_t)L * D_;
            const float* bng = P[6] + (size_t)L * 3 * D_;
            const float* bnb = P[7] + (size_t)L * 3 * D_;
            const float* b1  = P[9] + (size_t)L * 2 * D_;
            const float* b2  = P[11] + (size_t)L * D_;
            float rcount = 1.f / (float)R;

            gmeanv_kernel<<<G * 16 / 256, 256, 0, stream>>>(h, ab3, hbar, G, n);
            linear64_kernel<<<G / 64, 256, 0, stream>>>(hbar, gwb, gb, gcn);
            if (n == J_)
                attn_mfma_kernel<J_, 3><<<G / 3, 256, 0, stream>>>(h, ab3, gcn, qwb, qb, owb, ob, t2, spart12);
            else
                attn_mfma_kernel<NI_, 4><<<G / 4, 256, 0, stream>>>(h, ab3, gcn, qwb, qb, owb, ob, t2, spart12);
            finalize12_kernel<<<1, 128, 0, stream>>>(spart12, bng, bnb, rcount, ab12);
            mlp_mfma_kernel<<<R / 64, 256, 0, stream>>>(h, ab3, gcn, t2, ab12,
                                                        w1b, b1, w2b, b2, n, spart3);
            finalize3_kernel<<<1, 128, 0, stream>>>(spart3, bng + 2 * D_, bnb + 2 * D_,
                                                    rcount, ab3);
        }
    };

    // joint stage (h raw in bufA; ab3 carries pending BN3 between layers)
    run_stage(jp, wb[0], bufA, bufB, hbarJ, gcn1, G1_, J_, R1_);
    // joint -> individual pooling (applies joint-final ab3 after the mean)
    gmeanv_kernel<<<G1_ * 16 / 256, 256, 0, stream>>>(bufA, ab3, hbarJ, G1_, J_);
    // individual stage
    run_stage(ip, wb[1], hbarJ, bufB, hbar2, gcn2, G2_, NI_, R2_);
    // final pooling (pending ind-final ab3) + classifier
    poolcls_kernel<<<B_, 128, 0, stream>>>(hbarJ, ab3, cls_w, cls_b, (float*)d_out);
}

// Round 9
// 1827.428 us; speedup vs baseline: 13.2455x; 1.0006x over previous
//
#include <hip/hip_runtime.h>
#include <hip/hip_bf16.h>

#define TID threadIdx.x

typedef __hip_bfloat16 bf16;
typedef short s8v __attribute__((ext_vector_type(8)));
typedef float f4v __attribute__((ext_vector_type(4)));
typedef float f16v __attribute__((ext_vector_type(16)));

__device__ __forceinline__ float b2f(bf16 x) { return __bfloat162float(x); }
__device__ __forceinline__ bf16  f2b(float x) { return __float2bfloat16(x); }
__device__ __forceinline__ short f2s(float x) {
    __hip_bfloat16 b = __float2bfloat16(x); short s; __builtin_memcpy(&s, &b, 2); return s;
}
__device__ __forceinline__ float bfu(short s) {
    unsigned u = ((unsigned)(unsigned short)s) << 16; float f; __builtin_memcpy(&f, &u, 4); return f;
}

// ---- problem constants ----
#define B_   256
#define T_   7
#define NI_  12
#define TN_  84
#define J_   17
#define D_   128
#define H_   4
#define DH_  32
#define C_   8
#define G1_  21504       // B_*TN_
#define R1_  365568      // G1_*J_
#define G2_  1792        // B_*T_
#define R2_  21504       // G2_*NI_
#define EPS_ 1e-5f
#define NSLOT 32

// =====================================================================
__global__ __launch_bounds__(256)
void zero_kernel(float* __restrict__ p, int n)
{
    int stride = gridDim.x * 256;
    for (int i = blockIdx.x * 256 + TID; i < n; i += stride) p[i] = 0.f;
}

__global__ __launch_bounds__(128)
void setid_kernel(float* __restrict__ ab)
{
    ab[TID] = 1.f; ab[128 + TID] = 0.f;
}

// fp32 -> bf16 weight conversion
__global__ __launch_bounds__(256)
void wconv_kernel(const float* __restrict__ src, bf16* __restrict__ dst, int n)
{
    int stride = gridDim.x * 256;
    for (int i = blockIdx.x * 256 + TID; i < n; i += stride) dst[i] = f2b(src[i]);
}

// =====================================================================
// Embedding: h = leaky_relu(poses @ ew.T + eb)
// =====================================================================
__global__ __launch_bounds__(256)
void embedv_kernel(const float* __restrict__ poses, const float* __restrict__ ew,
                   const float* __restrict__ eb, bf16* __restrict__ h, int R)
{
    __shared__ float sE0[128], sE1[128], sEb[128];
    if (TID < 128) { sE0[TID] = ew[2 * TID]; sE1[TID] = ew[2 * TID + 1]; sEb[TID] = eb[TID]; }
    __syncthreads();
    int stride = gridDim.x * 256;
    for (int i8 = blockIdx.x * 256 + TID; i8 < R * 16; i8 += stride) {
        int r = i8 >> 4, c8 = (i8 & 15) * 8;
        float p0 = poses[2 * r], p1 = poses[2 * r + 1];
        s8v o;
        #pragma unroll
        for (int e = 0; e < 8; ++e) {
            int c = c8 + e;
            float v = p0 * sE0[c] + p1 * sE1[c] + sEb[c];
            o[e] = f2s(v > 0.f ? v : 0.01f * v);
        }
        *(s8v*)(h + (size_t)r * D_ + c8) = o;
    }
}

// =====================================================================
// Per-graph mean with pending-BN affine applied after the (linear) mean
// =====================================================================
__global__ __launch_bounds__(256)
void gmeanv_kernel(const bf16* __restrict__ h, const float* __restrict__ ab,
                   bf16* __restrict__ hbar, int G, int n)
{
    int i8 = blockIdx.x * 256 + TID;
    if (i8 >= G * 16) return;
    int g = i8 >> 4, c8 = (i8 & 15) * 8;
    const bf16* p = h + (size_t)g * n * D_ + c8;
    float acc[8] = {0,0,0,0,0,0,0,0};
    for (int j = 0; j < n; ++j) {
        s8v v = *(const s8v*)(p + j * D_);
        #pragma unroll
        for (int e = 0; e < 8; ++e) acc[e] += bfu(v[e]);
    }
    float rn = 1.f / n;
    s8v o;
    #pragma unroll
    for (int e = 0; e < 8; ++e) {
        int c = c8 + e;
        o[e] = f2s(acc[e] * rn * ab[c] + ab[128 + c]);
    }
    *(s8v*)(hbar + (size_t)g * D_ + c8) = o;
}

// =====================================================================
// linear64: out[r,:] = X[r,:] @ W.T + bias
// =====================================================================
__global__ __launch_bounds__(256)
void linear64_kernel(const bf16* __restrict__ X, const bf16* __restrict__ Wb,
                     const float* __restrict__ bias, bf16* __restrict__ out)
{
    const int l = TID & 63, wid = TID >> 6;
    const size_t rbase = (size_t)blockIdx.x * 64;
    const int t = wid;
    const int arow = t * 16 + (l & 15);
    s8v a[4];
    #pragma unroll
    for (int ks = 0; ks < 4; ++ks)
        a[ks] = *(const s8v*)(X + (rbase + arow) * D_ + ks * 32 + ((l >> 4) * 8));
    for (int nt = 0; nt < 8; ++nt) {
        int col = nt * 16 + (l & 15);
        float bs = bias[col];
        f4v acc = {bs, bs, bs, bs};
        #pragma unroll
        for (int ks = 0; ks < 4; ++ks) {
            s8v b = *(const s8v*)(Wb + (size_t)col * D_ + ks * 32 + ((l >> 4) * 8));
            acc = __builtin_amdgcn_mfma_f32_16x16x32_bf16(a[ks], b, acc, 0, 0, 0);
        }
        #pragma unroll
        for (int r = 0; r < 4; ++r) {
            int row = t * 16 + (l >> 4) * 4 + r;
            out[(rbase + row) * D_ + col] = f2b(acc[r]);
        }
    }
}

// =====================================================================
// Fused attention + BN1/BN2 stats. MFMA QK^T (S^T trick) + MFMA PV.
// Row strides padded to 48B mod 128 for bank spread.
// =====================================================================
template<int NN, int NG>
__global__ __launch_bounds__(256)
void attn_mfma_kernel(const bf16* __restrict__ h, const float* __restrict__ ab3,
                      const bf16* __restrict__ gcn,
                      const bf16* __restrict__ qwb, const float* __restrict__ qb,
                      const bf16* __restrict__ owb, const float* __restrict__ ob,
                      bf16* __restrict__ out, float* __restrict__ spart)
{
    constexpr int ROWS = NG * NN;
    constexpr int MT = (ROWS + 15) / 16;
    constexpr int QP = 3 * D_ + 24;            // 408 shorts: 816B rows (≡48 mod 128)
    constexpr int HP = 152;                    // 304B rows (≡48 mod 128)
    constexpr int NPAIR = NG * H_;
    constexpr int PBROWS = NPAIR * NN + 15;    // garbage tail for 32-row A reads
    __shared__ __align__(16) short sQKV[MT * 16][QP];
    __shared__ __align__(16) short sHN[ROWS][HP];
    __shared__ __align__(16) short sPb[PBROWS][40];   // 80B rows
    __shared__ short sGCN[NG][128];
    __shared__ float sAB[256];
    __shared__ float sRED[512];

    const int l = TID & 63, wid = TID >> 6;
    const size_t gbase = (size_t)blockIdx.x * ROWS * D_;
    const bf16* hb = h + gbase;

    sAB[TID] = ab3[TID];
    for (int i = TID; i < NG * 128; i += 256)
        sGCN[i >> 7][i & 127] = ((const short*)gcn)[(size_t)blockIdx.x * NG * 128 + i];
    for (int i = TID; i < 512; i += 256) sRED[i] = 0.f;
    __syncthreads();

    // ---------- phase 0: hn = affine(h) -> sHN ----------
    for (int task = TID; task < ROWS * 16; task += 256) {
        int row = task >> 4, c8 = (task & 15) * 8;
        s8v raw = *(const s8v*)(hb + (size_t)row * D_ + c8);
        s8v af;
        #pragma unroll
        for (int e = 0; e < 8; ++e) {
            int c = c8 + e;
            af[e] = f2s(bfu(raw[e]) * sAB[c] + sAB[128 + c]);
        }
        *(s8v*)(&sHN[row][c8]) = af;
    }
    __syncthreads();

    // ---------- phase 1: QKV = hn @ qw.T + qb (16x16x32 MFMA) ----------
    s8v a[MT][4];
    #pragma unroll
    for (int t = 0; t < MT; ++t) {
        int row = t * 16 + (l & 15);
        if (row >= ROWS) row = ROWS - 1;
        const short* rp = &sHN[row][(l >> 4) * 8];
        #pragma unroll
        for (int ks = 0; ks < 4; ++ks) a[t][ks] = *(const s8v*)(rp + ks * 32);
    }
    for (int nt = wid; nt < 24; nt += 4) {
        int col = nt * 16 + (l & 15);
        const bf16* wp = qwb + (size_t)col * D_ + ((l >> 4) * 8);
        s8v b[4];
        #pragma unroll
        for (int ks = 0; ks < 4; ++ks) b[ks] = *(const s8v*)(wp + ks * 32);
        float bs = qb[col];
        #pragma unroll
        for (int t = 0; t < MT; ++t) {
            f4v acc = {bs, bs, bs, bs};
            #pragma unroll
            for (int ks = 0; ks < 4; ++ks)
                acc = __builtin_amdgcn_mfma_f32_16x16x32_bf16(a[t][ks], b[ks], acc, 0, 0, 0);
            #pragma unroll
            for (int r = 0; r < 4; ++r)
                sQKV[t * 16 + (l >> 4) * 4 + r][col] = f2s(acc[r]);
        }
    }
    __syncthreads();

    // ---------- phases 2-3: per (g,h) pair: S^T=K@Q^T -> softmax -> O=P@V ----------
    // 32x32x16 MFMA; D layout: col=lane&31, row=(reg&3)+8*(reg>>2)+4*(lane>>5)
    {
        const float inv = 0.17677669529663687f;   // 1/sqrt(32)
        const int l31 = l & 31, Gq = l >> 5;
        #pragma unroll
        for (int q = 0; q < NPAIR / 4; ++q) {
            int p = wid + 4 * q;
            int g = p >> 2, hd = p & 3;
            int gr = g * NN;
            int pb = p * NN;
            int rr = gr + (l31 < NN ? l31 : NN - 1);
            // A = K rows j (lane&31), B = Q cols i (lane&31); k = head dim
            s8v ka0 = *(const s8v*)(&sQKV[rr][D_ + hd * DH_ + Gq * 8]);
            s8v ka1 = *(const s8v*)(&sQKV[rr][D_ + hd * DH_ + Gq * 8 + 16]);
            s8v qb0 = *(const s8v*)(&sQKV[rr][hd * DH_ + Gq * 8]);
            s8v qb1 = *(const s8v*)(&sQKV[rr][hd * DH_ + Gq * 8 + 16]);
            f16v s = {};
            s = __builtin_amdgcn_mfma_f32_32x32x16_bf16(ka0, qb0, s, 0, 0, 0);
            s = __builtin_amdgcn_mfma_f32_32x32x16_bf16(ka1, qb1, s, 0, 0, 0);
            // softmax over j for row i = l31 (lane + lane^32 hold all 32 j)
            float m = -1e30f;
            #pragma unroll
            for (int r = 0; r < 16; ++r) {
                int j = (r & 3) + 8 * (r >> 2) + 4 * Gq;
                if (j < NN) m = fmaxf(m, s[r]);
            }
            m = fmaxf(m, __shfl_xor(m, 32));
            float pv[16]; float sum = 0.f;
            #pragma unroll
            for (int r = 0; r < 16; ++r) {
                int j = (r & 3) + 8 * (r >> 2) + 4 * Gq;
                float e = (j < NN) ? __expf((s[r] - m) * inv) : 0.f;
                pv[r] = e; sum += e;
            }
            sum += __shfl_xor(sum, 32);
            float rs = 1.f / sum;
            if (l31 < NN) {
                #pragma unroll
                for (int r = 0; r < 16; ++r) {
                    int j = (r & 3) + 8 * (r >> 2) + 4 * Gq;
                    sPb[pb + l31][j] = f2s(pv[r] * rs);   // exact 0 for j>=NN
                }
            }
            asm volatile("s_waitcnt lgkmcnt(0)" ::: "memory");
            // PV: A = P rows i (lane&31), k = j; B = V[j][col c=lane&31]
            s8v pa0 = *(const s8v*)(&sPb[pb + l31][Gq * 8]);
            s8v pa1 = *(const s8v*)(&sPb[pb + l31][Gq * 8 + 16]);
            s8v vb0, vb1;
            #pragma unroll
            for (int e = 0; e < 8; ++e) {
                int j0 = Gq * 8 + e;      int jj0 = j0 < NN ? j0 : 0;
                int j1 = 16 + Gq * 8 + e; int jj1 = j1 < NN ? j1 : 0;
                vb0[e] = sQKV[gr + jj0][2 * D_ + hd * DH_ + l31];
                vb1[e] = sQKV[gr + jj1][2 * D_ + hd * DH_ + l31];
            }
            f16v o = {};
            o = __builtin_amdgcn_mfma_f32_32x32x16_bf16(pa0, vb0, o, 0, 0, 0);
            o = __builtin_amdgcn_mfma_f32_32x32x16_bf16(pa1, vb1, o, 0, 0, 0);
            #pragma unroll
            for (int r = 0; r < 16; ++r) {
                int i = (r & 3) + 8 * (r >> 2) + 4 * Gq;
                if (i < NN) sQKV[gr + i][hd * DH_ + l31] = f2s(o[r]);  // O -> Q slot
            }
        }
    }
    __syncthreads();

    // ---------- phase 4: t2 = O @ ow.T + ob + hn ; stats ----------
    bf16* og = out + gbase;
    #pragma unroll
    for (int t = 0; t < MT; ++t) {
        int row = t * 16 + (l & 15);
        if (row >= ROWS) row = ROWS - 1;
        const short* rp = &sQKV[row][(l >> 4) * 8];
        #pragma unroll
        for (int ks = 0; ks < 4; ++ks) a[t][ks] = *(const s8v*)(rp + ks * 32);
    }
    #pragma unroll
    for (int ni = 0; ni < 2; ++ni) {
        int nt = wid + 4 * ni;
        int col = nt * 16 + (l & 15);
        const bf16* wp = owb + (size_t)col * D_ + ((l >> 4) * 8);
        s8v b[4];
        #pragma unroll
        for (int ks = 0; ks < 4; ++ks) b[ks] = *(const s8v*)(wp + ks * 32);
        float bs = ob[col];
        float s1 = 0.f, q1 = 0.f, s2 = 0.f, q2 = 0.f;
        #pragma unroll
        for (int t = 0; t < MT; ++t) {
            f4v acc = {bs, bs, bs, bs};
            #pragma unroll
            for (int ks = 0; ks < 4; ++ks)
                acc = __builtin_amdgcn_mfma_f32_16x16x32_bf16(a[t][ks], b[ks], acc, 0, 0, 0);
            #pragma unroll
            for (int r = 0; r < 4; ++r) {
                int row = t * 16 + (l >> 4) * 4 + r;
                if (row < ROWS) {
                    float res = bfu(sHN[row][col]);
                    float t2v = acc[r] + res;
                    og[(size_t)row * D_ + col] = f2b(t2v);
                    s2 += t2v; q2 += t2v * t2v;
                    int g = row / NN;
                    float x1 = res + bfu(sGCN[g][col]);
                    s1 += x1; q1 += x1 * x1;
                }
            }
        }
        atomicAdd(&sRED[col], s1);
        atomicAdd(&sRED[128 + col], q1);
        atomicAdd(&sRED[256 + col], s2);
        atomicAdd(&sRED[384 + col], q2);
    }
    __syncthreads();
    {
        int slot = blockIdx.x & (NSLOT - 1);
        for (int i = TID; i < 512; i += 256) atomicAdd(&spart[slot * 512 + i], sRED[i]);
    }
}

// =====================================================================
// finalize BN1+BN2: reduce partial slots -> affine; re-zero
// =====================================================================
__global__ __launch_bounds__(128)
void finalize12_kernel(float* __restrict__ spart, const float* __restrict__ bng,
                       const float* __restrict__ bnb, float rcount,
                       float* __restrict__ ab12)
{
    int c = TID;
    float s1 = 0, q1 = 0, s2 = 0, q2 = 0;
    for (int s = 0; s < NSLOT; ++s) {
        float* p = spart + s * 512;
        s1 += p[c]; q1 += p[128 + c]; s2 += p[256 + c]; q2 += p[384 + c];
        p[c] = 0.f; p[128 + c] = 0.f; p[256 + c] = 0.f; p[384 + c] = 0.f;
    }
    float m1 = s1 * rcount, v1 = q1 * rcount - m1 * m1;
    float a1 = rsqrtf(v1 + EPS_) * bng[c];
    ab12[c] = a1; ab12[128 + c] = bnb[c] - m1 * a1;
    float m2 = s2 * rcount, v2 = q2 * rcount - m2 * m2;
    float a2 = rsqrtf(v2 + EPS_) * bng[128 + c];
    ab12[256 + c] = a2; ab12[384 + c] = bnb[128 + c] - m2 * a2;
}

// finalize BN3 -> ab3; re-zero partials
__global__ __launch_bounds__(128)
void finalize3_kernel(float* __restrict__ spart, const float* __restrict__ gamma,
                      const float* __restrict__ beta, float rcount,
                      float* __restrict__ ab3)
{
    int c = TID;
    float s1 = 0, q1 = 0;
    for (int s = 0; s < NSLOT; ++s) {
        float* p = spart + s * 256;
        s1 += p[c]; q1 += p[128 + c];
        p[c] = 0.f; p[128 + c] = 0.f;
    }
    float m = s1 * rcount, v = q1 * rcount - m * m;
    float a = rsqrtf(v + EPS_) * gamma[c];
    ab3[c] = a; ab3[128 + c] = beta[c] - m * a;
}

// =====================================================================
// Fused MLP (de-duplicated, unchanged from R8)
// =====================================================================
__global__ __launch_bounds__(256)
void mlp_mfma_kernel(bf16* __restrict__ X, const float* __restrict__ ab3,
                     const bf16* __restrict__ gcn, const bf16* __restrict__ t2,
                     const float* __restrict__ ab12,
                     const bf16* __restrict__ w1b, const float* __restrict__ b1,
                     const bf16* __restrict__ w2b, const float* __restrict__ b2,
                     int n, float* __restrict__ spart3)
{
    constexpr int MP = 264;
    __shared__ short sM[64][MP];
    __shared__ short sOUT[64][136];
    __shared__ float sAB[768];
    __shared__ float sRED[256];
    const int l = TID & 63, wid = TID >> 6;
    const size_t rbase = (size_t)blockIdx.x * 64;
    bf16* Xb = X + rbase * D_;
    const bf16* Tb = t2 + rbase * D_;

    sAB[TID] = ab3[TID];
    for (int i = TID; i < 512; i += 256) sAB[256 + i] = ab12[i];
    sRED[TID] = 0.f;
    __syncthreads();

    {
        int row = TID >> 2;
        int cb0 = (TID & 3) * 32;
        int g = (int)((rbase + row) / n);
        #pragma unroll
        for (int k2 = 0; k2 < 4; ++k2) {
            int cb = cb0 + k2 * 8;
            s8v xv = *(const s8v*)(Xb + (size_t)row * D_ + cb);
            s8v gv = *(const s8v*)(gcn + (size_t)g * D_ + cb);
            s8v tv = *(const s8v*)(Tb + (size_t)row * D_ + cb);
            s8v af;
            #pragma unroll
            for (int e = 0; e < 8; ++e) {
                int c = cb + e;
                float hn = bfu(xv[e]) * sAB[c] + sAB[128 + c];
                float outv = (hn + bfu(gv[e])) * sAB[256 + c] + sAB[384 + c]
                           + bfu(tv[e]) * sAB[512 + c] + sAB[640 + c];
                af[e] = f2s(outv);
            }
            *(s8v*)(&sOUT[row][cb]) = af;
        }
    }
    __syncthreads();

    s8v a[4][4];
    #pragma unroll
    for (int t = 0; t < 4; ++t) {
        const short* rp = &sOUT[t * 16 + (l & 15)][(l >> 4) * 8];
        #pragma unroll
        for (int ks = 0; ks < 4; ++ks) a[t][ks] = *(const s8v*)(rp + ks * 32);
    }
    for (int nt = wid; nt < 16; nt += 4) {
        int col = nt * 16 + (l & 15);
        const bf16* wp = w1b + (size_t)col * D_ + ((l >> 4) * 8);
        s8v b[4];
        #pragma unroll
        for (int ks = 0; ks < 4; ++ks) b[ks] = *(const s8v*)(wp + ks * 32);
        float bs = b1[col];
        #pragma unroll
        for (int t = 0; t < 4; ++t) {
            f4v acc = {bs, bs, bs, bs};
            #pragma unroll
            for (int ks = 0; ks < 4; ++ks)
                acc = __builtin_amdgcn_mfma_f32_16x16x32_bf16(a[t][ks], b[ks], acc, 0, 0, 0);
            #pragma unroll
            for (int r = 0; r < 4; ++r)
                sM[t * 16 + (l >> 4) * 4 + r][col] = f2s(fmaxf(acc[r], 0.f));
        }
    }
    __syncthreads();

    {
        const int nt0 = wid * 2;
        const int col0 = nt0 * 16 + (l & 15), col1 = col0 + 16;
        s8v b0[8], b1v[8];
        #pragma unroll
        for (int ks = 0; ks < 8; ++ks) {
            b0[ks]  = *(const s8v*)(w2b + (size_t)col0 * 256 + ks * 32 + ((l >> 4) * 8));
            b1v[ks] = *(const s8v*)(w2b + (size_t)col1 * 256 + ks * 32 + ((l >> 4) * 8));
        }
        float bs0 = b2[col0], bs1 = b2[col1];
        float ss0 = 0.f, qq0 = 0.f, ss1 = 0.f, qq1 = 0.f;
        #pragma unroll
        for (int t = 0; t < 4; ++t) {
            s8v am[8];
            const short* rp = &sM[t * 16 + (l & 15)][(l >> 4) * 8];
            #pragma unroll
            for (int ks = 0; ks < 8; ++ks) am[ks] = *(const s8v*)(rp + ks * 32);
            f4v acc0 = {bs0, bs0, bs0, bs0};
            f4v acc1 = {bs1, bs1, bs1, bs1};
            #pragma unroll
            for (int ks = 0; ks < 8; ++ks) {
                acc0 = __builtin_amdgcn_mfma_f32_16x16x32_bf16(am[ks], b0[ks], acc0, 0, 0, 0);
                acc1 = __builtin_amdgcn_mfma_f32_16x16x32_bf16(am[ks], b1v[ks], acc1, 0, 0, 0);
            }
            #pragma unroll
            for (int r = 0; r < 4; ++r) {
                int row = t * 16 + (l >> 4) * 4 + r;
                float xn0 = acc0[r] + bfu(sOUT[row][col0]);
                float xn1 = acc1[r] + bfu(sOUT[row][col1]);
                Xb[(size_t)row * D_ + col0] = f2b(xn0);
                Xb[(size_t)row * D_ + col1] = f2b(xn1);
                ss0 += xn0; qq0 += xn0 * xn0;
                ss1 += xn1; qq1 += xn1 * xn1;
            }
        }
        atomicAdd(&sRED[col0], ss0); atomicAdd(&sRED[128 + col0], qq0);
        atomicAdd(&sRED[col1], ss1); atomicAdd(&sRED[128 + col1], qq1);
    }
    __syncthreads();
    {
        int slot = blockIdx.x & (NSLOT - 1);
        atomicAdd(&spart3[slot * 256 + TID], sRED[TID]);
    }
}

// =====================================================================
// Final pooling (with pending ab3 affine) + classifier
// =====================================================================
__global__ __launch_bounds__(128)
void poolcls_kernel(const bf16* __restrict__ gi, const float* __restrict__ ab,
                    const float* __restrict__ cw, const float* __restrict__ cb,
                    float* __restrict__ out)
{
    __shared__ float sP[128];
    int b = blockIdx.x, d = TID;
    const bf16* p = gi + (size_t)b * TN_ * D_ + d;
    float s = 0.f;
    for (int i = 0; i < TN_; ++i) s += b2f(p[i * D_]);
    sP[d] = (s * (1.f / TN_)) * ab[d] + ab[128 + d];
    __syncthreads();
    if (d < C_) {
        float acc = cb[d];
        for (int k = 0; k < D_; ++k) acc += sP[k] * cw[d * D_ + k];
        out[b * C_ + d] = acc;
    }
}

// =====================================================================
extern "C" void kernel_launch(void* const* d_in, const int* in_sizes, int n_in,
                              void* d_out, int out_size, void* d_ws, size_t ws_size,
                              hipStream_t stream)
{
    (void)in_sizes; (void)n_in; (void)out_size; (void)ws_size;

    const float* poses = (const float*)d_in[0];
    const float* emb_w = (const float*)d_in[1];
    const float* emb_b = (const float*)d_in[2];
    const float* cls_w = (const float*)d_in[3];
    const float* cls_b = (const float*)d_in[4];
    const float* jp[12]; const float* ip[12];
    for (int k = 0; k < 12; ++k) { jp[k] = (const float*)d_in[5 + k]; ip[k] = (const float*)d_in[17 + k]; }

    // ---- workspace layout ----
    char* base = (char*)d_ws;
    size_t off = 0;
    auto alloc_b = [&](size_t elems) -> bf16* {
        bf16* p = (bf16*)(base + off);
        off = (off + elems * sizeof(bf16) + 255) & ~(size_t)255;
        return p;
    };
    bf16* bufA  = alloc_b((size_t)R1_ * D_);
    bf16* bufB  = alloc_b((size_t)R1_ * D_);
    bf16* hbarJ = alloc_b((size_t)G1_ * D_);
    bf16* gcn1  = alloc_b((size_t)G1_ * D_);
    bf16* hbar2 = alloc_b((size_t)G2_ * D_);
    bf16* gcn2  = alloc_b((size_t)G2_ * D_);
    float* spart12 = (float*)(base + off); off += NSLOT * 512 * 4;
    float* spart3  = (float*)(base + off); off += NSLOT * 256 * 4;
    float* ab3     = (float*)(base + off); off += 256 * 4;
    float* ab12    = (float*)(base + off); off = (off + 512 * 4 + 255) & ~(size_t)255;
    bf16* wb[2][5];
    const int wsz[5] = {3 * D_ * D_, 3 * 3 * D_ * D_, 3 * D_ * D_, 3 * 2 * D_ * D_, 3 * 2 * D_ * D_};
    for (int s = 0; s < 2; ++s)
        for (int k = 0; k < 5; ++k) wb[s][k] = alloc_b((size_t)wsz[k]);

    const int widx[5] = {0, 2, 4, 8, 10};
    for (int s = 0; s < 2; ++s) {
        const float** P = s ? ip : jp;
        for (int k = 0; k < 5; ++k)
            wconv_kernel<<<(wsz[k] + 4095) / 4096, 256, 0, stream>>>(P[widx[k]], wb[s][k], wsz[k]);
    }
    zero_kernel<<<24, 256, 0, stream>>>(spart12, NSLOT * 512 + NSLOT * 256);

    embedv_kernel<<<4096, 256, 0, stream>>>(poses, emb_w, emb_b, bufA, R1_);

    auto run_stage = [&](const float** P, const bf16* const* W, bf16* h, bf16* t2,
                         bf16* hbar, bf16* gcn, int G, int n, int R) {
        setid_kernel<<<1, 128, 0, stream>>>(ab3);
        for (int L = 0; L < 3; ++L) {
            const bf16* gwb = W[0] + (size_t)L * D_ * D_;
            const bf16* qwb = W[1] + (size_t)L * 3 * D_ * D_;
            const bf16* owb = W[2] + (size_t)L * D_ * D_;
            const bf16* w1b = W[3] + (size_t)L * 2 * D_ * D_;
            const bf16* w2b = W[4] + (size_t)L * 2 * D_ * D_;
            const float* gb  = P[1] + (size_t)L * D_;
            const float* qb  = P[3] + (size_t)L * 3 * D_;
            const float* ob  = P[5] + (size_t)L * D_;
            const float* bng = P[6] + (size_t)L * 3 * D_;
            const float* bnb = P[7] + (size_t)L * 3 * D_;
            const float* b1  = P[9] + (size_t)L * 2 * D_;
            const float* b2  = P[11] + (size_t)L * D_;
            float rcount = 1.f / (float)R;

            gmeanv_kernel<<<G * 16 / 256, 256, 0, stream>>>(h, ab3, hbar, G, n);
            linear64_kernel<<<G / 64, 256, 0, stream>>>(hbar, gwb, gb, gcn);
            if (n == J_)
                attn_mfma_kernel<J_, 2><<<G / 2, 256, 0, stream>>>(h, ab3, gcn, qwb, qb, owb, ob, t2, spart12);
            else
                attn_mfma_kernel<NI_, 4><<<G / 4, 256, 0, stream>>>(h, ab3, gcn, qwb, qb, owb, ob, t2, spart12);
            finalize12_kernel<<<1, 128, 0, stream>>>(spart12, bng, bnb, rcount, ab12);
            mlp_mfma_kernel<<<R / 64, 256, 0, stream>>>(h, ab3, gcn, t2, ab12,
                                                        w1b, b1, w2b, b2, n, spart3);
            finalize3_kernel<<<1, 128, 0, stream>>>(spart3, bng + 2 * D_, bnb + 2 * D_,
                                                    rcount, ab3);
        }
    };

    // joint stage
    run_stage(jp, wb[0], bufA, bufB, hbarJ, gcn1, G1_, J_, R1_);
    // joint -> individual pooling
    gmeanv_kernel<<<G1_ * 16 / 256, 256, 0, stream>>>(bufA, ab3, hbarJ, G1_, J_);
    // individual stage
    run_stage(ip, wb[1], hbarJ, bufB, hbar2, gcn2, G2_, NI_, R2_);
    // final pooling + classifier
    poolcls_kernel<<<B_, 128, 0, stream>>>(hbarJ, ab3, cls_w, cls_b, (float*)d_out);
}

// Round 10
// 1689.461 us; speedup vs baseline: 14.3272x; 1.0817x over previous
//
#include <hip/hip_runtime.h>
#include <hip/hip_bf16.h>

#define TID threadIdx.x

typedef __hip_bfloat16 bf16;
typedef short s8v __attribute__((ext_vector_type(8)));
typedef float f4v __attribute__((ext_vector_type(4)));
typedef float f16v __attribute__((ext_vector_type(16)));

__device__ __forceinline__ float b2f(bf16 x) { return __bfloat162float(x); }
__device__ __forceinline__ bf16  f2b(float x) { return __float2bfloat16(x); }
__device__ __forceinline__ short f2s(float x) {
    __hip_bfloat16 b = __float2bfloat16(x); short s; __builtin_memcpy(&s, &b, 2); return s;
}
__device__ __forceinline__ float bfu(short s) {
    unsigned u = ((unsigned)(unsigned short)s) << 16; float f; __builtin_memcpy(&f, &u, 4); return f;
}

// ---- problem constants ----
#define B_   256
#define T_   7
#define NI_  12
#define TN_  84
#define J_   17
#define D_   128
#define H_   4
#define DH_  32
#define C_   8
#define G1_  21504       // B_*TN_
#define R1_  365568      // G1_*J_
#define G2_  1792        // B_*T_
#define R2_  21504       // G2_*NI_
#define EPS_ 1e-5f
#define NSLOT 32

// =====================================================================
__global__ __launch_bounds__(256)
void zero_kernel(float* __restrict__ p, int n)
{
    int stride = gridDim.x * 256;
    for (int i = blockIdx.x * 256 + TID; i < n; i += stride) p[i] = 0.f;
}

__global__ __launch_bounds__(128)
void setid_kernel(float* __restrict__ ab)
{
    ab[TID] = 1.f; ab[128 + TID] = 0.f;
}

// fp32 -> bf16 weight conversion
__global__ __launch_bounds__(256)
void wconv_kernel(const float* __restrict__ src, bf16* __restrict__ dst, int n)
{
    int stride = gridDim.x * 256;
    for (int i = blockIdx.x * 256 + TID; i < n; i += stride) dst[i] = f2b(src[i]);
}

// =====================================================================
// Embedding: h = leaky_relu(poses @ ew.T + eb)
// =====================================================================
__global__ __launch_bounds__(256)
void embedv_kernel(const float* __restrict__ poses, const float* __restrict__ ew,
                   const float* __restrict__ eb, bf16* __restrict__ h, int R)
{
    __shared__ float sE0[128], sE1[128], sEb[128];
    if (TID < 128) { sE0[TID] = ew[2 * TID]; sE1[TID] = ew[2 * TID + 1]; sEb[TID] = eb[TID]; }
    __syncthreads();
    int stride = gridDim.x * 256;
    for (int i8 = blockIdx.x * 256 + TID; i8 < R * 16; i8 += stride) {
        int r = i8 >> 4, c8 = (i8 & 15) * 8;
        float p0 = poses[2 * r], p1 = poses[2 * r + 1];
        s8v o;
        #pragma unroll
        for (int e = 0; e < 8; ++e) {
            int c = c8 + e;
            float v = p0 * sE0[c] + p1 * sE1[c] + sEb[c];
            o[e] = f2s(v > 0.f ? v : 0.01f * v);
        }
        *(s8v*)(h + (size_t)r * D_ + c8) = o;
    }
}

// =====================================================================
// Per-graph mean with pending-BN affine applied after the (linear) mean
// =====================================================================
__global__ __launch_bounds__(256)
void gmeanv_kernel(const bf16* __restrict__ h, const float* __restrict__ ab,
                   bf16* __restrict__ hbar, int G, int n)
{
    int i8 = blockIdx.x * 256 + TID;
    if (i8 >= G * 16) return;
    int g = i8 >> 4, c8 = (i8 & 15) * 8;
    const bf16* p = h + (size_t)g * n * D_ + c8;
    float acc[8] = {0,0,0,0,0,0,0,0};
    for (int j = 0; j < n; ++j) {
        s8v v = *(const s8v*)(p + j * D_);
        #pragma unroll
        for (int e = 0; e < 8; ++e) acc[e] += bfu(v[e]);
    }
    float rn = 1.f / n;
    s8v o;
    #pragma unroll
    for (int e = 0; e < 8; ++e) {
        int c = c8 + e;
        o[e] = f2s(acc[e] * rn * ab[c] + ab[128 + c]);
    }
    *(s8v*)(hbar + (size_t)g * D_ + c8) = o;
}

// =====================================================================
// linear64: out[r,:] = X[r,:] @ W.T + bias
// =====================================================================
__global__ __launch_bounds__(256)
void linear64_kernel(const bf16* __restrict__ X, const bf16* __restrict__ Wb,
                     const float* __restrict__ bias, bf16* __restrict__ out)
{
    const int l = TID & 63, wid = TID >> 6;
    const size_t rbase = (size_t)blockIdx.x * 64;
    const int t = wid;
    const int arow = t * 16 + (l & 15);
    s8v a[4];
    #pragma unroll
    for (int ks = 0; ks < 4; ++ks)
        a[ks] = *(const s8v*)(X + (rbase + arow) * D_ + ks * 32 + ((l >> 4) * 8));
    for (int nt = 0; nt < 8; ++nt) {
        int col = nt * 16 + (l & 15);
        float bs = bias[col];
        f4v acc = {bs, bs, bs, bs};
        #pragma unroll
        for (int ks = 0; ks < 4; ++ks) {
            s8v b = *(const s8v*)(Wb + (size_t)col * D_ + ks * 32 + ((l >> 4) * 8));
            acc = __builtin_amdgcn_mfma_f32_16x16x32_bf16(a[ks], b, acc, 0, 0, 0);
        }
        #pragma unroll
        for (int r = 0; r < 4; ++r) {
            int row = t * 16 + (l >> 4) * 4 + r;
            out[(rbase + row) * D_ + col] = f2b(acc[r]);
        }
    }
}

// =====================================================================
// Fused attention + BN1/BN2 stats. MFMA QK^T (S^T trick) + MFMA PV.
// P overlaid into the dead K-slice of sQKV (saves 12KB LDS -> 3 blocks/CU).
// =====================================================================
template<int NN, int NG>
__global__ __launch_bounds__(256)
void attn_mfma_kernel(const bf16* __restrict__ h, const float* __restrict__ ab3,
                      const bf16* __restrict__ gcn,
                      const bf16* __restrict__ qwb, const float* __restrict__ qb,
                      const bf16* __restrict__ owb, const float* __restrict__ ob,
                      bf16* __restrict__ out, float* __restrict__ spart)
{
    constexpr int ROWS = NG * NN;
    constexpr int MT = (ROWS + 15) / 16;
    constexpr int QP = 3 * D_ + 24;            // 408 shorts: 816B rows (≡48 mod 128)
    constexpr int HP = 152;                    // 304B rows (≡48 mod 128)
    constexpr int NPAIR = NG * H_;
    __shared__ __align__(16) short sQKV[MT * 16][QP];
    __shared__ __align__(16) short sHN[ROWS][HP];
    __shared__ short sGCN[NG][128];
    __shared__ float sAB[256];
    __shared__ float sRED[512];

    const int l = TID & 63, wid = TID >> 6;
    const size_t gbase = (size_t)blockIdx.x * ROWS * D_;
    const bf16* hb = h + gbase;

    sAB[TID] = ab3[TID];
    for (int i = TID; i < NG * 128; i += 256)
        sGCN[i >> 7][i & 127] = ((const short*)gcn)[(size_t)blockIdx.x * NG * 128 + i];
    for (int i = TID; i < 512; i += 256) sRED[i] = 0.f;
    __syncthreads();

    // ---------- phase 0: hn = affine(h) -> sHN ----------
    for (int task = TID; task < ROWS * 16; task += 256) {
        int row = task >> 4, c8 = (task & 15) * 8;
        s8v raw = *(const s8v*)(hb + (size_t)row * D_ + c8);
        s8v af;
        #pragma unroll
        for (int e = 0; e < 8; ++e) {
            int c = c8 + e;
            af[e] = f2s(bfu(raw[e]) * sAB[c] + sAB[128 + c]);
        }
        *(s8v*)(&sHN[row][c8]) = af;
    }
    __syncthreads();

    // ---------- phase 1: QKV = hn @ qw.T + qb (16x16x32 MFMA) ----------
    s8v a[MT][4];
    #pragma unroll
    for (int t = 0; t < MT; ++t) {
        int row = t * 16 + (l & 15);
        if (row >= ROWS) row = ROWS - 1;
        const short* rp = &sHN[row][(l >> 4) * 8];
        #pragma unroll
        for (int ks = 0; ks < 4; ++ks) a[t][ks] = *(const s8v*)(rp + ks * 32);
    }
    for (int nt = wid; nt < 24; nt += 4) {
        int col = nt * 16 + (l & 15);
        const bf16* wp = qwb + (size_t)col * D_ + ((l >> 4) * 8);
        s8v b[4];
        #pragma unroll
        for (int ks = 0; ks < 4; ++ks) b[ks] = *(const s8v*)(wp + ks * 32);
        float bs = qb[col];
        #pragma unroll
        for (int t = 0; t < MT; ++t) {
            f4v acc = {bs, bs, bs, bs};
            #pragma unroll
            for (int ks = 0; ks < 4; ++ks)
                acc = __builtin_amdgcn_mfma_f32_16x16x32_bf16(a[t][ks], b[ks], acc, 0, 0, 0);
            #pragma unroll
            for (int r = 0; r < 4; ++r)
                sQKV[t * 16 + (l >> 4) * 4 + r][col] = f2s(acc[r]);
        }
    }
    __syncthreads();

    // ---------- phases 2-3: per (g,h) pair: S^T=K@Q^T -> softmax -> O=P@V ----------
    // 32x32x16 MFMA; D layout: col=lane&31, row=(reg&3)+8*(reg>>2)+4*(lane>>5)
    // P[i][j] stored into the pair's own (consumed) K slice: cols D_+hd*32+j.
    {
        const float inv = 0.17677669529663687f;   // 1/sqrt(32)
        const int l31 = l & 31, Gq = l >> 5;
        #pragma unroll
        for (int q = 0; q < NPAIR / 4; ++q) {
            int p = wid + 4 * q;
            int g = p >> 2, hd = p & 3;
            int gr = g * NN;
            int rr = gr + (l31 < NN ? l31 : NN - 1);
            // A = K rows j (lane&31), B = Q cols i (lane&31); k = head dim
            s8v ka0 = *(const s8v*)(&sQKV[rr][D_ + hd * DH_ + Gq * 8]);
            s8v ka1 = *(const s8v*)(&sQKV[rr][D_ + hd * DH_ + Gq * 8 + 16]);
            s8v qb0 = *(const s8v*)(&sQKV[rr][hd * DH_ + Gq * 8]);
            s8v qb1 = *(const s8v*)(&sQKV[rr][hd * DH_ + Gq * 8 + 16]);
            f16v s = {};
            s = __builtin_amdgcn_mfma_f32_32x32x16_bf16(ka0, qb0, s, 0, 0, 0);
            s = __builtin_amdgcn_mfma_f32_32x32x16_bf16(ka1, qb1, s, 0, 0, 0);
            // softmax over j for row i = l31 (lane + lane^32 hold all 32 j)
            float m = -1e30f;
            #pragma unroll
            for (int r = 0; r < 16; ++r) {
                int j = (r & 3) + 8 * (r >> 2) + 4 * Gq;
                if (j < NN) m = fmaxf(m, s[r]);
            }
            m = fmaxf(m, __shfl_xor(m, 32));
            float pv[16]; float sum = 0.f;
            #pragma unroll
            for (int r = 0; r < 16; ++r) {
                int j = (r & 3) + 8 * (r >> 2) + 4 * Gq;
                float e = (j < NN) ? __expf((s[r] - m) * inv) : 0.f;
                pv[r] = e; sum += e;
            }
            sum += __shfl_xor(sum, 32);
            float rs = 1.f / sum;
            if (l31 < NN) {
                #pragma unroll
                for (int r = 0; r < 16; ++r) {
                    int j = (r & 3) + 8 * (r >> 2) + 4 * Gq;
                    sQKV[gr + l31][D_ + hd * DH_ + j] = f2s(pv[r] * rs); // 0 for j>=NN
                }
            }
            // PV: A = P rows i (lane&31), k = j; B = V[j][col c=lane&31]
            int prow = gr + l31; if (prow > MT * 16 - 1) prow = MT * 16 - 1;
            s8v pa0 = *(const s8v*)(&sQKV[prow][D_ + hd * DH_ + Gq * 8]);
            s8v pa1 = *(const s8v*)(&sQKV[prow][D_ + hd * DH_ + Gq * 8 + 16]);
            s8v vb0, vb1;
            #pragma unroll
            for (int e = 0; e < 8; ++e) {
                int j0 = Gq * 8 + e;      int jj0 = j0 < NN ? j0 : 0;
                int j1 = 16 + Gq * 8 + e; int jj1 = j1 < NN ? j1 : 0;
                vb0[e] = sQKV[gr + jj0][2 * D_ + hd * DH_ + l31];
                vb1[e] = sQKV[gr + jj1][2 * D_ + hd * DH_ + l31];
            }
            f16v o = {};
            o = __builtin_amdgcn_mfma_f32_32x32x16_bf16(pa0, vb0, o, 0, 0, 0);
            o = __builtin_amdgcn_mfma_f32_32x32x16_bf16(pa1, vb1, o, 0, 0, 0);
            #pragma unroll
            for (int r = 0; r < 16; ++r) {
                int i = (r & 3) + 8 * (r >> 2) + 4 * Gq;
                if (i < NN) sQKV[gr + i][hd * DH_ + l31] = f2s(o[r]);  // O -> Q slot
            }
        }
    }
    __syncthreads();

    // ---------- phase 4: t2 = O @ ow.T + ob + hn ; stats ----------
    bf16* og = out + gbase;
    #pragma unroll
    for (int t = 0; t < MT; ++t) {
        int row = t * 16 + (l & 15);
        if (row >= ROWS) row = ROWS - 1;
        const short* rp = &sQKV[row][(l >> 4) * 8];
        #pragma unroll
        for (int ks = 0; ks < 4; ++ks) a[t][ks] = *(const s8v*)(rp + ks * 32);
    }
    #pragma unroll
    for (int ni = 0; ni < 2; ++ni) {
        int nt = wid + 4 * ni;
        int col = nt * 16 + (l & 15);
        const bf16* wp = owb + (size_t)col * D_ + ((l >> 4) * 8);
        s8v b[4];
        #pragma unroll
        for (int ks = 0; ks < 4; ++ks) b[ks] = *(const s8v*)(wp + ks * 32);
        float bs = ob[col];
        float s1 = 0.f, q1 = 0.f, s2 = 0.f, q2 = 0.f;
        #pragma unroll
        for (int t = 0; t < MT; ++t) {
            f4v acc = {bs, bs, bs, bs};
            #pragma unroll
            for (int ks = 0; ks < 4; ++ks)
                acc = __builtin_amdgcn_mfma_f32_16x16x32_bf16(a[t][ks], b[ks], acc, 0, 0, 0);
            #pragma unroll
            for (int r = 0; r < 4; ++r) {
                int row = t * 16 + (l >> 4) * 4 + r;
                if (row < ROWS) {
                    float res = bfu(sHN[row][col]);
                    float t2v = acc[r] + res;
                    og[(size_t)row * D_ + col] = f2b(t2v);
                    s2 += t2v; q2 += t2v * t2v;
                    int g = row / NN;
                    float x1 = res + bfu(sGCN[g][col]);
                    s1 += x1; q1 += x1 * x1;
                }
            }
        }
        atomicAdd(&sRED[col], s1);
        atomicAdd(&sRED[128 + col], q1);
        atomicAdd(&sRED[256 + col], s2);
        atomicAdd(&sRED[384 + col], q2);
    }
    __syncthreads();
    {
        int slot = blockIdx.x & (NSLOT - 1);
        for (int i = TID; i < 512; i += 256) atomicAdd(&spart[slot * 512 + i], sRED[i]);
    }
}

// =====================================================================
// finalize BN1+BN2: reduce partial slots -> affine; re-zero
// =====================================================================
__global__ __launch_bounds__(128)
void finalize12_kernel(float* __restrict__ spart, const float* __restrict__ bng,
                       const float* __restrict__ bnb, float rcount,
                       float* __restrict__ ab12)
{
    int c = TID;
    float s1 = 0, q1 = 0, s2 = 0, q2 = 0;
    for (int s = 0; s < NSLOT; ++s) {
        float* p = spart + s * 512;
        s1 += p[c]; q1 += p[128 + c]; s2 += p[256 + c]; q2 += p[384 + c];
        p[c] = 0.f; p[128 + c] = 0.f; p[256 + c] = 0.f; p[384 + c] = 0.f;
    }
    float m1 = s1 * rcount, v1 = q1 * rcount - m1 * m1;
    float a1 = rsqrtf(v1 + EPS_) * bng[c];
    ab12[c] = a1; ab12[128 + c] = bnb[c] - m1 * a1;
    float m2 = s2 * rcount, v2 = q2 * rcount - m2 * m2;
    float a2 = rsqrtf(v2 + EPS_) * bng[128 + c];
    ab12[256 + c] = a2; ab12[384 + c] = bnb[128 + c] - m2 * a2;
}

// finalize BN3 -> ab3; re-zero partials
__global__ __launch_bounds__(128)
void finalize3_kernel(float* __restrict__ spart, const float* __restrict__ gamma,
                      const float* __restrict__ beta, float rcount,
                      float* __restrict__ ab3)
{
    int c = TID;
    float s1 = 0, q1 = 0;
    for (int s = 0; s < NSLOT; ++s) {
        float* p = spart + s * 256;
        s1 += p[c]; q1 += p[128 + c];
        p[c] = 0.f; p[128 + c] = 0.f;
    }
    float m = s1 * rcount, v = q1 * rcount - m * m;
    float a = rsqrtf(v + EPS_) * gamma[c];
    ab3[c] = a; ab3[128 + c] = beta[c] - m * a;
}

// =====================================================================
// Fused MLP (de-duplicated, unchanged from R8)
// =====================================================================
__global__ __launch_bounds__(256)
void mlp_mfma_kernel(bf16* __restrict__ X, const float* __restrict__ ab3,
                     const bf16* __restrict__ gcn, const bf16* __restrict__ t2,
                     const float* __restrict__ ab12,
                     const bf16* __restrict__ w1b, const float* __restrict__ b1,
                     const bf16* __restrict__ w2b, const float* __restrict__ b2,
                     int n, float* __restrict__ spart3)
{
    constexpr int MP = 264;
    __shared__ short sM[64][MP];
    __shared__ short sOUT[64][136];
    __shared__ float sAB[768];
    __shared__ float sRED[256];
    const int l = TID & 63, wid = TID >> 6;
    const size_t rbase = (size_t)blockIdx.x * 64;
    bf16* Xb = X + rbase * D_;
    const bf16* Tb = t2 + rbase * D_;

    sAB[TID] = ab3[TID];
    for (int i = TID; i < 512; i += 256) sAB[256 + i] = ab12[i];
    sRED[TID] = 0.f;
    __syncthreads();

    {
        int row = TID >> 2;
        int cb0 = (TID & 3) * 32;
        int g = (int)((rbase + row) / n);
        #pragma unroll
        for (int k2 = 0; k2 < 4; ++k2) {
            int cb = cb0 + k2 * 8;
            s8v xv = *(const s8v*)(Xb + (size_t)row * D_ + cb);
            s8v gv = *(const s8v*)(gcn + (size_t)g * D_ + cb);
            s8v tv = *(const s8v*)(Tb + (size_t)row * D_ + cb);
            s8v af;
            #pragma unroll
            for (int e = 0; e < 8; ++e) {
                int c = cb + e;
                float hn = bfu(xv[e]) * sAB[c] + sAB[128 + c];
                float outv = (hn + bfu(gv[e])) * sAB[256 + c] + sAB[384 + c]
                           + bfu(tv[e]) * sAB[512 + c] + sAB[640 + c];
                af[e] = f2s(outv);
            }
            *(s8v*)(&sOUT[row][cb]) = af;
        }
    }
    __syncthreads();

    s8v a[4][4];
    #pragma unroll
    for (int t = 0; t < 4; ++t) {
        const short* rp = &sOUT[t * 16 + (l & 15)][(l >> 4) * 8];
        #pragma unroll
        for (int ks = 0; ks < 4; ++ks) a[t][ks] = *(const s8v*)(rp + ks * 32);
    }
    for (int nt = wid; nt < 16; nt += 4) {
        int col = nt * 16 + (l & 15);
        const bf16* wp = w1b + (size_t)col * D_ + ((l >> 4) * 8);
        s8v b[4];
        #pragma unroll
        for (int ks = 0; ks < 4; ++ks) b[ks] = *(const s8v*)(wp + ks * 32);
        float bs = b1[col];
        #pragma unroll
        for (int t = 0; t < 4; ++t) {
            f4v acc = {bs, bs, bs, bs};
            #pragma unroll
            for (int ks = 0; ks < 4; ++ks)
                acc = __builtin_amdgcn_mfma_f32_16x16x32_bf16(a[t][ks], b[ks], acc, 0, 0, 0);
            #pragma unroll
            for (int r = 0; r < 4; ++r)
                sM[t * 16 + (l >> 4) * 4 + r][col] = f2s(fmaxf(acc[r], 0.f));
        }
    }
    __syncthreads();

    {
        const int nt0 = wid * 2;
        const int col0 = nt0 * 16 + (l & 15), col1 = col0 + 16;
        s8v b0[8], b1v[8];
        #pragma unroll
        for (int ks = 0; ks < 8; ++ks) {
            b0[ks]  = *(const s8v*)(w2b + (size_t)col0 * 256 + ks * 32 + ((l >> 4) * 8));
            b1v[ks] = *(const s8v*)(w2b + (size_t)col1 * 256 + ks * 32 + ((l >> 4) * 8));
        }
        float bs0 = b2[col0], bs1 = b2[col1];
        float ss0 = 0.f, qq0 = 0.f, ss1 = 0.f, qq1 = 0.f;
        #pragma unroll
        for (int t = 0; t < 4; ++t) {
            s8v am[8];
            const short* rp = &sM[t * 16 + (l & 15)][(l >> 4) * 8];
            #pragma unroll
            for (int ks = 0; ks < 8; ++ks) am[ks] = *(const s8v*)(rp + ks * 32);
            f4v acc0 = {bs0, bs0, bs0, bs0};
            f4v acc1 = {bs1, bs1, bs1, bs1};
            #pragma unroll
            for (int ks = 0; ks < 8; ++ks) {
                acc0 = __builtin_amdgcn_mfma_f32_16x16x32_bf16(am[ks], b0[ks], acc0, 0, 0, 0);
                acc1 = __builtin_amdgcn_mfma_f32_16x16x32_bf16(am[ks], b1v[ks], acc1, 0, 0, 0);
            }
            #pragma unroll
            for (int r = 0; r < 4; ++r) {
                int row = t * 16 + (l >> 4) * 4 + r;
                float xn0 = acc0[r] + bfu(sOUT[row][col0]);
                float xn1 = acc1[r] + bfu(sOUT[row][col1]);
                Xb[(size_t)row * D_ + col0] = f2b(xn0);
                Xb[(size_t)row * D_ + col1] = f2b(xn1);
                ss0 += xn0; qq0 += xn0 * xn0;
                ss1 += xn1; qq1 += xn1 * xn1;
            }
        }
        atomicAdd(&sRED[col0], ss0); atomicAdd(&sRED[128 + col0], qq0);
        atomicAdd(&sRED[col1], ss1); atomicAdd(&sRED[128 + col1], qq1);
    }
    __syncthreads();
    {
        int slot = blockIdx.x & (NSLOT - 1);
        atomicAdd(&spart3[slot * 256 + TID], sRED[TID]);
    }
}

// =====================================================================
// Final pooling (with pending ab3 affine) + classifier
// =====================================================================
__global__ __launch_bounds__(128)
void poolcls_kernel(const bf16* __restrict__ gi, const float* __restrict__ ab,
                    const float* __restrict__ cw, const float* __restrict__ cb,
                    float* __restrict__ out)
{
    __shared__ float sP[128];
    int b = blockIdx.x, d = TID;
    const bf16* p = gi + (size_t)b * TN_ * D_ + d;
    float s = 0.f;
    for (int i = 0; i < TN_; ++i) s += b2f(p[i * D_]);
    sP[d] = (s * (1.f / TN_)) * ab[d] + ab[128 + d];
    __syncthreads();
    if (d < C_) {
        float acc = cb[d];
        for (int k = 0; k < D_; ++k) acc += sP[k] * cw[d * D_ + k];
        out[b * C_ + d] = acc;
    }
}

// =====================================================================
extern "C" void kernel_launch(void* const* d_in, const int* in_sizes, int n_in,
                              void* d_out, int out_size, void* d_ws, size_t ws_size,
                              hipStream_t stream)
{
    (void)in_sizes; (void)n_in; (void)out_size; (void)ws_size;

    const float* poses = (const float*)d_in[0];
    const float* emb_w = (const float*)d_in[1];
    const float* emb_b = (const float*)d_in[2];
    const float* cls_w = (const float*)d_in[3];
    const float* cls_b = (const float*)d_in[4];
    const float* jp[12]; const float* ip[12];
    for (int k = 0; k < 12; ++k) { jp[k] = (const float*)d_in[5 + k]; ip[k] = (const float*)d_in[17 + k]; }

    // ---- workspace layout ----
    char* base = (char*)d_ws;
    size_t off = 0;
    auto alloc_b = [&](size_t elems) -> bf16* {
        bf16* p = (bf16*)(base + off);
        off = (off + elems * sizeof(bf16) + 255) & ~(size_t)255;
        return p;
    };
    bf16* bufA  = alloc_b((size_t)R1_ * D_);
    bf16* bufB  = alloc_b((size_t)R1_ * D_);
    bf16* hbarJ = alloc_b((size_t)G1_ * D_);
    bf16* gcn1  = alloc_b((size_t)G1_ * D_);
    bf16* hbar2 = alloc_b((size_t)G2_ * D_);
    bf16* gcn2  = alloc_b((size_t)G2_ * D_);
    float* spart12 = (float*)(base + off); off += NSLOT * 512 * 4;
    float* spart3  = (float*)(base + off); off += NSLOT * 256 * 4;
    float* ab3     = (float*)(base + off); off += 256 * 4;
    float* ab12    = (float*)(base + off); off = (off + 512 * 4 + 255) & ~(size_t)255;
    bf16* wb[2][5];
    const int wsz[5] = {3 * D_ * D_, 3 * 3 * D_ * D_, 3 * D_ * D_, 3 * 2 * D_ * D_, 3 * 2 * D_ * D_};
    for (int s = 0; s < 2; ++s)
        for (int k = 0; k < 5; ++k) wb[s][k] = alloc_b((size_t)wsz[k]);

    const int widx[5] = {0, 2, 4, 8, 10};
    for (int s = 0; s < 2; ++s) {
        const float** P = s ? ip : jp;
        for (int k = 0; k < 5; ++k)
            wconv_kernel<<<(wsz[k] + 4095) / 4096, 256, 0, stream>>>(P[widx[k]], wb[s][k], wsz[k]);
    }
    zero_kernel<<<24, 256, 0, stream>>>(spart12, NSLOT * 512 + NSLOT * 256);

    embedv_kernel<<<4096, 256, 0, stream>>>(poses, emb_w, emb_b, bufA, R1_);

    auto run_stage = [&](const float** P, const bf16* const* W, bf16* h, bf16* t2,
                         bf16* hbar, bf16* gcn, int G, int n, int R) {
        setid_kernel<<<1, 128, 0, stream>>>(ab3);
        for (int L = 0; L < 3; ++L) {
            const bf16* gwb = W[0] + (size_t)L * D_ * D_;
            const bf16* qwb = W[1] + (size_t)L * 3 * D_ * D_;
            const bf16* owb = W[2] + (size_t)L * D_ * D_;
            const bf16* w1b = W[3] + (size_t)L * 2 * D_ * D_;
            const bf16* w2b = W[4] + (size_t)L * 2 * D_ * D_;
            const float* gb  = P[1] + (size_t)L * D_;
            const float* qb  = P[3] + (size_t)L * 3 * D_;
            const float* ob  = P[5] + (size_t)L * D_;
            const float* bng = P[6] + (size_t)L * 3 * D_;
            const float* bnb = P[7] + (size_t)L * 3 * D_;
            const float* b1  = P[9] + (size_t)L * 2 * D_;
            const float* b2  = P[11] + (size_t)L * D_;
            float rcount = 1.f / (float)R;

            gmeanv_kernel<<<G * 16 / 256, 256, 0, stream>>>(h, ab3, hbar, G, n);
            linear64_kernel<<<G / 64, 256, 0, stream>>>(hbar, gwb, gb, gcn);
            if (n == J_)
                attn_mfma_kernel<J_, 2><<<G / 2, 256, 0, stream>>>(h, ab3, gcn, qwb, qb, owb, ob, t2, spart12);
            else
                attn_mfma_kernel<NI_, 4><<<G / 4, 256, 0, stream>>>(h, ab3, gcn, qwb, qb, owb, ob, t2, spart12);
            finalize12_kernel<<<1, 128, 0, stream>>>(spart12, bng, bnb, rcount, ab12);
            mlp_mfma_kernel<<<R / 64, 256, 0, stream>>>(h, ab3, gcn, t2, ab12,
                                                        w1b, b1, w2b, b2, n, spart3);
            finalize3_kernel<<<1, 128, 0, stream>>>(spart3, bng + 2 * D_, bnb + 2 * D_,
                                                    rcount, ab3);
        }
    };

    // joint stage
    run_stage(jp, wb[0], bufA, bufB, hbarJ, gcn1, G1_, J_, R1_);
    // joint -> individual pooling
    gmeanv_kernel<<<G1_ * 16 / 256, 256, 0, stream>>>(bufA, ab3, hbarJ, G1_, J_);
    // individual stage
    run_stage(ip, wb[1], hbarJ, bufB, hbar2, gcn2, G2_, NI_, R2_);
    // final pooling + classifier
    poolcls_kernel<<<B_, 128, 0, stream>>>(hbarJ, ab3, cls_w, cls_b, (float*)d_out);
}

// Round 11
// 1428.865 us; speedup vs baseline: 16.9402x; 1.1824x over previous
//
#include <hip/hip_runtime.h>
#include <hip/hip_bf16.h>

#define TID threadIdx.x

typedef __hip_bfloat16 bf16;
typedef short s8v __attribute__((ext_vector_type(8)));
typedef float f4v __attribute__((ext_vector_type(4)));
typedef float f16v __attribute__((ext_vector_type(16)));

__device__ __forceinline__ float b2f(bf16 x) { return __bfloat162float(x); }
__device__ __forceinline__ bf16  f2b(float x) { return __float2bfloat16(x); }
__device__ __forceinline__ short f2s(float x) {
    __hip_bfloat16 b = __float2bfloat16(x); short s; __builtin_memcpy(&s, &b, 2); return s;
}
__device__ __forceinline__ float bfu(short s) {
    unsigned u = ((unsigned)(unsigned short)s) << 16; float f; __builtin_memcpy(&f, &u, 4); return f;
}

// ---- problem constants ----
#define B_   256
#define T_   7
#define NI_  12
#define TN_  84
#define J_   17
#define D_   128
#define H_   4
#define DH_  32
#define C_   8
#define G1_  21504       // B_*TN_
#define R1_  365568      // G1_*J_
#define G2_  1792        // B_*T_
#define R2_  21504       // G2_*NI_
#define EPS_ 1e-5f
#define NSLOT 32

// =====================================================================
__global__ __launch_bounds__(256)
void zero_kernel(float* __restrict__ p, int n)
{
    int stride = gridDim.x * 256;
    for (int i = blockIdx.x * 256 + TID; i < n; i += stride) p[i] = 0.f;
}

__global__ __launch_bounds__(128)
void setid_kernel(float* __restrict__ ab)
{
    ab[TID] = 1.f; ab[128 + TID] = 0.f;
}

// fp32 -> bf16 weight conversion
__global__ __launch_bounds__(256)
void wconv_kernel(const float* __restrict__ src, bf16* __restrict__ dst, int n)
{
    int stride = gridDim.x * 256;
    for (int i = blockIdx.x * 256 + TID; i < n; i += stride) dst[i] = f2b(src[i]);
}

// =====================================================================
// Embedding: h = leaky_relu(poses @ ew.T + eb)
// =====================================================================
__global__ __launch_bounds__(256)
void embedv_kernel(const float* __restrict__ poses, const float* __restrict__ ew,
                   const float* __restrict__ eb, bf16* __restrict__ h, int R)
{
    __shared__ float sE0[128], sE1[128], sEb[128];
    if (TID < 128) { sE0[TID] = ew[2 * TID]; sE1[TID] = ew[2 * TID + 1]; sEb[TID] = eb[TID]; }
    __syncthreads();
    int stride = gridDim.x * 256;
    for (int i8 = blockIdx.x * 256 + TID; i8 < R * 16; i8 += stride) {
        int r = i8 >> 4, c8 = (i8 & 15) * 8;
        float p0 = poses[2 * r], p1 = poses[2 * r + 1];
        s8v o;
        #pragma unroll
        for (int e = 0; e < 8; ++e) {
            int c = c8 + e;
            float v = p0 * sE0[c] + p1 * sE1[c] + sEb[c];
            o[e] = f2s(v > 0.f ? v : 0.01f * v);
        }
        *(s8v*)(h + (size_t)r * D_ + c8) = o;
    }
}

// =====================================================================
// Per-graph mean with pending-BN affine (used only for joint->ind pooling)
// =====================================================================
__global__ __launch_bounds__(256)
void gmeanv_kernel(const bf16* __restrict__ h, const float* __restrict__ ab,
                   bf16* __restrict__ hbar, int G, int n)
{
    int i8 = blockIdx.x * 256 + TID;
    if (i8 >= G * 16) return;
    int g = i8 >> 4, c8 = (i8 & 15) * 8;
    const bf16* p = h + (size_t)g * n * D_ + c8;
    float acc[8] = {0,0,0,0,0,0,0,0};
    for (int j = 0; j < n; ++j) {
        s8v v = *(const s8v*)(p + j * D_);
        #pragma unroll
        for (int e = 0; e < 8; ++e) acc[e] += bfu(v[e]);
    }
    float rn = 1.f / n;
    s8v o;
    #pragma unroll
    for (int e = 0; e < 8; ++e) {
        int c = c8 + e;
        o[e] = f2s(acc[e] * rn * ab[c] + ab[128 + c]);
    }
    *(s8v*)(hbar + (size_t)g * D_ + c8) = o;
}

// =====================================================================
// Fused attention + in-block GCN (mean + matvec) + BN1/BN2 stats.
// P overlaid into the dead K-slice of sQKV. 3 blocks/CU for n=17.
// =====================================================================
template<int NN, int NG>
__global__ __launch_bounds__(256)
void attn_mfma_kernel(const bf16* __restrict__ h, const float* __restrict__ ab3,
                      const bf16* __restrict__ gwb, const float* __restrict__ gb,
                      const bf16* __restrict__ qwb, const float* __restrict__ qb,
                      const bf16* __restrict__ owb, const float* __restrict__ ob,
                      bf16* __restrict__ out, bf16* __restrict__ gcnb,
                      float* __restrict__ spart)
{
    constexpr int ROWS = NG * NN;
    constexpr int MT = (ROWS + 15) / 16;
    constexpr int QP = 3 * D_ + 24;            // 408 shorts: 816B rows (≡48 mod 128)
    constexpr int HP = 152;                    // 304B rows
    constexpr int NPAIR = NG * H_;
    __shared__ __align__(16) short sQKV[MT * 16][QP];
    __shared__ __align__(16) short sHN[ROWS][HP];
    __shared__ __align__(16) short sHB[NG][128];
    __shared__ short sGCN[NG][128];
    __shared__ float sAB[256];

    const int l = TID & 63, wid = TID >> 6;
    const size_t gbase = (size_t)blockIdx.x * ROWS * D_;
    const bf16* hb = h + gbase;

    sAB[TID] = ab3[TID];
    __syncthreads();

    // ---------- phase 0: hn = affine(h) -> sHN ----------
    for (int task = TID; task < ROWS * 16; task += 256) {
        int row = task >> 4, c8 = (task & 15) * 8;
        s8v raw = *(const s8v*)(hb + (size_t)row * D_ + c8);
        s8v af;
        #pragma unroll
        for (int e = 0; e < 8; ++e) {
            int c = c8 + e;
            af[e] = f2s(bfu(raw[e]) * sAB[c] + sAB[128 + c]);
        }
        *(s8v*)(&sHN[row][c8]) = af;
    }
    __syncthreads();

    // A-frags for QKV GEMM (sHN stable from here on)
    s8v a[MT][4];
    #pragma unroll
    for (int t = 0; t < MT; ++t) {
        int row = t * 16 + (l & 15);
        if (row >= ROWS) row = ROWS - 1;
        const short* rp = &sHN[row][(l >> 4) * 8];
        #pragma unroll
        for (int ks = 0; ks < 4; ++ks) a[t][ks] = *(const s8v*)(rp + ks * 32);
    }

    // ---------- phase 0.5: hbar[g] = mean_j sHN[g*NN+j] ----------
    for (int task = TID; task < NG * D_; task += 256) {
        int g = task >> 7, col = task & 127;
        float s = 0.f;
        for (int j = 0; j < NN; ++j) s += bfu(sHN[g * NN + j][col]);
        sHB[g][col] = f2s(s * (1.f / NN));
    }
    __syncthreads();

    // ---------- phase 0.75: gcn = hbar @ gw.T + gb -> sGCN + global ----------
    {
        int rclamp = (l & 15) < NG ? (l & 15) : NG - 1;
        s8v ag[4];
        #pragma unroll
        for (int ks = 0; ks < 4; ++ks)
            ag[ks] = *(const s8v*)(&sHB[rclamp][ks * 32 + ((l >> 4) * 8)]);
        bf16* gout = gcnb + (size_t)blockIdx.x * NG * D_;
        #pragma unroll
        for (int ci = 0; ci < 2; ++ci) {
            int col = (wid * 2 + ci) * 16 + (l & 15);
            float bs = gb[col];
            f4v acc = {bs, bs, bs, bs};
            #pragma unroll
            for (int ks = 0; ks < 4; ++ks) {
                s8v b = *(const s8v*)(gwb + (size_t)col * D_ + ks * 32 + ((l >> 4) * 8));
                acc = __builtin_amdgcn_mfma_f32_16x16x32_bf16(ag[ks], b, acc, 0, 0, 0);
            }
            if ((l >> 4) == 0) {
                #pragma unroll
                for (int r = 0; r < NG; ++r) {
                    sGCN[r][col] = f2s(acc[r]);
                    gout[(size_t)r * D_ + col] = f2b(acc[r]);
                }
            }
        }
    }

    // ---------- phase 1: QKV = hn @ qw.T + qb ----------
    for (int nt = wid; nt < 24; nt += 4) {
        int col = nt * 16 + (l & 15);
        const bf16* wp = qwb + (size_t)col * D_ + ((l >> 4) * 8);
        s8v b[4];
        #pragma unroll
        for (int ks = 0; ks < 4; ++ks) b[ks] = *(const s8v*)(wp + ks * 32);
        float bs = qb[col];
        #pragma unroll
        for (int t = 0; t < MT; ++t) {
            f4v acc = {bs, bs, bs, bs};
            #pragma unroll
            for (int ks = 0; ks < 4; ++ks)
                acc = __builtin_amdgcn_mfma_f32_16x16x32_bf16(a[t][ks], b[ks], acc, 0, 0, 0);
            #pragma unroll
            for (int r = 0; r < 4; ++r)
                sQKV[t * 16 + (l >> 4) * 4 + r][col] = f2s(acc[r]);
        }
    }
    __syncthreads();

    // ---------- phases 2-3: per (g,h): S^T=K@Q^T -> softmax -> O=P@V ----------
    {
        const float inv = 0.17677669529663687f;   // 1/sqrt(32)
        const int l31 = l & 31, Gq = l >> 5;
        #pragma unroll
        for (int q = 0; q < NPAIR / 4; ++q) {
            int p = wid + 4 * q;
            int g = p >> 2, hd = p & 3;
            int gr = g * NN;
            int rr = gr + (l31 < NN ? l31 : NN - 1);
            s8v ka0 = *(const s8v*)(&sQKV[rr][D_ + hd * DH_ + Gq * 8]);
            s8v ka1 = *(const s8v*)(&sQKV[rr][D_ + hd * DH_ + Gq * 8 + 16]);
            s8v qb0 = *(const s8v*)(&sQKV[rr][hd * DH_ + Gq * 8]);
            s8v qb1 = *(const s8v*)(&sQKV[rr][hd * DH_ + Gq * 8 + 16]);
            f16v s = {};
            s = __builtin_amdgcn_mfma_f32_32x32x16_bf16(ka0, qb0, s, 0, 0, 0);
            s = __builtin_amdgcn_mfma_f32_32x32x16_bf16(ka1, qb1, s, 0, 0, 0);
            float m = -1e30f;
            #pragma unroll
            for (int r = 0; r < 16; ++r) {
                int j = (r & 3) + 8 * (r >> 2) + 4 * Gq;
                if (j < NN) m = fmaxf(m, s[r]);
            }
            m = fmaxf(m, __shfl_xor(m, 32));
            float pv[16]; float sum = 0.f;
            #pragma unroll
            for (int r = 0; r < 16; ++r) {
                int j = (r & 3) + 8 * (r >> 2) + 4 * Gq;
                float e = (j < NN) ? __expf((s[r] - m) * inv) : 0.f;
                pv[r] = e; sum += e;
            }
            sum += __shfl_xor(sum, 32);
            float rs = 1.f / sum;
            if (l31 < NN) {
                #pragma unroll
                for (int r = 0; r < 16; ++r) {
                    int j = (r & 3) + 8 * (r >> 2) + 4 * Gq;
                    sQKV[gr + l31][D_ + hd * DH_ + j] = f2s(pv[r] * rs); // 0 for j>=NN
                }
            }
            int prow = gr + l31; if (prow > MT * 16 - 1) prow = MT * 16 - 1;
            s8v pa0 = *(const s8v*)(&sQKV[prow][D_ + hd * DH_ + Gq * 8]);
            s8v pa1 = *(const s8v*)(&sQKV[prow][D_ + hd * DH_ + Gq * 8 + 16]);
            s8v vb0, vb1;
            #pragma unroll
            for (int e = 0; e < 8; ++e) {
                int j0 = Gq * 8 + e;      int jj0 = j0 < NN ? j0 : 0;
                int j1 = 16 + Gq * 8 + e; int jj1 = j1 < NN ? j1 : 0;
                vb0[e] = sQKV[gr + jj0][2 * D_ + hd * DH_ + l31];
                vb1[e] = sQKV[gr + jj1][2 * D_ + hd * DH_ + l31];
            }
            f16v o = {};
            o = __builtin_amdgcn_mfma_f32_32x32x16_bf16(pa0, vb0, o, 0, 0, 0);
            o = __builtin_amdgcn_mfma_f32_32x32x16_bf16(pa1, vb1, o, 0, 0, 0);
            #pragma unroll
            for (int r = 0; r < 16; ++r) {
                int i = (r & 3) + 8 * (r >> 2) + 4 * Gq;
                if (i < NN) sQKV[gr + i][hd * DH_ + l31] = f2s(o[r]);  // O -> Q slot
            }
        }
    }
    __syncthreads();

    // ---------- phase 4: t2 = O @ ow.T + ob + hn ; stats via shfl-reduce ----------
    bf16* og = out + gbase;
    #pragma unroll
    for (int t = 0; t < MT; ++t) {
        int row = t * 16 + (l & 15);
        if (row >= ROWS) row = ROWS - 1;
        const short* rp = &sQKV[row][(l >> 4) * 8];
        #pragma unroll
        for (int ks = 0; ks < 4; ++ks) a[t][ks] = *(const s8v*)(rp + ks * 32);
    }
    const int slot = blockIdx.x & (NSLOT - 1);
    #pragma unroll
    for (int ni = 0; ni < 2; ++ni) {
        int nt = wid + 4 * ni;
        int col = nt * 16 + (l & 15);
        const bf16* wp = owb + (size_t)col * D_ + ((l >> 4) * 8);
        s8v b[4];
        #pragma unroll
        for (int ks = 0; ks < 4; ++ks) b[ks] = *(const s8v*)(wp + ks * 32);
        float bs = ob[col];
        float s1 = 0.f, q1 = 0.f, s2 = 0.f, q2 = 0.f;
        #pragma unroll
        for (int t = 0; t < MT; ++t) {
            f4v acc = {bs, bs, bs, bs};
            #pragma unroll
            for (int ks = 0; ks < 4; ++ks)
                acc = __builtin_amdgcn_mfma_f32_16x16x32_bf16(a[t][ks], b[ks], acc, 0, 0, 0);
            #pragma unroll
            for (int r = 0; r < 4; ++r) {
                int row = t * 16 + (l >> 4) * 4 + r;
                if (row < ROWS) {
                    float res = bfu(sHN[row][col]);
                    float t2v = acc[r] + res;
                    og[(size_t)row * D_ + col] = f2b(t2v);
                    s2 += t2v; q2 += t2v * t2v;
                    int g = row / NN;
                    float x1 = res + bfu(sGCN[g][col]);
                    s1 += x1; q1 += x1 * x1;
                }
            }
        }
        // lanes {l, l^16, l^32, l^48} share col -> reduce, then 1 atomic set
        s1 += __shfl_xor(s1, 16); s1 += __shfl_xor(s1, 32);
        q1 += __shfl_xor(q1, 16); q1 += __shfl_xor(q1, 32);
        s2 += __shfl_xor(s2, 16); s2 += __shfl_xor(s2, 32);
        q2 += __shfl_xor(q2, 16); q2 += __shfl_xor(q2, 32);
        if ((l >> 4) == 0) {
            atomicAdd(&spart[slot * 512 + col], s1);
            atomicAdd(&spart[slot * 512 + 128 + col], q1);
            atomicAdd(&spart[slot * 512 + 256 + col], s2);
            atomicAdd(&spart[slot * 512 + 384 + col], q2);
        }
    }
}

// =====================================================================
// finalize BN1+BN2: reduce partial slots -> affine; re-zero
// =====================================================================
__global__ __launch_bounds__(128)
void finalize12_kernel(float* __restrict__ spart, const float* __restrict__ bng,
                       const float* __restrict__ bnb, float rcount,
                       float* __restrict__ ab12)
{
    int c = TID;
    float s1 = 0, q1 = 0, s2 = 0, q2 = 0;
    for (int s = 0; s < NSLOT; ++s) {
        float* p = spart + s * 512;
        s1 += p[c]; q1 += p[128 + c]; s2 += p[256 + c]; q2 += p[384 + c];
        p[c] = 0.f; p[128 + c] = 0.f; p[256 + c] = 0.f; p[384 + c] = 0.f;
    }
    float m1 = s1 * rcount, v1 = q1 * rcount - m1 * m1;
    float a1 = rsqrtf(v1 + EPS_) * bng[c];
    ab12[c] = a1; ab12[128 + c] = bnb[c] - m1 * a1;
    float m2 = s2 * rcount, v2 = q2 * rcount - m2 * m2;
    float a2 = rsqrtf(v2 + EPS_) * bng[128 + c];
    ab12[256 + c] = a2; ab12[384 + c] = bnb[128 + c] - m2 * a2;
}

// finalize BN3 -> ab3; re-zero partials
__global__ __launch_bounds__(128)
void finalize3_kernel(float* __restrict__ spart, const float* __restrict__ gamma,
                      const float* __restrict__ beta, float rcount,
                      float* __restrict__ ab3)
{
    int c = TID;
    float s1 = 0, q1 = 0;
    for (int s = 0; s < NSLOT; ++s) {
        float* p = spart + s * 256;
        s1 += p[c]; q1 += p[128 + c];
        p[c] = 0.f; p[128 + c] = 0.f;
    }
    float m = s1 * rcount, v = q1 * rcount - m * m;
    float a = rsqrtf(v + EPS_) * gamma[c];
    ab3[c] = a; ab3[128 + c] = beta[c] - m * a;
}

// =====================================================================
// Fused MLP — LDS 54272B -> 3 blocks/CU; stats via shfl-reduce
// =====================================================================
__global__ __launch_bounds__(256)
void mlp_mfma_kernel(bf16* __restrict__ X, const float* __restrict__ ab3,
                     const bf16* __restrict__ gcn, const bf16* __restrict__ t2,
                     const float* __restrict__ ab12,
                     const bf16* __restrict__ w1b, const float* __restrict__ b1,
                     const bf16* __restrict__ w2b, const float* __restrict__ b2,
                     int n, float* __restrict__ spart3)
{
    constexpr int MP = 264;
    __shared__ short sM[64][MP];
    __shared__ short sOUT[64][136];
    __shared__ float sAB[768];
    const int l = TID & 63, wid = TID >> 6;
    const size_t rbase = (size_t)blockIdx.x * 64;
    bf16* Xb = X + rbase * D_;
    const bf16* Tb = t2 + rbase * D_;

    sAB[TID] = ab3[TID];
    for (int i = TID; i < 512; i += 256) sAB[256 + i] = ab12[i];
    __syncthreads();

    {
        int row = TID >> 2;
        int cb0 = (TID & 3) * 32;
        int g = (int)((rbase + row) / n);
        #pragma unroll
        for (int k2 = 0; k2 < 4; ++k2) {
            int cb = cb0 + k2 * 8;
            s8v xv = *(const s8v*)(Xb + (size_t)row * D_ + cb);
            s8v gv = *(const s8v*)(gcn + (size_t)g * D_ + cb);
            s8v tv = *(const s8v*)(Tb + (size_t)row * D_ + cb);
            s8v af;
            #pragma unroll
            for (int e = 0; e < 8; ++e) {
                int c = cb + e;
                float hn = bfu(xv[e]) * sAB[c] + sAB[128 + c];
                float outv = (hn + bfu(gv[e])) * sAB[256 + c] + sAB[384 + c]
                           + bfu(tv[e]) * sAB[512 + c] + sAB[640 + c];
                af[e] = f2s(outv);
            }
            *(s8v*)(&sOUT[row][cb]) = af;
        }
    }
    __syncthreads();

    s8v a[4][4];
    #pragma unroll
    for (int t = 0; t < 4; ++t) {
        const short* rp = &sOUT[t * 16 + (l & 15)][(l >> 4) * 8];
        #pragma unroll
        for (int ks = 0; ks < 4; ++ks) a[t][ks] = *(const s8v*)(rp + ks * 32);
    }
    for (int nt = wid; nt < 16; nt += 4) {
        int col = nt * 16 + (l & 15);
        const bf16* wp = w1b + (size_t)col * D_ + ((l >> 4) * 8);
        s8v b[4];
        #pragma unroll
        for (int ks = 0; ks < 4; ++ks) b[ks] = *(const s8v*)(wp + ks * 32);
        float bs = b1[col];
        #pragma unroll
        for (int t = 0; t < 4; ++t) {
            f4v acc = {bs, bs, bs, bs};
            #pragma unroll
            for (int ks = 0; ks < 4; ++ks)
                acc = __builtin_amdgcn_mfma_f32_16x16x32_bf16(a[t][ks], b[ks], acc, 0, 0, 0);
            #pragma unroll
            for (int r = 0; r < 4; ++r)
                sM[t * 16 + (l >> 4) * 4 + r][col] = f2s(fmaxf(acc[r], 0.f));
        }
    }
    __syncthreads();

    {
        const int nt0 = wid * 2;
        const int col0 = nt0 * 16 + (l & 15), col1 = col0 + 16;
        s8v b0[8], b1v[8];
        #pragma unroll
        for (int ks = 0; ks < 8; ++ks) {
            b0[ks]  = *(const s8v*)(w2b + (size_t)col0 * 256 + ks * 32 + ((l >> 4) * 8));
            b1v[ks] = *(const s8v*)(w2b + (size_t)col1 * 256 + ks * 32 + ((l >> 4) * 8));
        }
        float bs0 = b2[col0], bs1 = b2[col1];
        float ss0 = 0.f, qq0 = 0.f, ss1 = 0.f, qq1 = 0.f;
        #pragma unroll
        for (int t = 0; t < 4; ++t) {
            s8v am[8];
            const short* rp = &sM[t * 16 + (l & 15)][(l >> 4) * 8];
            #pragma unroll
            for (int ks = 0; ks < 8; ++ks) am[ks] = *(const s8v*)(rp + ks * 32);
            f4v acc0 = {bs0, bs0, bs0, bs0};
            f4v acc1 = {bs1, bs1, bs1, bs1};
            #pragma unroll
            for (int ks = 0; ks < 8; ++ks) {
                acc0 = __builtin_amdgcn_mfma_f32_16x16x32_bf16(am[ks], b0[ks], acc0, 0, 0, 0);
                acc1 = __builtin_amdgcn_mfma_f32_16x16x32_bf16(am[ks], b1v[ks], acc1, 0, 0, 0);
            }
            #pragma unroll
            for (int r = 0; r < 4; ++r) {
                int row = t * 16 + (l >> 4) * 4 + r;
                float xn0 = acc0[r] + bfu(sOUT[row][col0]);
                float xn1 = acc1[r] + bfu(sOUT[row][col1]);
                Xb[(size_t)row * D_ + col0] = f2b(xn0);
                Xb[(size_t)row * D_ + col1] = f2b(xn1);
                ss0 += xn0; qq0 += xn0 * xn0;
                ss1 += xn1; qq1 += xn1 * xn1;
            }
        }
        ss0 += __shfl_xor(ss0, 16); ss0 += __shfl_xor(ss0, 32);
        qq0 += __shfl_xor(qq0, 16); qq0 += __shfl_xor(qq0, 32);
        ss1 += __shfl_xor(ss1, 16); ss1 += __shfl_xor(ss1, 32);
        qq1 += __shfl_xor(qq1, 16); qq1 += __shfl_xor(qq1, 32);
        if ((l >> 4) == 0) {
            int slot = blockIdx.x & (NSLOT - 1);
            atomicAdd(&spart3[slot * 256 + col0], ss0);
            atomicAdd(&spart3[slot * 256 + 128 + col0], qq0);
            atomicAdd(&spart3[slot * 256 + col1], ss1);
            atomicAdd(&spart3[slot * 256 + 128 + col1], qq1);
        }
    }
}

// =====================================================================
// Final pooling (with pending ab3 affine) + classifier
// =====================================================================
__global__ __launch_bounds__(128)
void poolcls_kernel(const bf16* __restrict__ gi, const float* __restrict__ ab,
                    const float* __restrict__ cw, const float* __restrict__ cb,
                    float* __restrict__ out)
{
    __shared__ float sP[128];
    int b = blockIdx.x, d = TID;
    const bf16* p = gi + (size_t)b * TN_ * D_ + d;
    float s = 0.f;
    for (int i = 0; i < TN_; ++i) s += b2f(p[i * D_]);
    sP[d] = (s * (1.f / TN_)) * ab[d] + ab[128 + d];
    __syncthreads();
    if (d < C_) {
        float acc = cb[d];
        for (int k = 0; k < D_; ++k) acc += sP[k] * cw[d * D_ + k];
        out[b * C_ + d] = acc;
    }
}

// =====================================================================
extern "C" void kernel_launch(void* const* d_in, const int* in_sizes, int n_in,
                              void* d_out, int out_size, void* d_ws, size_t ws_size,
                              hipStream_t stream)
{
    (void)in_sizes; (void)n_in; (void)out_size; (void)ws_size;

    const float* poses = (const float*)d_in[0];
    const float* emb_w = (const float*)d_in[1];
    const float* emb_b = (const float*)d_in[2];
    const float* cls_w = (const float*)d_in[3];
    const float* cls_b = (const float*)d_in[4];
    const float* jp[12]; const float* ip[12];
    for (int k = 0; k < 12; ++k) { jp[k] = (const float*)d_in[5 + k]; ip[k] = (const float*)d_in[17 + k]; }

    // ---- workspace layout ----
    char* base = (char*)d_ws;
    size_t off = 0;
    auto alloc_b = [&](size_t elems) -> bf16* {
        bf16* p = (bf16*)(base + off);
        off = (off + elems * sizeof(bf16) + 255) & ~(size_t)255;
        return p;
    };
    bf16* bufA  = alloc_b((size_t)R1_ * D_);
    bf16* bufB  = alloc_b((size_t)R1_ * D_);
    bf16* hbarJ = alloc_b((size_t)G1_ * D_);
    bf16* gcn1  = alloc_b((size_t)G1_ * D_);
    bf16* gcn2  = alloc_b((size_t)G2_ * D_);
    float* spart12 = (float*)(base + off); off += NSLOT * 512 * 4;
    float* spart3  = (float*)(base + off); off += NSLOT * 256 * 4;
    float* ab3     = (float*)(base + off); off += 256 * 4;
    float* ab12    = (float*)(base + off); off = (off + 512 * 4 + 255) & ~(size_t)255;
    bf16* wb[2][5];
    const int wsz[5] = {3 * D_ * D_, 3 * 3 * D_ * D_, 3 * D_ * D_, 3 * 2 * D_ * D_, 3 * 2 * D_ * D_};
    for (int s = 0; s < 2; ++s)
        for (int k = 0; k < 5; ++k) wb[s][k] = alloc_b((size_t)wsz[k]);

    const int widx[5] = {0, 2, 4, 8, 10};
    for (int s = 0; s < 2; ++s) {
        const float** P = s ? ip : jp;
        for (int k = 0; k < 5; ++k)
            wconv_kernel<<<(wsz[k] + 4095) / 4096, 256, 0, stream>>>(P[widx[k]], wb[s][k], wsz[k]);
    }
    zero_kernel<<<24, 256, 0, stream>>>(spart12, NSLOT * 512 + NSLOT * 256);

    embedv_kernel<<<4096, 256, 0, stream>>>(poses, emb_w, emb_b, bufA, R1_);

    auto run_stage = [&](const float** P, const bf16* const* W, bf16* h, bf16* t2,
                         bf16* gcn, int G, int n, int R) {
        setid_kernel<<<1, 128, 0, stream>>>(ab3);
        for (int L = 0; L < 3; ++L) {
            const bf16* gwb = W[0] + (size_t)L * D_ * D_;
            const bf16* qwb = W[1] + (size_t)L * 3 * D_ * D_;
            const bf16* owb = W[2] + (size_t)L * D_ * D_;
            const bf16* w1b = W[3] + (size_t)L * 2 * D_ * D_;
            const bf16* w2b = W[4] + (size_t)L * 2 * D_ * D_;
            const float* gb  = P[1] + (size_t)L * D_;
            const float* qb  = P[3] + (size_t)L * 3 * D_;
            const float* ob  = P[5] + (size_t)L * D_;
            const float* bng = P[6] + (size_t)L * 3 * D_;
            const float* bnb = P[7] + (size_t)L * 3 * D_;
            const float* b1  = P[9] + (size_t)L * 2 * D_;
            const float* b2  = P[11] + (size_t)L * D_;
            float rcount = 1.f / (float)R;

            if (n == J_)
                attn_mfma_kernel<J_, 2><<<G / 2, 256, 0, stream>>>(
                    h, ab3, gwb, gb, qwb, qb, owb, ob, t2, gcn, spart12);
            else
                attn_mfma_kernel<NI_, 4><<<G / 4, 256, 0, stream>>>(
                    h, ab3, gwb, gb, qwb, qb, owb, ob, t2, gcn, spart12);
            finalize12_kernel<<<1, 128, 0, stream>>>(spart12, bng, bnb, rcount, ab12);
            mlp_mfma_kernel<<<R / 64, 256, 0, stream>>>(h, ab3, gcn, t2, ab12,
                                                        w1b, b1, w2b, b2, n, spart3);
            finalize3_kernel<<<1, 128, 0, stream>>>(spart3, bng + 2 * D_, bnb + 2 * D_,
                                                    rcount, ab3);
        }
    };

    // joint stage
    run_stage(jp, wb[0], bufA, bufB, gcn1, G1_, J_, R1_);
    // joint -> individual pooling (applies joint-final ab3 after the mean)
    gmeanv_kernel<<<G1_ * 16 / 256, 256, 0, stream>>>(bufA, ab3, hbarJ, G1_, J_);
    // individual stage
    run_stage(ip, wb[1], hbarJ, bufB, gcn2, G2_, NI_, R2_);
    // final pooling + classifier
    poolcls_kernel<<<B_, 128, 0, stream>>>(hbarJ, ab3, cls_w, cls_b, (float*)d_out);
}

// Round 13
// 1405.987 us; speedup vs baseline: 17.2158x; 1.0163x over previous
//
#include <hip/hip_runtime.h>
#include <hip/hip_bf16.h>

#define TID threadIdx.x

typedef __hip_bfloat16 bf16;
typedef short s8v __attribute__((ext_vector_type(8)));
typedef float f4v __attribute__((ext_vector_type(4)));
typedef float f16v __attribute__((ext_vector_type(16)));

__device__ __forceinline__ float b2f(bf16 x) { return __bfloat162float(x); }
__device__ __forceinline__ bf16  f2b(float x) { return __float2bfloat16(x); }
__device__ __forceinline__ short f2s(float x) {
    __hip_bfloat16 b = __float2bfloat16(x); short s; __builtin_memcpy(&s, &b, 2); return s;
}
__device__ __forceinline__ float bfu(short s) {
    unsigned u = ((unsigned)(unsigned short)s) << 16; float f; __builtin_memcpy(&f, &u, 4); return f;
}

// ---- problem constants ----
#define B_   256
#define T_   7
#define NI_  12
#define TN_  84
#define J_   17
#define D_   128
#define H_   4
#define DH_  32
#define C_   8
#define G1_  21504       // B_*TN_
#define R1_  365568      // G1_*J_
#define G2_  1792        // B_*T_
#define R2_  21504       // G2_*NI_
#define EPS_ 1e-5f
#define NSLOT 32

// =====================================================================
__global__ __launch_bounds__(256)
void zero_kernel(float* __restrict__ p, int n)
{
    int stride = gridDim.x * 256;
    for (int i = blockIdx.x * 256 + TID; i < n; i += stride) p[i] = 0.f;
}

__global__ __launch_bounds__(128)
void setid_kernel(float* __restrict__ ab)
{
    ab[TID] = 1.f; ab[128 + TID] = 0.f;
}

// fp32 -> bf16 conversion of the 5 weight tensors of one stage (1 launch)
// segment sizes: gw 3DD, qw 9DD, ow 3DD, w1 6DD, w2 6DD  (DD = 16384)
__global__ __launch_bounds__(256)
void wconv5_kernel(const float* __restrict__ s0, const float* __restrict__ s1,
                   const float* __restrict__ s2, const float* __restrict__ s3,
                   const float* __restrict__ s4,
                   bf16* __restrict__ d0, bf16* __restrict__ d1,
                   bf16* __restrict__ d2, bf16* __restrict__ d3,
                   bf16* __restrict__ d4)
{
    const int DD = D_ * D_;
    const int n0 = 3 * DD, n1 = 9 * DD, n2 = 3 * DD, n3 = 6 * DD;
    const int e0 = n0, e1 = e0 + n1, e2 = e1 + n2, e3 = e2 + n3, e4 = e3 + 6 * DD;
    int stride = gridDim.x * 256;
    for (int i = blockIdx.x * 256 + TID; i < e4; i += stride) {
        if (i < e0)      d0[i]      = f2b(s0[i]);
        else if (i < e1) d1[i - e0] = f2b(s1[i - e0]);
        else if (i < e2) d2[i - e1] = f2b(s2[i - e1]);
        else if (i < e3) d3[i - e2] = f2b(s3[i - e2]);
        else             d4[i - e3] = f2b(s4[i - e3]);
    }
}

// =====================================================================
// Embedding: h = leaky_relu(poses @ ew.T + eb)
// =====================================================================
__global__ __launch_bounds__(256)
void embedv_kernel(const float* __restrict__ poses, const float* __restrict__ ew,
                   const float* __restrict__ eb, bf16* __restrict__ h, int R)
{
    __shared__ float sE0[128], sE1[128], sEb[128];
    if (TID < 128) { sE0[TID] = ew[2 * TID]; sE1[TID] = ew[2 * TID + 1]; sEb[TID] = eb[TID]; }
    __syncthreads();
    int stride = gridDim.x * 256;
    for (int i8 = blockIdx.x * 256 + TID; i8 < R * 16; i8 += stride) {
        int r = i8 >> 4, c8 = (i8 & 15) * 8;
        float p0 = poses[2 * r], p1 = poses[2 * r + 1];
        s8v o;
        #pragma unroll
        for (int e = 0; e < 8; ++e) {
            int c = c8 + e;
            float v = p0 * sE0[c] + p1 * sE1[c] + sEb[c];
            o[e] = f2s(v > 0.f ? v : 0.01f * v);
        }
        *(s8v*)(h + (size_t)r * D_ + c8) = o;
    }
}

// =====================================================================
// Per-graph mean with pending-BN affine (used only for joint->ind pooling)
// =====================================================================
__global__ __launch_bounds__(256)
void gmeanv_kernel(const bf16* __restrict__ h, const float* __restrict__ ab,
                   bf16* __restrict__ hbar, int G, int n)
{
    int i8 = blockIdx.x * 256 + TID;
    if (i8 >= G * 16) return;
    int g = i8 >> 4, c8 = (i8 & 15) * 8;
    const bf16* p = h + (size_t)g * n * D_ + c8;
    float acc[8] = {0,0,0,0,0,0,0,0};
    for (int j = 0; j < n; ++j) {
        s8v v = *(const s8v*)(p + j * D_);
        #pragma unroll
        for (int e = 0; e < 8; ++e) acc[e] += bfu(v[e]);
    }
    float rn = 1.f / n;
    s8v o;
    #pragma unroll
    for (int e = 0; e < 8; ++e) {
        int c = c8 + e;
        o[e] = f2s(acc[e] * rn * ab[c] + ab[128 + c]);
    }
    *(s8v*)(hbar + (size_t)g * D_ + c8) = o;
}

// =====================================================================
// Fused attention + in-block GCN (mean + matvec) + BN1/BN2 stats.
// sQKV trimmed to ROWS rows (34 for n=17) -> 39.6KB LDS -> 4 blocks/CU.
// =====================================================================
template<int NN, int NG>
__global__ __launch_bounds__(256)
void attn_mfma_kernel(const bf16* __restrict__ h, const float* __restrict__ ab3,
                      const bf16* __restrict__ gwb, const float* __restrict__ gb,
                      const bf16* __restrict__ qwb, const float* __restrict__ qb,
                      const bf16* __restrict__ owb, const float* __restrict__ ob,
                      bf16* __restrict__ out, bf16* __restrict__ gcnb,
                      float* __restrict__ spart)
{
    constexpr int ROWS = NG * NN;
    constexpr int MT = (ROWS + 15) / 16;
    constexpr int QP = 3 * D_ + 16;            // 400 shorts: 800B rows (16B-aligned)
    constexpr int HP = 152;                    // 304B rows
    constexpr int NPAIR = NG * H_;
    __shared__ __align__(16) short sQKV[ROWS][QP];
    __shared__ __align__(16) short sHN[ROWS][HP];
    __shared__ __align__(16) short sHB[NG][128];
    __shared__ short sGCN[NG][128];
    __shared__ float sAB[256];

    const int l = TID & 63, wid = TID >> 6;
    const size_t gbase = (size_t)blockIdx.x * ROWS * D_;
    const bf16* hb = h + gbase;

    sAB[TID] = ab3[TID];
    __syncthreads();

    // ---------- phase 0: hn = affine(h) -> sHN ----------
    for (int task = TID; task < ROWS * 16; task += 256) {
        int row = task >> 4, c8 = (task & 15) * 8;
        s8v raw = *(const s8v*)(hb + (size_t)row * D_ + c8);
        s8v af;
        #pragma unroll
        for (int e = 0; e < 8; ++e) {
            int c = c8 + e;
            af[e] = f2s(bfu(raw[e]) * sAB[c] + sAB[128 + c]);
        }
        *(s8v*)(&sHN[row][c8]) = af;
    }
    __syncthreads();

    // A-frags for QKV GEMM (sHN stable from here on)
    s8v a[MT][4];
    #pragma unroll
    for (int t = 0; t < MT; ++t) {
        int row = t * 16 + (l & 15);
        if (row >= ROWS) row = ROWS - 1;
        const short* rp = &sHN[row][(l >> 4) * 8];
        #pragma unroll
        for (int ks = 0; ks < 4; ++ks) a[t][ks] = *(const s8v*)(rp + ks * 32);
    }

    // ---------- phase 0.5: hbar[g] = mean_j sHN[g*NN+j] ----------
    for (int task = TID; task < NG * D_; task += 256) {
        int g = task >> 7, col = task & 127;
        float s = 0.f;
        for (int j = 0; j < NN; ++j) s += bfu(sHN[g * NN + j][col]);
        sHB[g][col] = f2s(s * (1.f / NN));
    }
    __syncthreads();

    // ---------- phase 0.75: gcn = hbar @ gw.T + gb -> sGCN + global ----------
    {
        int rclamp = (l & 15) < NG ? (l & 15) : NG - 1;
        s8v ag[4];
        #pragma unroll
        for (int ks = 0; ks < 4; ++ks)
            ag[ks] = *(const s8v*)(&sHB[rclamp][ks * 32 + ((l >> 4) * 8)]);
        bf16* gout = gcnb + (size_t)blockIdx.x * NG * D_;
        #pragma unroll
        for (int ci = 0; ci < 2; ++ci) {
            int col = (wid * 2 + ci) * 16 + (l & 15);
            float bs = gb[col];
            f4v acc = {bs, bs, bs, bs};
            #pragma unroll
            for (int ks = 0; ks < 4; ++ks) {
                s8v b = *(const s8v*)(gwb + (size_t)col * D_ + ks * 32 + ((l >> 4) * 8));
                acc = __builtin_amdgcn_mfma_f32_16x16x32_bf16(ag[ks], b, acc, 0, 0, 0);
            }
            if ((l >> 4) == 0) {
                #pragma unroll
                for (int r = 0; r < NG; ++r) {
                    sGCN[r][col] = f2s(acc[r]);
                    gout[(size_t)r * D_ + col] = f2b(acc[r]);
                }
            }
        }
    }

    // ---------- phase 1: QKV = hn @ qw.T + qb ----------
    for (int nt = wid; nt < 24; nt += 4) {
        int col = nt * 16 + (l & 15);
        const bf16* wp = qwb + (size_t)col * D_ + ((l >> 4) * 8);
        s8v b[4];
        #pragma unroll
        for (int ks = 0; ks < 4; ++ks) b[ks] = *(const s8v*)(wp + ks * 32);
        float bs = qb[col];
        #pragma unroll
        for (int t = 0; t < MT; ++t) {
            f4v acc = {bs, bs, bs, bs};
            #pragma unroll
            for (int ks = 0; ks < 4; ++ks)
                acc = __builtin_amdgcn_mfma_f32_16x16x32_bf16(a[t][ks], b[ks], acc, 0, 0, 0);
            #pragma unroll
            for (int r = 0; r < 4; ++r) {
                int row2 = t * 16 + (l >> 4) * 4 + r;
                if (row2 < ROWS) sQKV[row2][col] = f2s(acc[r]);
            }
        }
    }
    __syncthreads();

    // ---------- phases 2-3: per (g,h): S^T=K@Q^T -> softmax -> O=P@V ----------
    {
        const float inv = 0.17677669529663687f;   // 1/sqrt(32)
        const int l31 = l & 31, Gq = l >> 5;
        #pragma unroll
        for (int q = 0; q < NPAIR / 4; ++q) {
            int p = wid + 4 * q;
            int g = p >> 2, hd = p & 3;
            int gr = g * NN;
            int rr = gr + (l31 < NN ? l31 : NN - 1);
            s8v ka0 = *(const s8v*)(&sQKV[rr][D_ + hd * DH_ + Gq * 8]);
            s8v ka1 = *(const s8v*)(&sQKV[rr][D_ + hd * DH_ + Gq * 8 + 16]);
            s8v qb0 = *(const s8v*)(&sQKV[rr][hd * DH_ + Gq * 8]);
            s8v qb1 = *(const s8v*)(&sQKV[rr][hd * DH_ + Gq * 8 + 16]);
            f16v s = {};
            s = __builtin_amdgcn_mfma_f32_32x32x16_bf16(ka0, qb0, s, 0, 0, 0);
            s = __builtin_amdgcn_mfma_f32_32x32x16_bf16(ka1, qb1, s, 0, 0, 0);
            float m = -1e30f;
            #pragma unroll
            for (int r = 0; r < 16; ++r) {
                int j = (r & 3) + 8 * (r >> 2) + 4 * Gq;
                if (j < NN) m = fmaxf(m, s[r]);
            }
            m = fmaxf(m, __shfl_xor(m, 32));
            float pv[16]; float sum = 0.f;
            #pragma unroll
            for (int r = 0; r < 16; ++r) {
                int j = (r & 3) + 8 * (r >> 2) + 4 * Gq;
                float e = (j < NN) ? __expf((s[r] - m) * inv) : 0.f;
                pv[r] = e; sum += e;
            }
            sum += __shfl_xor(sum, 32);
            float rs = 1.f / sum;
            if (l31 < NN) {
                #pragma unroll
                for (int r = 0; r < 16; ++r) {
                    int j = (r & 3) + 8 * (r >> 2) + 4 * Gq;
                    sQKV[gr + l31][D_ + hd * DH_ + j] = f2s(pv[r] * rs); // 0 for j>=NN
                }
            }
            int prow = gr + l31; if (prow > ROWS - 1) prow = ROWS - 1;
            s8v pa0 = *(const s8v*)(&sQKV[prow][D_ + hd * DH_ + Gq * 8]);
            s8v pa1 = *(const s8v*)(&sQKV[prow][D_ + hd * DH_ + Gq * 8 + 16]);
            s8v vb0, vb1;
            #pragma unroll
            for (int e = 0; e < 8; ++e) {
                int j0 = Gq * 8 + e;      int jj0 = j0 < NN ? j0 : 0;
                int j1 = 16 + Gq * 8 + e; int jj1 = j1 < NN ? j1 : 0;
                vb0[e] = sQKV[gr + jj0][2 * D_ + hd * DH_ + l31];
                vb1[e] = sQKV[gr + jj1][2 * D_ + hd * DH_ + l31];
            }
            f16v o = {};
            o = __builtin_amdgcn_mfma_f32_32x32x16_bf16(pa0, vb0, o, 0, 0, 0);
            o = __builtin_amdgcn_mfma_f32_32x32x16_bf16(pa1, vb1, o, 0, 0, 0);
            #pragma unroll
            for (int r = 0; r < 16; ++r) {
                int i = (r & 3) + 8 * (r >> 2) + 4 * Gq;
                if (i < NN) sQKV[gr + i][hd * DH_ + l31] = f2s(o[r]);  // O -> Q slot
            }
        }
    }
    __syncthreads();

    // ---------- phase 4: t2 = O @ ow.T + ob + hn ; stats via shfl-reduce ----------
    bf16* og = out + gbase;
    #pragma unroll
    for (int t = 0; t < MT; ++t) {
        int row = t * 16 + (l & 15);
        if (row >= ROWS) row = ROWS - 1;
        const short* rp = &sQKV[row][(l >> 4) * 8];
        #pragma unroll
        for (int ks = 0; ks < 4; ++ks) a[t][ks] = *(const s8v*)(rp + ks * 32);
    }
    const int slot = blockIdx.x & (NSLOT - 1);
    #pragma unroll
    for (int ni = 0; ni < 2; ++ni) {
        int nt = wid + 4 * ni;
        int col = nt * 16 + (l & 15);
        const bf16* wp = owb + (size_t)col * D_ + ((l >> 4) * 8);
        s8v b[4];
        #pragma unroll
        for (int ks = 0; ks < 4; ++ks) b[ks] = *(const s8v*)(wp + ks * 32);
        float bs = ob[col];
        float s1 = 0.f, q1 = 0.f, s2 = 0.f, q2 = 0.f;
        #pragma unroll
        for (int t = 0; t < MT; ++t) {
            f4v acc = {bs, bs, bs, bs};
            #pragma unroll
            for (int ks = 0; ks < 4; ++ks)
                acc = __builtin_amdgcn_mfma_f32_16x16x32_bf16(a[t][ks], b[ks], acc, 0, 0, 0);
            #pragma unroll
            for (int r = 0; r < 4; ++r) {
                int row = t * 16 + (l >> 4) * 4 + r;
                if (row < ROWS) {
                    float res = bfu(sHN[row][col]);
                    float t2v = acc[r] + res;
                    og[(size_t)row * D_ + col] = f2b(t2v);
                    s2 += t2v; q2 += t2v * t2v;
                    int g = row / NN;
                    float x1 = res + bfu(sGCN[g][col]);
                    s1 += x1; q1 += x1 * x1;
                }
            }
        }
        // lanes {l, l^16, l^32, l^48} share col -> reduce, then 1 atomic set
        s1 += __shfl_xor(s1, 16); s1 += __shfl_xor(s1, 32);
        q1 += __shfl_xor(q1, 16); q1 += __shfl_xor(q1, 32);
        s2 += __shfl_xor(s2, 16); s2 += __shfl_xor(s2, 32);
        q2 += __shfl_xor(q2, 16); q2 += __shfl_xor(q2, 32);
        if ((l >> 4) == 0) {
            atomicAdd(&spart[slot * 512 + col], s1);
            atomicAdd(&spart[slot * 512 + 128 + col], q1);
            atomicAdd(&spart[slot * 512 + 256 + col], s2);
            atomicAdd(&spart[slot * 512 + 384 + col], q2);
        }
    }
}

// =====================================================================
// finalize BN1+BN2: reduce partial slots -> affine; re-zero
// =====================================================================
__global__ __launch_bounds__(128)
void finalize12_kernel(float* __restrict__ spart, const float* __restrict__ bng,
                       const float* __restrict__ bnb, float rcount,
                       float* __restrict__ ab12)
{
    int c = TID;
    float s1 = 0, q1 = 0, s2 = 0, q2 = 0;
    for (int s = 0; s < NSLOT; ++s) {
        float* p = spart + s * 512;
        s1 += p[c]; q1 += p[128 + c]; s2 += p[256 + c]; q2 += p[384 + c];
        p[c] = 0.f; p[128 + c] = 0.f; p[256 + c] = 0.f; p[384 + c] = 0.f;
    }
    float m1 = s1 * rcount, v1 = q1 * rcount - m1 * m1;
    float a1 = rsqrtf(v1 + EPS_) * bng[c];
    ab12[c] = a1; ab12[128 + c] = bnb[c] - m1 * a1;
    float m2 = s2 * rcount, v2 = q2 * rcount - m2 * m2;
    float a2 = rsqrtf(v2 + EPS_) * bng[128 + c];
    ab12[256 + c] = a2; ab12[384 + c] = bnb[128 + c] - m2 * a2;
}

// finalize BN3 -> ab3; re-zero partials
__global__ __launch_bounds__(128)
void finalize3_kernel(float* __restrict__ spart, const float* __restrict__ gamma,
                      const float* __restrict__ beta, float rcount,
                      float* __restrict__ ab3)
{
    int c = TID;
    float s1 = 0, q1 = 0;
    for (int s = 0; s < NSLOT; ++s) {
        float* p = spart + s * 256;
        s1 += p[c]; q1 += p[128 + c];
        p[c] = 0.f; p[128 + c] = 0.f;
    }
    float m = s1 * rcount, v = q1 * rcount - m * m;
    float a = rsqrtf(v + EPS_) * gamma[c];
    ab3[c] = a; ab3[128 + c] = beta[c] - m * a;
}

// =====================================================================
// Fused MLP — LDS 54272B -> 3 blocks/CU; stats via shfl-reduce
// =====================================================================
__global__ __launch_bounds__(256)
void mlp_mfma_kernel(bf16* __restrict__ X, const float* __restrict__ ab3,
                     const bf16* __restrict__ gcn, const bf16* __restrict__ t2,
                     const float* __restrict__ ab12,
                     const bf16* __restrict__ w1b, const float* __restrict__ b1,
                     const bf16* __restrict__ w2b, const float* __restrict__ b2,
                     int n, float* __restrict__ spart3)
{
    constexpr int MP = 264;
    __shared__ short sM[64][MP];
    __shared__ short sOUT[64][136];
    __shared__ float sAB[768];
    const int l = TID & 63, wid = TID >> 6;
    const size_t rbase = (size_t)blockIdx.x * 64;
    bf16* Xb = X + rbase * D_;
    const bf16* Tb = t2 + rbase * D_;

    sAB[TID] = ab3[TID];
    for (int i = TID; i < 512; i += 256) sAB[256 + i] = ab12[i];
    __syncthreads();

    {
        int row = TID >> 2;
        int cb0 = (TID & 3) * 32;
        int g = (int)((rbase + row) / n);
        #pragma unroll
        for (int k2 = 0; k2 < 4; ++k2) {
            int cb = cb0 + k2 * 8;
            s8v xv = *(const s8v*)(Xb + (size_t)row * D_ + cb);
            s8v gv = *(const s8v*)(gcn + (size_t)g * D_ + cb);
            s8v tv = *(const s8v*)(Tb + (size_t)row * D_ + cb);
            s8v af;
            #pragma unroll
            for (int e = 0; e < 8; ++e) {
                int c = cb + e;
                float hn = bfu(xv[e]) * sAB[c] + sAB[128 + c];
                float outv = (hn + bfu(gv[e])) * sAB[256 + c] + sAB[384 + c]
                           + bfu(tv[e]) * sAB[512 + c] + sAB[640 + c];
                af[e] = f2s(outv);
            }
            *(s8v*)(&sOUT[row][cb]) = af;
        }
    }
    __syncthreads();

    s8v a[4][4];
    #pragma unroll
    for (int t = 0; t < 4; ++t) {
        const short* rp = &sOUT[t * 16 + (l & 15)][(l >> 4) * 8];
        #pragma unroll
        for (int ks = 0; ks < 4; ++ks) a[t][ks] = *(const s8v*)(rp + ks * 32);
    }
    for (int nt = wid; nt < 16; nt += 4) {
        int col = nt * 16 + (l & 15);
        const bf16* wp = w1b + (size_t)col * D_ + ((l >> 4) * 8);
        s8v b[4];
        #pragma unroll
        for (int ks = 0; ks < 4; ++ks) b[ks] = *(const s8v*)(wp + ks * 32);
        float bs = b1[col];
        #pragma unroll
        for (int t = 0; t < 4; ++t) {
            f4v acc = {bs, bs, bs, bs};
            #pragma unroll
            for (int ks = 0; ks < 4; ++ks)
                acc = __builtin_amdgcn_mfma_f32_16x16x32_bf16(a[t][ks], b[ks], acc, 0, 0, 0);
            #pragma unroll
            for (int r = 0; r < 4; ++r)
                sM[t * 16 + (l >> 4) * 4 + r][col] = f2s(fmaxf(acc[r], 0.f));
        }
    }
    __syncthreads();

    {
        const int nt0 = wid * 2;
        const int col0 = nt0 * 16 + (l & 15), col1 = col0 + 16;
        s8v b0[8], b1v[8];
        #pragma unroll
        for (int ks = 0; ks < 8; ++ks) {
            b0[ks]  = *(const s8v*)(w2b + (size_t)col0 * 256 + ks * 32 + ((l >> 4) * 8));
            b1v[ks] = *(const s8v*)(w2b + (size_t)col1 * 256 + ks * 32 + ((l >> 4) * 8));
        }
        float bs0 = b2[col0], bs1 = b2[col1];
        float ss0 = 0.f, qq0 = 0.f, ss1 = 0.f, qq1 = 0.f;
        #pragma unroll
        for (int t = 0; t < 4; ++t) {
            s8v am[8];
            const short* rp = &sM[t * 16 + (l & 15)][(l >> 4) * 8];
            #pragma unroll
            for (int ks = 0; ks < 8; ++ks) am[ks] = *(const s8v*)(rp + ks * 32);
            f4v acc0 = {bs0, bs0, bs0, bs0};
            f4v acc1 = {bs1, bs1, bs1, bs1};
            #pragma unroll
            for (int ks = 0; ks < 8; ++ks) {
                acc0 = __builtin_amdgcn_mfma_f32_16x16x32_bf16(am[ks], b0[ks], acc0, 0, 0, 0);
                acc1 = __builtin_amdgcn_mfma_f32_16x16x32_bf16(am[ks], b1v[ks], acc1, 0, 0, 0);
            }
            #pragma unroll
            for (int r = 0; r < 4; ++r) {
                int row = t * 16 + (l >> 4) * 4 + r;
                float xn0 = acc0[r] + bfu(sOUT[row][col0]);
                float xn1 = acc1[r] + bfu(sOUT[row][col1]);
                Xb[(size_t)row * D_ + col0] = f2b(xn0);
                Xb[(size_t)row * D_ + col1] = f2b(xn1);
                ss0 += xn0; qq0 += xn0 * xn0;
                ss1 += xn1; qq1 += xn1 * xn1;
            }
        }
        ss0 += __shfl_xor(ss0, 16); ss0 += __shfl_xor(ss0, 32);
        qq0 += __shfl_xor(qq0, 16); qq0 += __shfl_xor(qq0, 32);
        ss1 += __shfl_xor(ss1, 16); ss1 += __shfl_xor(ss1, 32);
        qq1 += __shfl_xor(qq1, 16); qq1 += __shfl_xor(qq1, 32);
        if ((l >> 4) == 0) {
            int slot = blockIdx.x & (NSLOT - 1);
            atomicAdd(&spart3[slot * 256 + col0], ss0);
            atomicAdd(&spart3[slot * 256 + 128 + col0], qq0);
            atomicAdd(&spart3[slot * 256 + col1], ss1);
            atomicAdd(&spart3[slot * 256 + 128 + col1], qq1);
        }
    }
}

// =====================================================================
// Final pooling (with pending ab3 affine) + classifier
// =====================================================================
__global__ __launch_bounds__(128)
void poolcls_kernel(const bf16* __restrict__ gi, const float* __restrict__ ab,
                    const float* __restrict__ cw, const float* __restrict__ cb,
                    float* __restrict__ out)
{
    __shared__ float sP[128];
    int b = blockIdx.x, d = TID;
    const bf16* p = gi + (size_t)b * TN_ * D_ + d;
    float s = 0.f;
    for (int i = 0; i < TN_; ++i) s += b2f(p[i * D_]);
    sP[d] = (s * (1.f / TN_)) * ab[d] + ab[128 + d];
    __syncthreads();
    if (d < C_) {
        float acc = cb[d];
        for (int k = 0; k < D_; ++k) acc += sP[k] * cw[d * D_ + k];
        out[b * C_ + d] = acc;
    }
}

// =====================================================================
extern "C" void kernel_launch(void* const* d_in, const int* in_sizes, int n_in,
                              void* d_out, int out_size, void* d_ws, size_t ws_size,
                              hipStream_t stream)
{
    (void)in_sizes; (void)n_in; (void)out_size; (void)ws_size;

    const float* poses = (const float*)d_in[0];
    const float* emb_w = (const float*)d_in[1];
    const float* emb_b = (const float*)d_in[2];
    const float* cls_w = (const float*)d_in[3];
    const float* cls_b = (const float*)d_in[4];
    const float* jp[12]; const float* ip[12];
    for (int k = 0; k < 12; ++k) { jp[k] = (const float*)d_in[5 + k]; ip[k] = (const float*)d_in[17 + k]; }

    // ---- workspace layout ----
    char* base = (char*)d_ws;
    size_t off = 0;
    auto alloc_b = [&](size_t elems) -> bf16* {
        bf16* p = (bf16*)(base + off);
        off = (off + elems * sizeof(bf16) + 255) & ~(size_t)255;
        return p;
    };
    bf16* bufA  = alloc_b((size_t)R1_ * D_);
    bf16* bufB  = alloc_b((size_t)R1_ * D_);
    bf16* hbarJ = alloc_b((size_t)G1_ * D_);
    bf16* gcn1  = alloc_b((size_t)G1_ * D_);
    bf16* gcn2  = alloc_b((size_t)G2_ * D_);
    float* spart12 = (float*)(base + off); off += NSLOT * 512 * 4;
    float* spart3  = (float*)(base + off); off += NSLOT * 256 * 4;
    float* ab3     = (float*)(base + off); off += 256 * 4;
    float* ab12    = (float*)(base + off); off = (off + 512 * 4 + 255) & ~(size_t)255;
    bf16* wb[2][5];
    const int wsz[5] = {3 * D_ * D_, 3 * 3 * D_ * D_, 3 * D_ * D_, 3 * 2 * D_ * D_, 3 * 2 * D_ * D_};
    for (int s = 0; s < 2; ++s)
        for (int k = 0; k < 5; ++k) wb[s][k] = alloc_b((size_t)wsz[k]);

    // convert all weights: one launch per stage
    for (int s = 0; s < 2; ++s) {
        const float** P = s ? ip : jp;
        wconv5_kernel<<<1728, 256, 0, stream>>>(P[0], P[2], P[4], P[8], P[10],
                                                wb[s][0], wb[s][1], wb[s][2], wb[s][3], wb[s][4]);
    }
    zero_kernel<<<24, 256, 0, stream>>>(spart12, NSLOT * 512 + NSLOT * 256);

    embedv_kernel<<<4096, 256, 0, stream>>>(poses, emb_w, emb_b, bufA, R1_);

    auto run_stage = [&](const float** P, const bf16* const* W, bf16* h, bf16* t2,
                         bf16* gcn, int G, int n, int R) {
        setid_kernel<<<1, 128, 0, stream>>>(ab3);
        for (int L = 0; L < 3; ++L) {
            const bf16* gwb = W[0] + (size_t)L * D_ * D_;
            const bf16* qwb = W[1] + (size_t)L * 3 * D_ * D_;
            const bf16* owb = W[2] + (size_t)L * D_ * D_;
            const bf16* w1b = W[3] + (size_t)L * 2 * D_ * D_;
            const bf16* w2b = W[4] + (size_t)L * 2 * D_ * D_;
            const float* gb  = P[1] + (size_t)L * D_;
            const float* qb  = P[3] + (size_t)L * 3 * D_;
            const float* ob  = P[5] + (size_t)L * D_;
            const float* bng = P[6] + (size_t)L * 3 * D_;
            const float* bnb = P[7] + (size_t)L * 3 * D_;
            const float* b1  = P[9] + (size_t)L * 2 * D_;
            const float* b2  = P[11] + (size_t)L * D_;
            float rcount = 1.f / (float)R;

            if (n == J_)
                attn_mfma_kernel<J_, 2><<<G / 2, 256, 0, stream>>>(
                    h, ab3, gwb, gb, qwb, qb, owb, ob, t2, gcn, spart12);
            else
                attn_mfma_kernel<NI_, 4><<<G / 4, 256, 0, stream>>>(
                    h, ab3, gwb, gb, qwb, qb, owb, ob, t2, gcn, spart12);
            finalize12_kernel<<<1, 128, 0, stream>>>(spart12, bng, bnb, rcount, ab12);
            mlp_mfma_kernel<<<R / 64, 256, 0, stream>>>(h, ab3, gcn, t2, ab12,
                                                        w1b, b1, w2b, b2, n, spart3);
            finalize3_kernel<<<1, 128, 0, stream>>>(spart3, bng + 2 * D_, bnb + 2 * D_,
                                                    rcount, ab3);
        }
    };

    // joint stage
    run_stage(jp, wb[0], bufA, bufB, gcn1, G1_, J_, R1_);
    // joint -> individual pooling (applies joint-final ab3 after the mean)
    gmeanv_kernel<<<G1_ * 16 / 256, 256, 0, stream>>>(bufA, ab3, hbarJ, G1_, J_);
    // individual stage
    run_stage(ip, wb[1], hbarJ, bufB, gcn2, G2_, NI_, R2_);
    // final pooling + classifier
    poolcls_kernel<<<B_, 128, 0, stream>>>(hbarJ, ab3, cls_w, cls_b, (float*)d_out);
}

// Round 14
// 1370.005 us; speedup vs baseline: 17.6680x; 1.0263x over previous
//
#include <hip/hip_runtime.h>
#include <hip/hip_bf16.h>

#define TID threadIdx.x

typedef __hip_bfloat16 bf16;
typedef short s8v __attribute__((ext_vector_type(8)));
typedef float f4v __attribute__((ext_vector_type(4)));
typedef float f16v __attribute__((ext_vector_type(16)));

__device__ __forceinline__ float b2f(bf16 x) { return __bfloat162float(x); }
__device__ __forceinline__ bf16  f2b(float x) { return __float2bfloat16(x); }
__device__ __forceinline__ short f2s(float x) {
    __hip_bfloat16 b = __float2bfloat16(x); short s; __builtin_memcpy(&s, &b, 2); return s;
}
__device__ __forceinline__ float bfu(short s) {
    unsigned u = ((unsigned)(unsigned short)s) << 16; float f; __builtin_memcpy(&f, &u, 4); return f;
}

// ---- problem constants ----
#define B_   256
#define T_   7
#define NI_  12
#define TN_  84
#define J_   17
#define D_   128
#define H_   4
#define DH_  32
#define C_   8
#define G1_  21504       // B_*TN_
#define R1_  365568      // G1_*J_
#define G2_  1792        // B_*T_
#define R2_  21504       // G2_*NI_
#define EPS_ 1e-5f
#define NSLOT 32

// =====================================================================
__global__ __launch_bounds__(256)
void zero_kernel(float* __restrict__ p, int n)
{
    int stride = gridDim.x * 256;
    for (int i = blockIdx.x * 256 + TID; i < n; i += stride) p[i] = 0.f;
}

__global__ __launch_bounds__(128)
void setid_kernel(float* __restrict__ ab)
{
    ab[TID] = 1.f; ab[128 + TID] = 0.f;
}

// fp32 -> bf16 conversion of the 5 weight tensors of one stage (1 launch)
__global__ __launch_bounds__(256)
void wconv5_kernel(const float* __restrict__ s0, const float* __restrict__ s1,
                   const float* __restrict__ s2, const float* __restrict__ s3,
                   const float* __restrict__ s4,
                   bf16* __restrict__ d0, bf16* __restrict__ d1,
                   bf16* __restrict__ d2, bf16* __restrict__ d3,
                   bf16* __restrict__ d4)
{
    const int DD = D_ * D_;
    const int n0 = 3 * DD, n1 = 9 * DD, n2 = 3 * DD, n3 = 6 * DD;
    const int e0 = n0, e1 = e0 + n1, e2 = e1 + n2, e3 = e2 + n3, e4 = e3 + 6 * DD;
    int stride = gridDim.x * 256;
    for (int i = blockIdx.x * 256 + TID; i < e4; i += stride) {
        if (i < e0)      d0[i]      = f2b(s0[i]);
        else if (i < e1) d1[i - e0] = f2b(s1[i - e0]);
        else if (i < e2) d2[i - e1] = f2b(s2[i - e1]);
        else if (i < e3) d3[i - e2] = f2b(s3[i - e2]);
        else             d4[i - e3] = f2b(s4[i - e3]);
    }
}

// =====================================================================
// Embedding: h = leaky_relu(poses @ ew.T + eb)
// =====================================================================
__global__ __launch_bounds__(256)
void embedv_kernel(const float* __restrict__ poses, const float* __restrict__ ew,
                   const float* __restrict__ eb, bf16* __restrict__ h, int R)
{
    __shared__ float sE0[128], sE1[128], sEb[128];
    if (TID < 128) { sE0[TID] = ew[2 * TID]; sE1[TID] = ew[2 * TID + 1]; sEb[TID] = eb[TID]; }
    __syncthreads();
    int stride = gridDim.x * 256;
    for (int i8 = blockIdx.x * 256 + TID; i8 < R * 16; i8 += stride) {
        int r = i8 >> 4, c8 = (i8 & 15) * 8;
        float p0 = poses[2 * r], p1 = poses[2 * r + 1];
        s8v o;
        #pragma unroll
        for (int e = 0; e < 8; ++e) {
            int c = c8 + e;
            float v = p0 * sE0[c] + p1 * sE1[c] + sEb[c];
            o[e] = f2s(v > 0.f ? v : 0.01f * v);
        }
        *(s8v*)(h + (size_t)r * D_ + c8) = o;
    }
}

// =====================================================================
// Per-graph mean with pending-BN affine (joint->ind pooling only)
// =====================================================================
__global__ __launch_bounds__(256)
void gmeanv_kernel(const bf16* __restrict__ h, const float* __restrict__ ab,
                   bf16* __restrict__ hbar, int G, int n)
{
    int i8 = blockIdx.x * 256 + TID;
    if (i8 >= G * 16) return;
    int g = i8 >> 4, c8 = (i8 & 15) * 8;
    const bf16* p = h + (size_t)g * n * D_ + c8;
    float acc[8] = {0,0,0,0,0,0,0,0};
    for (int j = 0; j < n; ++j) {
        s8v v = *(const s8v*)(p + j * D_);
        #pragma unroll
        for (int e = 0; e < 8; ++e) acc[e] += bfu(v[e]);
    }
    float rn = 1.f / n;
    s8v o;
    #pragma unroll
    for (int e = 0; e < 8; ++e) {
        int c = c8 + e;
        o[e] = f2s(acc[e] * rn * ab[c] + ab[128 + c]);
    }
    *(s8v*)(hbar + (size_t)g * D_ + c8) = o;
}

// =====================================================================
// Fused attention + in-block GCN + BN1/BN2 stats.  512 threads (8 waves).
// =====================================================================
template<int NN, int NG>
__global__ __launch_bounds__(512)
void attn_mfma_kernel(const bf16* __restrict__ h, const float* __restrict__ ab3,
                      const bf16* __restrict__ gwb, const float* __restrict__ gb,
                      const bf16* __restrict__ qwb, const float* __restrict__ qb,
                      const bf16* __restrict__ owb, const float* __restrict__ ob,
                      bf16* __restrict__ out, bf16* __restrict__ gcnb,
                      float* __restrict__ spart)
{
    constexpr int ROWS = NG * NN;
    constexpr int MT = (ROWS + 15) / 16;
    constexpr int QP = 3 * D_ + 16;            // 400 shorts / row
    constexpr int HP = 152;
    constexpr int NPAIR = NG * H_;
    __shared__ __align__(16) short sQKV[ROWS][QP];
    __shared__ __align__(16) short sHN[ROWS][HP];
    __shared__ __align__(16) short sHB[NG][128];
    __shared__ short sGCN[NG][128];
    __shared__ float sAB[256];

    const int l = TID & 63, wid = TID >> 6;   // wid in [0,8)
    const size_t gbase = (size_t)blockIdx.x * ROWS * D_;
    const bf16* hb = h + gbase;

    if (TID < 256) sAB[TID] = ab3[TID];
    __syncthreads();

    // ---------- phase 0: hn = affine(h) -> sHN ----------
    for (int task = TID; task < ROWS * 16; task += 512) {
        int row = task >> 4, c8 = (task & 15) * 8;
        s8v raw = *(const s8v*)(hb + (size_t)row * D_ + c8);
        s8v af;
        #pragma unroll
        for (int e = 0; e < 8; ++e) {
            int c = c8 + e;
            af[e] = f2s(bfu(raw[e]) * sAB[c] + sAB[128 + c]);
        }
        *(s8v*)(&sHN[row][c8]) = af;
    }
    __syncthreads();

    // A-frags for QKV GEMM (sHN stable from here on)
    s8v a[MT][4];
    #pragma unroll
    for (int t = 0; t < MT; ++t) {
        int row = t * 16 + (l & 15);
        if (row >= ROWS) row = ROWS - 1;
        const short* rp = &sHN[row][(l >> 4) * 8];
        #pragma unroll
        for (int ks = 0; ks < 4; ++ks) a[t][ks] = *(const s8v*)(rp + ks * 32);
    }

    // ---------- phase 0.5: hbar[g] = mean_j sHN[g*NN+j] ----------
    for (int task = TID; task < NG * D_; task += 512) {
        int g = task >> 7, col = task & 127;
        float s = 0.f;
        for (int j = 0; j < NN; ++j) s += bfu(sHN[g * NN + j][col]);
        sHB[g][col] = f2s(s * (1.f / NN));
    }
    __syncthreads();

    // ---------- phase 0.75: gcn = hbar @ gw.T + gb (1 col-tile / wave) ----------
    {
        int rclamp = (l & 15) < NG ? (l & 15) : NG - 1;
        s8v ag[4];
        #pragma unroll
        for (int ks = 0; ks < 4; ++ks)
            ag[ks] = *(const s8v*)(&sHB[rclamp][ks * 32 + ((l >> 4) * 8)]);
        bf16* gout = gcnb + (size_t)blockIdx.x * NG * D_;
        int col = wid * 16 + (l & 15);
        float bs = gb[col];
        f4v acc = {bs, bs, bs, bs};
        #pragma unroll
        for (int ks = 0; ks < 4; ++ks) {
            s8v b = *(const s8v*)(gwb + (size_t)col * D_ + ks * 32 + ((l >> 4) * 8));
            acc = __builtin_amdgcn_mfma_f32_16x16x32_bf16(ag[ks], b, acc, 0, 0, 0);
        }
        if ((l >> 4) == 0) {
            #pragma unroll
            for (int r = 0; r < NG; ++r) {
                sGCN[r][col] = f2s(acc[r]);
                gout[(size_t)r * D_ + col] = f2b(acc[r]);
            }
        }
    }

    // ---------- phase 1: QKV = hn @ qw.T + qb (3 nt / wave) ----------
    for (int nt = wid; nt < 24; nt += 8) {
        int col = nt * 16 + (l & 15);
        const bf16* wp = qwb + (size_t)col * D_ + ((l >> 4) * 8);
        s8v b[4];
        #pragma unroll
        for (int ks = 0; ks < 4; ++ks) b[ks] = *(const s8v*)(wp + ks * 32);
        float bs = qb[col];
        #pragma unroll
        for (int t = 0; t < MT; ++t) {
            f4v acc = {bs, bs, bs, bs};
            #pragma unroll
            for (int ks = 0; ks < 4; ++ks)
                acc = __builtin_amdgcn_mfma_f32_16x16x32_bf16(a[t][ks], b[ks], acc, 0, 0, 0);
            #pragma unroll
            for (int r = 0; r < 4; ++r) {
                int row2 = t * 16 + (l >> 4) * 4 + r;
                if (row2 < ROWS) sQKV[row2][col] = f2s(acc[r]);
            }
        }
    }
    __syncthreads();

    // ---------- phases 2-3: per (g,h): S^T=K@Q^T -> softmax -> O=P@V ----------
    {
        const float inv = 0.17677669529663687f;   // 1/sqrt(32)
        const int l31 = l & 31, Gq = l >> 5;
        #pragma unroll
        for (int q = 0; q < (NPAIR + 7) / 8; ++q) {
            int p = wid + 8 * q;
            if (p < NPAIR) {
                int g = p >> 2, hd = p & 3;
                int gr = g * NN;
                int rr = gr + (l31 < NN ? l31 : NN - 1);
                s8v ka0 = *(const s8v*)(&sQKV[rr][D_ + hd * DH_ + Gq * 8]);
                s8v ka1 = *(const s8v*)(&sQKV[rr][D_ + hd * DH_ + Gq * 8 + 16]);
                s8v qb0 = *(const s8v*)(&sQKV[rr][hd * DH_ + Gq * 8]);
                s8v qb1 = *(const s8v*)(&sQKV[rr][hd * DH_ + Gq * 8 + 16]);
                f16v s = {};
                s = __builtin_amdgcn_mfma_f32_32x32x16_bf16(ka0, qb0, s, 0, 0, 0);
                s = __builtin_amdgcn_mfma_f32_32x32x16_bf16(ka1, qb1, s, 0, 0, 0);
                float m = -1e30f;
                #pragma unroll
                for (int r = 0; r < 16; ++r) {
                    int j = (r & 3) + 8 * (r >> 2) + 4 * Gq;
                    if (j < NN) m = fmaxf(m, s[r]);
                }
                m = fmaxf(m, __shfl_xor(m, 32));
                float pv[16]; float sum = 0.f;
                #pragma unroll
                for (int r = 0; r < 16; ++r) {
                    int j = (r & 3) + 8 * (r >> 2) + 4 * Gq;
                    float e = (j < NN) ? __expf((s[r] - m) * inv) : 0.f;
                    pv[r] = e; sum += e;
                }
                sum += __shfl_xor(sum, 32);
                float rs = 1.f / sum;
                if (l31 < NN) {
                    #pragma unroll
                    for (int r = 0; r < 16; ++r) {
                        int j = (r & 3) + 8 * (r >> 2) + 4 * Gq;
                        sQKV[gr + l31][D_ + hd * DH_ + j] = f2s(pv[r] * rs); // 0 for j>=NN
                    }
                }
                int prow = gr + l31; if (prow > ROWS - 1) prow = ROWS - 1;
                s8v pa0 = *(const s8v*)(&sQKV[prow][D_ + hd * DH_ + Gq * 8]);
                s8v pa1 = *(const s8v*)(&sQKV[prow][D_ + hd * DH_ + Gq * 8 + 16]);
                s8v vb0, vb1;
                #pragma unroll
                for (int e = 0; e < 8; ++e) {
                    int j0 = Gq * 8 + e;      int jj0 = j0 < NN ? j0 : 0;
                    int j1 = 16 + Gq * 8 + e; int jj1 = j1 < NN ? j1 : 0;
                    vb0[e] = sQKV[gr + jj0][2 * D_ + hd * DH_ + l31];
                    vb1[e] = sQKV[gr + jj1][2 * D_ + hd * DH_ + l31];
                }
                f16v o = {};
                o = __builtin_amdgcn_mfma_f32_32x32x16_bf16(pa0, vb0, o, 0, 0, 0);
                o = __builtin_amdgcn_mfma_f32_32x32x16_bf16(pa1, vb1, o, 0, 0, 0);
                #pragma unroll
                for (int r = 0; r < 16; ++r) {
                    int i = (r & 3) + 8 * (r >> 2) + 4 * Gq;
                    if (i < NN) sQKV[gr + i][hd * DH_ + l31] = f2s(o[r]);  // O -> Q slot
                }
            }
        }
    }
    __syncthreads();

    // ---------- phase 4: t2 = O @ ow.T + ob + hn ; stats (1 nt / wave) ----------
    bf16* og = out + gbase;
    #pragma unroll
    for (int t = 0; t < MT; ++t) {
        int row = t * 16 + (l & 15);
        if (row >= ROWS) row = ROWS - 1;
        const short* rp = &sQKV[row][(l >> 4) * 8];
        #pragma unroll
        for (int ks = 0; ks < 4; ++ks) a[t][ks] = *(const s8v*)(rp + ks * 32);
    }
    const int slot = blockIdx.x & (NSLOT - 1);
    {
        int nt = wid;
        int col = nt * 16 + (l & 15);
        const bf16* wp = owb + (size_t)col * D_ + ((l >> 4) * 8);
        s8v b[4];
        #pragma unroll
        for (int ks = 0; ks < 4; ++ks) b[ks] = *(const s8v*)(wp + ks * 32);
        float bs = ob[col];
        float s1 = 0.f, q1 = 0.f, s2 = 0.f, q2 = 0.f;
        #pragma unroll
        for (int t = 0; t < MT; ++t) {
            f4v acc = {bs, bs, bs, bs};
            #pragma unroll
            for (int ks = 0; ks < 4; ++ks)
                acc = __builtin_amdgcn_mfma_f32_16x16x32_bf16(a[t][ks], b[ks], acc, 0, 0, 0);
            #pragma unroll
            for (int r = 0; r < 4; ++r) {
                int row = t * 16 + (l >> 4) * 4 + r;
                if (row < ROWS) {
                    float res = bfu(sHN[row][col]);
                    float t2v = acc[r] + res;
                    og[(size_t)row * D_ + col] = f2b(t2v);
                    s2 += t2v; q2 += t2v * t2v;
                    int g = row / NN;
                    float x1 = res + bfu(sGCN[g][col]);
                    s1 += x1; q1 += x1 * x1;
                }
            }
        }
        s1 += __shfl_xor(s1, 16); s1 += __shfl_xor(s1, 32);
        q1 += __shfl_xor(q1, 16); q1 += __shfl_xor(q1, 32);
        s2 += __shfl_xor(s2, 16); s2 += __shfl_xor(s2, 32);
        q2 += __shfl_xor(q2, 16); q2 += __shfl_xor(q2, 32);
        if ((l >> 4) == 0) {
            atomicAdd(&spart[slot * 512 + col], s1);
            atomicAdd(&spart[slot * 512 + 128 + col], q1);
            atomicAdd(&spart[slot * 512 + 256 + col], s2);
            atomicAdd(&spart[slot * 512 + 384 + col], q2);
        }
    }
}

// =====================================================================
// finalize BN1+BN2: reduce partial slots -> affine; re-zero
// =====================================================================
__global__ __launch_bounds__(128)
void finalize12_kernel(float* __restrict__ spart, const float* __restrict__ bng,
                       const float* __restrict__ bnb, float rcount,
                       float* __restrict__ ab12)
{
    int c = TID;
    float s1 = 0, q1 = 0, s2 = 0, q2 = 0;
    for (int s = 0; s < NSLOT; ++s) {
        float* p = spart + s * 512;
        s1 += p[c]; q1 += p[128 + c]; s2 += p[256 + c]; q2 += p[384 + c];
        p[c] = 0.f; p[128 + c] = 0.f; p[256 + c] = 0.f; p[384 + c] = 0.f;
    }
    float m1 = s1 * rcount, v1 = q1 * rcount - m1 * m1;
    float a1 = rsqrtf(v1 + EPS_) * bng[c];
    ab12[c] = a1; ab12[128 + c] = bnb[c] - m1 * a1;
    float m2 = s2 * rcount, v2 = q2 * rcount - m2 * m2;
    float a2 = rsqrtf(v2 + EPS_) * bng[128 + c];
    ab12[256 + c] = a2; ab12[384 + c] = bnb[128 + c] - m2 * a2;
}

// finalize BN3 -> ab3; re-zero partials
__global__ __launch_bounds__(128)
void finalize3_kernel(float* __restrict__ spart, const float* __restrict__ gamma,
                      const float* __restrict__ beta, float rcount,
                      float* __restrict__ ab3)
{
    int c = TID;
    float s1 = 0, q1 = 0;
    for (int s = 0; s < NSLOT; ++s) {
        float* p = spart + s * 256;
        s1 += p[c]; q1 += p[128 + c];
        p[c] = 0.f; p[128 + c] = 0.f;
    }
    float m = s1 * rcount, v = q1 * rcount - m * m;
    float a = rsqrtf(v + EPS_) * gamma[c];
    ab3[c] = a; ab3[128 + c] = beta[c] - m * a;
}

// =====================================================================
// Fused MLP — 512 threads (8 waves), LDS unchanged -> 24 waves/CU
// =====================================================================
__global__ __launch_bounds__(512)
void mlp_mfma_kernel(bf16* __restrict__ X, const float* __restrict__ ab3,
                     const bf16* __restrict__ gcn, const bf16* __restrict__ t2,
                     const float* __restrict__ ab12,
                     const bf16* __restrict__ w1b, const float* __restrict__ b1,
                     const bf16* __restrict__ w2b, const float* __restrict__ b2,
                     int n, float* __restrict__ spart3)
{
    constexpr int MP = 264;
    __shared__ short sM[64][MP];
    __shared__ short sOUT[64][136];
    __shared__ float sAB[768];
    const int l = TID & 63, wid = TID >> 6;   // wid in [0,8)
    const size_t rbase = (size_t)blockIdx.x * 64;
    bf16* Xb = X + rbase * D_;
    const bf16* Tb = t2 + rbase * D_;

    if (TID < 256) sAB[TID] = ab3[TID];
    sAB[256 + TID] = ab12[TID];
    __syncthreads();

    // phase 0: out = BN1(hn+gcn)+BN2(t2) -> sOUT (cooperative)
    for (int task = TID; task < 64 * 16; task += 512) {
        int row = task >> 4, cb = (task & 15) * 8;
        int g = (int)((rbase + row) / n);
        s8v xv = *(const s8v*)(Xb + (size_t)row * D_ + cb);
        s8v gv = *(const s8v*)(gcn + (size_t)g * D_ + cb);
        s8v tv = *(const s8v*)(Tb + (size_t)row * D_ + cb);
        s8v af;
        #pragma unroll
        for (int e = 0; e < 8; ++e) {
            int c = cb + e;
            float hn = bfu(xv[e]) * sAB[c] + sAB[128 + c];
            float outv = (hn + bfu(gv[e])) * sAB[256 + c] + sAB[384 + c]
                       + bfu(tv[e]) * sAB[512 + c] + sAB[640 + c];
            af[e] = f2s(outv);
        }
        *(s8v*)(&sOUT[row][cb]) = af;
    }
    __syncthreads();

    // phase 1: M = relu(out @ w1.T + b1)  (2 nt / wave)
    s8v a[4][4];
    #pragma unroll
    for (int t = 0; t < 4; ++t) {
        const short* rp = &sOUT[t * 16 + (l & 15)][(l >> 4) * 8];
        #pragma unroll
        for (int ks = 0; ks < 4; ++ks) a[t][ks] = *(const s8v*)(rp + ks * 32);
    }
    for (int nt = wid; nt < 16; nt += 8) {
        int col = nt * 16 + (l & 15);
        const bf16* wp = w1b + (size_t)col * D_ + ((l >> 4) * 8);
        s8v b[4];
        #pragma unroll
        for (int ks = 0; ks < 4; ++ks) b[ks] = *(const s8v*)(wp + ks * 32);
        float bs = b1[col];
        #pragma unroll
        for (int t = 0; t < 4; ++t) {
            f4v acc = {bs, bs, bs, bs};
            #pragma unroll
            for (int ks = 0; ks < 4; ++ks)
                acc = __builtin_amdgcn_mfma_f32_16x16x32_bf16(a[t][ks], b[ks], acc, 0, 0, 0);
            #pragma unroll
            for (int r = 0; r < 4; ++r)
                sM[t * 16 + (l >> 4) * 4 + r][col] = f2s(fmaxf(acc[r], 0.f));
        }
    }
    __syncthreads();

    // phase 2: X = out + M @ w2.T + b2 ; stats3 (1 col-tile / wave)
    {
        const int col0 = wid * 16 + (l & 15);
        s8v b0[8];
        #pragma unroll
        for (int ks = 0; ks < 8; ++ks)
            b0[ks] = *(const s8v*)(w2b + (size_t)col0 * 256 + ks * 32 + ((l >> 4) * 8));
        float bs0 = b2[col0];
        float ss0 = 0.f, qq0 = 0.f;
        #pragma unroll
        for (int t = 0; t < 4; ++t) {
            s8v am[8];
            const short* rp = &sM[t * 16 + (l & 15)][(l >> 4) * 8];
            #pragma unroll
            for (int ks = 0; ks < 8; ++ks) am[ks] = *(const s8v*)(rp + ks * 32);
            f4v acc0 = {bs0, bs0, bs0, bs0};
            #pragma unroll
            for (int ks = 0; ks < 8; ++ks)
                acc0 = __builtin_amdgcn_mfma_f32_16x16x32_bf16(am[ks], b0[ks], acc0, 0, 0, 0);
            #pragma unroll
            for (int r = 0; r < 4; ++r) {
                int row = t * 16 + (l >> 4) * 4 + r;
                float xn0 = acc0[r] + bfu(sOUT[row][col0]);
                Xb[(size_t)row * D_ + col0] = f2b(xn0);
                ss0 += xn0; qq0 += xn0 * xn0;
            }
        }
        ss0 += __shfl_xor(ss0, 16); ss0 += __shfl_xor(ss0, 32);
        qq0 += __shfl_xor(qq0, 16); qq0 += __shfl_xor(qq0, 32);
        if ((l >> 4) == 0) {
            int slot = blockIdx.x & (NSLOT - 1);
            atomicAdd(&spart3[slot * 256 + col0], ss0);
            atomicAdd(&spart3[slot * 256 + 128 + col0], qq0);
        }
    }
}

// =====================================================================
// Final pooling (with pending ab3 affine) + classifier
// =====================================================================
__global__ __launch_bounds__(128)
void poolcls_kernel(const bf16* __restrict__ gi, const float* __restrict__ ab,
                    const float* __restrict__ cw, const float* __restrict__ cb,
                    float* __restrict__ out)
{
    __shared__ float sP[128];
    int b = blockIdx.x, d = TID;
    const bf16* p = gi + (size_t)b * TN_ * D_ + d;
    float s = 0.f;
    for (int i = 0; i < TN_; ++i) s += b2f(p[i * D_]);
    sP[d] = (s * (1.f / TN_)) * ab[d] + ab[128 + d];
    __syncthreads();
    if (d < C_) {
        float acc = cb[d];
        for (int k = 0; k < D_; ++k) acc += sP[k] * cw[d * D_ + k];
        out[b * C_ + d] = acc;
    }
}

// =====================================================================
extern "C" void kernel_launch(void* const* d_in, const int* in_sizes, int n_in,
                              void* d_out, int out_size, void* d_ws, size_t ws_size,
                              hipStream_t stream)
{
    (void)in_sizes; (void)n_in; (void)out_size; (void)ws_size;

    const float* poses = (const float*)d_in[0];
    const float* emb_w = (const float*)d_in[1];
    const float* emb_b = (const float*)d_in[2];
    const float* cls_w = (const float*)d_in[3];
    const float* cls_b = (const float*)d_in[4];
    const float* jp[12]; const float* ip[12];
    for (int k = 0; k < 12; ++k) { jp[k] = (const float*)d_in[5 + k]; ip[k] = (const float*)d_in[17 + k]; }

    // ---- workspace layout ----
    char* base = (char*)d_ws;
    size_t off = 0;
    auto alloc_b = [&](size_t elems) -> bf16* {
        bf16* p = (bf16*)(base + off);
        off = (off + elems * sizeof(bf16) + 255) & ~(size_t)255;
        return p;
    };
    bf16* bufA  = alloc_b((size_t)R1_ * D_);
    bf16* bufB  = alloc_b((size_t)R1_ * D_);
    bf16* hbarJ = alloc_b((size_t)G1_ * D_);
    bf16* gcn1  = alloc_b((size_t)G1_ * D_);
    bf16* gcn2  = alloc_b((size_t)G2_ * D_);
    float* spart12 = (float*)(base + off); off += NSLOT * 512 * 4;
    float* spart3  = (float*)(base + off); off += NSLOT * 256 * 4;
    float* ab3     = (float*)(base + off); off += 256 * 4;
    float* ab12    = (float*)(base + off); off = (off + 512 * 4 + 255) & ~(size_t)255;
    bf16* wb[2][5];
    const int wsz[5] = {3 * D_ * D_, 3 * 3 * D_ * D_, 3 * D_ * D_, 3 * 2 * D_ * D_, 3 * 2 * D_ * D_};
    for (int s = 0; s < 2; ++s)
        for (int k = 0; k < 5; ++k) wb[s][k] = alloc_b((size_t)wsz[k]);

    // convert all weights: one launch per stage
    for (int s = 0; s < 2; ++s) {
        const float** P = s ? ip : jp;
        wconv5_kernel<<<1728, 256, 0, stream>>>(P[0], P[2], P[4], P[8], P[10],
                                                wb[s][0], wb[s][1], wb[s][2], wb[s][3], wb[s][4]);
    }
    zero_kernel<<<24, 256, 0, stream>>>(spart12, NSLOT * 512 + NSLOT * 256);

    embedv_kernel<<<4096, 256, 0, stream>>>(poses, emb_w, emb_b, bufA, R1_);

    auto run_stage = [&](const float** P, const bf16* const* W, bf16* h, bf16* t2,
                         bf16* gcn, int G, int n, int R) {
        setid_kernel<<<1, 128, 0, stream>>>(ab3);
        for (int L = 0; L < 3; ++L) {
            const bf16* gwb = W[0] + (size_t)L * D_ * D_;
            const bf16* qwb = W[1] + (size_t)L * 3 * D_ * D_;
            const bf16* owb = W[2] + (size_t)L * D_ * D_;
            const bf16* w1b = W[3] + (size_t)L * 2 * D_ * D_;
            const bf16* w2b = W[4] + (size_t)L * 2 * D_ * D_;
            const float* gb  = P[1] + (size_t)L * D_;
            const float* qb  = P[3] + (size_t)L * 3 * D_;
            const float* ob  = P[5] + (size_t)L * D_;
            const float* bng = P[6] + (size_t)L * 3 * D_;
            const float* bnb = P[7] + (size_t)L * 3 * D_;
            const float* b1  = P[9] + (size_t)L * 2 * D_;
            const float* b2  = P[11] + (size_t)L * D_;
            float rcount = 1.f / (float)R;

            if (n == J_)
                attn_mfma_kernel<J_, 2><<<G / 2, 512, 0, stream>>>(
                    h, ab3, gwb, gb, qwb, qb, owb, ob, t2, gcn, spart12);
            else
                attn_mfma_kernel<NI_, 4><<<G / 4, 512, 0, stream>>>(
                    h, ab3, gwb, gb, qwb, qb, owb, ob, t2, gcn, spart12);
            finalize12_kernel<<<1, 128, 0, stream>>>(spart12, bng, bnb, rcount, ab12);
            mlp_mfma_kernel<<<R / 64, 512, 0, stream>>>(h, ab3, gcn, t2, ab12,
                                                        w1b, b1, w2b, b2, n, spart3);
            finalize3_kernel<<<1, 128, 0, stream>>>(spart3, bng + 2 * D_, bnb + 2 * D_,
                                                    rcount, ab3);
        }
    };

    // joint stage
    run_stage(jp, wb[0], bufA, bufB, gcn1, G1_, J_, R1_);
    // joint -> individual pooling (applies joint-final ab3 after the mean)
    gmeanv_kernel<<<G1_ * 16 / 256, 256, 0, stream>>>(bufA, ab3, hbarJ, G1_, J_);
    // individual stage
    run_stage(ip, wb[1], hbarJ, bufB, gcn2, G2_, NI_, R2_);
    // final pooling + classifier
    poolcls_kernel<<<B_, 128, 0, stream>>>(hbarJ, ab3, cls_w, cls_b, (float*)d_out);
}